// Round 1
// baseline (1694.742 us; speedup 1.0000x reference)
//
#include <hip/hip_runtime.h>
#include <math.h>

#define NN 100000
#define NE 1600000
#define ET (NE + NN)      // edges + self loops
#define NG 512
#define STATS_BLOCKS 240

// ---------------- edge sort (counting sort by dst) ----------------

__global__ void hist_edges(const int* __restrict__ ei, int* __restrict__ counts) {
    int e = blockIdx.x * blockDim.x + threadIdx.x;
    if (e >= ET) return;
    int d = (e < NE) ? ei[NE + e] : (e - NE);
    atomicAdd(&counts[d], 1);
}

__global__ void hist_batch(const int* __restrict__ batch, int* __restrict__ gcounts) {
    int n = blockIdx.x * blockDim.x + threadIdx.x;
    if (n >= NN) return;
    atomicAdd(&gcounts[batch[n]], 1);
}

// single-block exclusive scan (n up to ~100k), also writes out[n]=total and optional cursor copy
__global__ void scan_excl(const int* __restrict__ in, int n, int* __restrict__ out,
                          int* __restrict__ cursor) {
    __shared__ int lds[1024];
    int t = threadIdx.x;
    int running = 0;
    for (int base = 0; base < n; base += 1024) {
        int v = (base + t < n) ? in[base + t] : 0;
        lds[t] = v;
        __syncthreads();
        for (int off = 1; off < 1024; off <<= 1) {
            int x = (t >= off) ? lds[t - off] : 0;
            __syncthreads();
            lds[t] += x;
            __syncthreads();
        }
        int incl = lds[t];
        int total = lds[1023];
        if (base + t < n) {
            int ex = running + incl - v;
            out[base + t] = ex;
            if (cursor) cursor[base + t] = ex;
        }
        running += total;
        __syncthreads();
    }
    if (t == 0) out[n] = running;
}

__global__ void scatter_edges(const int* __restrict__ ei, int* __restrict__ cursor,
                              int* __restrict__ srcs) {
    int e = blockIdx.x * blockDim.x + threadIdx.x;
    if (e >= ET) return;
    int s, d;
    if (e < NE) { s = ei[e]; d = ei[NE + e]; }
    else        { s = d = e - NE; }
    int pos = atomicAdd(&cursor[d], 1);
    srcs[pos] = s;
}

// ---------------- gemm1: H = X(N,128) @ W(128,64) ----------------

__global__ __launch_bounds__(256) void gemm1(const float* __restrict__ X,
                                             const float* __restrict__ W,
                                             float* __restrict__ H) {
    __shared__ float wl[128 * 64];      // 32 KB
    __shared__ float xl[32 * 132];      // padded, ~16.9 KB
    int t = threadIdx.x;
    int n0 = blockIdx.x * 32;
    for (int i = t * 4; i < 128 * 64; i += 1024)
        *(float4*)&wl[i] = *(const float4*)&W[i];
    for (int i = t * 4; i < 32 * 128; i += 1024) {
        int r = i >> 7, c = i & 127;
        int n = n0 + r;
        float4 v = (n < NN) ? *(const float4*)&X[(size_t)n * 128 + c] : make_float4(0, 0, 0, 0);
        *(float4*)&xl[r * 132 + c] = v;
    }
    __syncthreads();
    int cg = (t & 15) * 4;
    int ng = (t >> 4) * 2;
    float acc[2][4] = {};
    for (int k = 0; k < 128; ++k) {
        float4 w4 = *(float4*)&wl[k * 64 + cg];
        #pragma unroll
        for (int j = 0; j < 2; ++j) {
            float xv = xl[(ng + j) * 132 + k];
            acc[j][0] += xv * w4.x; acc[j][1] += xv * w4.y;
            acc[j][2] += xv * w4.z; acc[j][3] += xv * w4.w;
        }
    }
    #pragma unroll
    for (int j = 0; j < 2; ++j) {
        int n = n0 + ng + j;
        if (n < NN)
            *(float4*)&H[(size_t)n * 64 + cg] =
                make_float4(acc[j][0], acc[j][1], acc[j][2], acc[j][3]);
    }
}

// ---------------- per-node attention scores ----------------

__global__ void scores_kernel(const float* __restrict__ H, const float* __restrict__ a_s,
                              const float* __restrict__ a_d, float* __restrict__ SS,
                              float* __restrict__ SD, int HEADS, int C) {
    int idx = blockIdx.x * blockDim.x + threadIdx.x;
    if (idx >= NN * HEADS) return;
    int n = idx / HEADS, h = idx % HEADS;
    const float* row = H + (size_t)n * HEADS * C + h * C;
    float s1 = 0.f, s2 = 0.f;
    for (int c = 0; c < C; ++c) {
        float v = row[c];
        s1 += v * a_s[h * C + c];
        s2 += v * a_d[h * C + c];
    }
    SS[idx] = s1;
    SD[idx] = s2;
}

// ---------------- GAT gather: one wave per dst node, online softmax ----------------

template <int HEADS, int C, int PL>
__global__ __launch_bounds__(256) void gat_kernel(const float* __restrict__ H,
                                                  const float* __restrict__ SS,
                                                  const float* __restrict__ SD,
                                                  const int* __restrict__ offsets,
                                                  const int* __restrict__ srcs,
                                                  const float* __restrict__ bias,
                                                  float* __restrict__ GO) {
    constexpr int CH = HEADS * C;  // 64 or 96
    int wid = blockIdx.x * (blockDim.x >> 6) + (threadIdx.x >> 6);
    int lane = threadIdx.x & 63;
    if (wid >= NN) return;
    int ch0 = lane * PL;
    bool active = ch0 < CH;
    int head = active ? (ch0 / C) : 0;
    float sdv = active ? SD[(size_t)wid * HEADS + head] : 0.f;
    float m = -1e30f, s = 0.f, a0 = 0.f, a1 = 0.f;
    int beg = offsets[wid], end = offsets[wid + 1];
    for (int e = beg; e < end; ++e) {
        int src = srcs[e];
        float sc = SS[(size_t)src * HEADS + head] + sdv;
        sc = sc > 0.f ? sc : 0.2f * sc;
        float mn = fmaxf(m, sc);
        float f = __expf(m - mn);
        float w = __expf(sc - mn);
        s = s * f + w;
        float h0 = 0.f, h1 = 0.f;
        if (active) {
            if (PL == 2) {
                float2 hv = *(const float2*)&H[(size_t)src * CH + ch0];
                h0 = hv.x; h1 = hv.y;
            } else {
                h0 = H[(size_t)src * CH + ch0];
            }
        }
        a0 = a0 * f + w * h0;
        if (PL == 2) a1 = a1 * f + w * h1;
        m = mn;
    }
    if (active) {
        float inv = 1.f / s;
        GO[(size_t)wid * CH + ch0] = a0 * inv + bias[ch0];
        if (PL == 2) GO[(size_t)wid * CH + ch0 + 1] = a1 * inv + bias[ch0 + 1];
    }
}

// ---------------- BN stats (deterministic two-stage) ----------------

__global__ void stats_kernel(const float* __restrict__ X, int Nn, int C,
                             float* __restrict__ partial) {
    int t = threadIdx.x;
    int c = t % C;
    int grp = t / C;
    int G_ = blockDim.x / C;
    float s = 0.f, q = 0.f;
    for (int n = blockIdx.x * G_ + grp; n < Nn; n += gridDim.x * G_) {
        float v = X[(size_t)n * C + c];
        s += v; q += v * v;
    }
    extern __shared__ float lds[];
    lds[t] = s; lds[blockDim.x + t] = q;
    __syncthreads();
    for (int off = blockDim.x >> 1; off >= C; off >>= 1) {
        if (t < off) {
            lds[t] += lds[t + off];
            lds[blockDim.x + t] += lds[blockDim.x + t + off];
        }
        __syncthreads();
    }
    if (t < C) {
        partial[(size_t)blockIdx.x * 2 * C + t] = lds[t];
        partial[(size_t)blockIdx.x * 2 * C + C + t] = lds[blockDim.x + t];
    }
}

__global__ void bn_finalize(const float* __restrict__ partial, int nb, int C, float invN,
                            const float* __restrict__ g, const float* __restrict__ be,
                            float* __restrict__ scale, float* __restrict__ shift) {
    int c = threadIdx.x;
    if (c >= C) return;
    float s = 0.f, q = 0.f;
    for (int b = 0; b < nb; ++b) {
        s += partial[(size_t)b * 2 * C + c];
        q += partial[(size_t)b * 2 * C + C + c];
    }
    float mean = s * invN;
    float var = fmaxf(q * invN - mean * mean, 0.f);
    float rs = rsqrtf(var + 1e-5f);
    float sc = g[c] * rs;
    scale[c] = sc;
    shift[c] = be[c] - mean * sc;
}

// ---------------- relu(bn(X[N,64])) @ Lw(64,KOUT) + lb -> U ----------------

template <int KOUT>
__global__ __launch_bounds__(256) void bnrelu_linear(const float* __restrict__ X,
                                                     const float* __restrict__ scale,
                                                     const float* __restrict__ shift,
                                                     const float* __restrict__ Lw,
                                                     const float* __restrict__ lb,
                                                     float* __restrict__ U) {
    __shared__ float tl[64 * 65];
    int t = threadIdx.x;
    int n0 = blockIdx.x * 64;
    for (int i = t * 4; i < 64 * 64; i += 1024) {
        int r = i >> 6, cc = i & 63;
        int n = n0 + r;
        float4 v = (n < NN) ? *(const float4*)&X[(size_t)n * 64 + cc] : make_float4(0, 0, 0, 0);
        float vv[4] = {v.x, v.y, v.z, v.w};
        #pragma unroll
        for (int j = 0; j < 4; ++j)
            tl[r * 65 + cc + j] = fmaxf(vv[j] * scale[cc + j] + shift[cc + j], 0.f);
    }
    __syncthreads();
    int nl = t & 63;
    int kg = (t >> 6) * (KOUT / 4);
    float acc[KOUT / 4] = {};
    for (int l = 0; l < 64; ++l) {
        float v = tl[nl * 65 + l];
        #pragma unroll
        for (int j = 0; j < KOUT / 4; ++j) acc[j] += v * Lw[l * KOUT + kg + j];
    }
    int n = n0 + nl;
    if (n < NN)
        #pragma unroll
        for (int j = 0; j < KOUT / 4; ++j)
            U[(size_t)n * KOUT + kg + j] = acc[j] + lb[kg + j];
}

// ---------------- relu(bn(U[N,CIN])) @ W(CIN,COUT) -> H ----------------

template <int CIN, int COUT>
__global__ __launch_bounds__(256) void bnrelu_gemm(const float* __restrict__ U,
                                                   const float* __restrict__ scale,
                                                   const float* __restrict__ shift,
                                                   const float* __restrict__ W,
                                                   float* __restrict__ H) {
    int t = threadIdx.x;
    int nl = t >> 2;
    int q = t & 3;
    int n = blockIdx.x * 64 + nl;
    if (n >= NN) return;
    constexpr int CPT = COUT / 4;
    float v[CIN];
    #pragma unroll
    for (int c = 0; c < CIN; ++c)
        v[c] = fmaxf(U[(size_t)n * CIN + c] * scale[c] + shift[c], 0.f);
    float acc[CPT] = {};
    #pragma unroll
    for (int c = 0; c < CIN; ++c) {
        #pragma unroll
        for (int j = 0; j < CPT; ++j) acc[j] += v[c] * W[c * COUT + q * CPT + j];
    }
    #pragma unroll
    for (int j = 0; j < CPT; ++j) H[(size_t)n * COUT + q * CPT + j] = acc[j];
}

// ---------------- mean-pool per graph (batch sorted -> contiguous ranges) ----------------

__global__ void pool_kernel(const float* __restrict__ GO, const float* __restrict__ scale,
                            const float* __restrict__ shift, const int* __restrict__ goff,
                            float* __restrict__ pooled) {
    int g = blockIdx.x;
    int t = threadIdx.x;
    if (t >= 96) return;
    int beg = goff[g], end = goff[g + 1];
    float s = 0.f;
    for (int n = beg; n < end; ++n)
        s += fmaxf(GO[(size_t)n * 96 + t] * scale[t] + shift[t], 0.f);
    float cnt = (float)(end - beg);
    pooled[g * 96 + t] = s / fmaxf(cnt, 1.f);
}

__global__ void final_gemm(const float* __restrict__ pooled, const float* __restrict__ oW,
                           const float* __restrict__ ob, float* __restrict__ out) {
    int idx = blockIdx.x * blockDim.x + threadIdx.x;
    if (idx >= NG * 10) return;
    int g = idx / 10, k = idx % 10;
    float s = ob[k];
    for (int c = 0; c < 96; ++c) s += pooled[g * 96 + c] * oW[c * 10 + k];
    out[idx] = s;
}

// ---------------- launch ----------------

extern "C" void kernel_launch(void* const* d_in, const int* in_sizes, int n_in,
                              void* d_out, int out_size, void* d_ws, size_t ws_size,
                              hipStream_t stream) {
    const float* x   = (const float*)d_in[0];
    const int*   ei  = (const int*)d_in[1];
    const int*   bat = (const int*)d_in[2];
    const float *W1 = (const float*)d_in[3], *a1s = (const float*)d_in[4],
                *a1d = (const float*)d_in[5], *b1 = (const float*)d_in[6],
                *g1 = (const float*)d_in[7], *be1 = (const float*)d_in[8],
                *lW1 = (const float*)d_in[9], *lb1 = (const float*)d_in[10],
                *gl1 = (const float*)d_in[11], *bel1 = (const float*)d_in[12],
                *W2 = (const float*)d_in[13], *a2s = (const float*)d_in[14],
                *a2d = (const float*)d_in[15], *b2 = (const float*)d_in[16],
                *g2 = (const float*)d_in[17], *be2 = (const float*)d_in[18],
                *lW2 = (const float*)d_in[19], *lb2 = (const float*)d_in[20],
                *gl2 = (const float*)d_in[21], *bel2 = (const float*)d_in[22],
                *W3 = (const float*)d_in[23], *a3s = (const float*)d_in[24],
                *a3d = (const float*)d_in[25], *b3 = (const float*)d_in[26],
                *g3 = (const float*)d_in[27], *be3 = (const float*)d_in[28],
                *oW = (const float*)d_in[29], *ob = (const float*)d_in[30];
    float* out = (float*)d_out;

    // workspace layout
    int* iw      = (int*)d_ws;
    int* counts  = iw;                   // NN
    int* gcounts = counts + NN;          // NG
    int* offsets = gcounts + NG;         // NN+1
    int* goff    = offsets + NN + 1;     // NG+1
    int* cursor  = goff + NG + 1;        // NN
    int* srcs    = cursor + NN;          // ET
    float* fw      = (float*)(srcs + ET);
    float* Hb      = fw;                         // NN*96
    float* GOb     = Hb + (size_t)NN * 96;       // NN*96
    float* Ub      = GOb + (size_t)NN * 96;      // NN*16
    float* SSb     = Ub + (size_t)NN * 16;       // NN*8
    float* SDb     = SSb + (size_t)NN * 8;       // NN*8
    float* partial = SDb + (size_t)NN * 8;       // STATS_BLOCKS*192
    float* scaleA  = partial + STATS_BLOCKS * 192;
    float* shiftA  = scaleA + 96;
    float* scaleB  = shiftA + 96;
    float* shiftB  = scaleB + 16;
    float* pooled  = shiftB + 16;                // NG*96

    const float invN = 1.0f / (float)NN;

    // ---- edge sort (shared by all layers) ----
    hipMemsetAsync(counts, 0, (NN + NG) * sizeof(int), stream);
    hist_edges<<<(ET + 255) / 256, 256, 0, stream>>>(ei, counts);
    hist_batch<<<(NN + 255) / 256, 256, 0, stream>>>(bat, gcounts);
    scan_excl<<<1, 1024, 0, stream>>>(counts, NN, offsets, cursor);
    scan_excl<<<1, 1024, 0, stream>>>(gcounts, NG, goff, nullptr);
    scatter_edges<<<(ET + 255) / 256, 256, 0, stream>>>(ei, cursor, srcs);

    // ---- layer 1 ----
    gemm1<<<(NN + 31) / 32, 256, 0, stream>>>(x, W1, Hb);
    scores_kernel<<<(NN * 8 + 255) / 256, 256, 0, stream>>>(Hb, a1s, a1d, SSb, SDb, 8, 8);
    gat_kernel<8, 8, 1><<<(NN + 3) / 4, 256, 0, stream>>>(Hb, SSb, SDb, offsets, srcs, b1, GOb);
    stats_kernel<<<STATS_BLOCKS, 256, 2 * 256 * sizeof(float), stream>>>(GOb, NN, 64, partial);
    bn_finalize<<<1, 128, 0, stream>>>(partial, STATS_BLOCKS, 64, invN, g1, be1, scaleA, shiftA);
    bnrelu_linear<8><<<(NN + 63) / 64, 256, 0, stream>>>(GOb, scaleA, shiftA, lW1, lb1, Ub);
    stats_kernel<<<STATS_BLOCKS, 256, 2 * 256 * sizeof(float), stream>>>(Ub, NN, 8, partial);
    bn_finalize<<<1, 128, 0, stream>>>(partial, STATS_BLOCKS, 8, invN, gl1, bel1, scaleB, shiftB);

    // ---- layer 2 ----
    bnrelu_gemm<8, 64><<<(NN + 63) / 64, 256, 0, stream>>>(Ub, scaleB, shiftB, W2, Hb);
    scores_kernel<<<(NN * 4 + 255) / 256, 256, 0, stream>>>(Hb, a2s, a2d, SSb, SDb, 4, 16);
    gat_kernel<4, 16, 1><<<(NN + 3) / 4, 256, 0, stream>>>(Hb, SSb, SDb, offsets, srcs, b2, GOb);
    stats_kernel<<<STATS_BLOCKS, 256, 2 * 256 * sizeof(float), stream>>>(GOb, NN, 64, partial);
    bn_finalize<<<1, 128, 0, stream>>>(partial, STATS_BLOCKS, 64, invN, g2, be2, scaleA, shiftA);
    bnrelu_linear<16><<<(NN + 63) / 64, 256, 0, stream>>>(GOb, scaleA, shiftA, lW2, lb2, Ub);
    stats_kernel<<<STATS_BLOCKS, 256, 2 * 256 * sizeof(float), stream>>>(Ub, NN, 16, partial);
    bn_finalize<<<1, 128, 0, stream>>>(partial, STATS_BLOCKS, 16, invN, gl2, bel2, scaleB, shiftB);

    // ---- layer 3 ----
    bnrelu_gemm<16, 96><<<(NN + 63) / 64, 256, 0, stream>>>(Ub, scaleB, shiftB, W3, Hb);
    scores_kernel<<<(NN * 4 + 255) / 256, 256, 0, stream>>>(Hb, a3s, a3d, SSb, SDb, 4, 24);
    gat_kernel<4, 24, 2><<<(NN + 3) / 4, 256, 0, stream>>>(Hb, SSb, SDb, offsets, srcs, b3, GOb);
    stats_kernel<<<STATS_BLOCKS, 192, 2 * 192 * sizeof(float), stream>>>(GOb, NN, 96, partial);
    bn_finalize<<<1, 128, 0, stream>>>(partial, STATS_BLOCKS, 96, invN, g3, be3, scaleA, shiftA);

    // ---- pool + head ----
    pool_kernel<<<NG, 128, 0, stream>>>(GOb, scaleA, shiftA, goff, pooled);
    final_gemm<<<(NG * 10 + 255) / 256, 256, 0, stream>>>(pooled, oW, ob, out);
}

// Round 2
// 1338.506 us; speedup vs baseline: 1.2661x; 1.2661x over previous
//
#include <hip/hip_runtime.h>
#include <math.h>

#define NN 100000
#define NE 1600000
#define ET (NE + NN)      // edges + self loops
#define NG 512
#define STATS_BLOCKS 240
#define SCAN_B 1024
#define SCAN_NB ((NN + SCAN_B - 1) / SCAN_B)   // 98

// ---------------- edge sort (counting sort by dst) ----------------

__global__ void hist_edges(const int* __restrict__ ei, int* __restrict__ counts) {
    int e = blockIdx.x * blockDim.x + threadIdx.x;
    if (e >= ET) return;
    int d = (e < NE) ? ei[NE + e] : (e - NE);
    atomicAdd(&counts[d], 1);
}

__global__ void hist_batch(const int* __restrict__ batch, int* __restrict__ gcounts) {
    int n = blockIdx.x * blockDim.x + threadIdx.x;
    if (n >= NN) return;
    atomicAdd(&gcounts[batch[n]], 1);
}

// multi-block exclusive scan: phase A (per-block reduce)
__global__ void scan_reduce(const int* __restrict__ in, int* __restrict__ bsum) {
    __shared__ int lds[256];
    int b = blockIdx.x, t = threadIdx.x;
    int s = 0;
    for (int i = t; i < SCAN_B; i += 256) {
        int idx = b * SCAN_B + i;
        if (idx < NN) s += in[idx];
    }
    lds[t] = s;
    __syncthreads();
    for (int off = 128; off > 0; off >>= 1) {
        if (t < off) lds[t] += lds[t + off];
        __syncthreads();
    }
    if (t == 0) bsum[b] = lds[0];
}

// phase B: single block scans block sums (nb <= 128), writes total to *total_loc
__global__ void scan_bsums(const int* __restrict__ bsum, int nb, int* __restrict__ boff,
                           int* __restrict__ total_loc) {
    __shared__ int lds[128];
    int t = threadIdx.x;
    int v = (t < nb) ? bsum[t] : 0;
    lds[t] = v;
    __syncthreads();
    for (int off = 1; off < 128; off <<= 1) {
        int x = (t >= off) ? lds[t - off] : 0;
        __syncthreads();
        lds[t] += x;
        __syncthreads();
    }
    if (t < nb) boff[t] = lds[t] - v;
    if (t == nb - 1) {
        boff[nb] = lds[t];
        if (total_loc) *total_loc = lds[t];
    }
}

// phase C: per-block scan + base add
__global__ void scan_final(const int* __restrict__ in, const int* __restrict__ boff,
                           int* __restrict__ out, int* __restrict__ cursor) {
    __shared__ int lds[SCAN_B];
    int b = blockIdx.x, t = threadIdx.x;
    int idx = b * SCAN_B + t;
    int v = (idx < NN) ? in[idx] : 0;
    lds[t] = v;
    __syncthreads();
    for (int off = 1; off < SCAN_B; off <<= 1) {
        int x = (t >= off) ? lds[t - off] : 0;
        __syncthreads();
        lds[t] += x;
        __syncthreads();
    }
    if (idx < NN) {
        int ex = boff[b] + lds[t] - v;
        out[idx] = ex;
        cursor[idx] = ex;
    }
}

// small single-block scan for graph offsets (NG=512)
__global__ void scan_small(const int* __restrict__ in, int n, int* __restrict__ out) {
    __shared__ int lds[1024];
    int t = threadIdx.x;
    int v = (t < n) ? in[t] : 0;
    lds[t] = v;
    __syncthreads();
    for (int off = 1; off < 1024; off <<= 1) {
        int x = (t >= off) ? lds[t - off] : 0;
        __syncthreads();
        lds[t] += x;
        __syncthreads();
    }
    if (t < n) out[t] = lds[t] - v;
    if (t == n - 1) out[n] = lds[t];
}

__global__ void scatter_edges(const int* __restrict__ ei, int* __restrict__ cursor,
                              int* __restrict__ srcs) {
    int e = blockIdx.x * blockDim.x + threadIdx.x;
    if (e >= ET) return;
    int s, d;
    if (e < NE) { s = ei[e]; d = ei[NE + e]; }
    else        { s = d = e - NE; }
    int pos = atomicAdd(&cursor[d], 1);
    srcs[pos] = s;
}

// ---------------- gemm1: H = X(N,128) @ W(128,64) ----------------

__global__ __launch_bounds__(256) void gemm1(const float* __restrict__ X,
                                             const float* __restrict__ W,
                                             float* __restrict__ H) {
    __shared__ float wl[128 * 64];      // 32 KB
    __shared__ float xl[32 * 132];      // padded, ~16.9 KB
    int t = threadIdx.x;
    int n0 = blockIdx.x * 32;
    for (int i = t * 4; i < 128 * 64; i += 1024)
        *(float4*)&wl[i] = *(const float4*)&W[i];
    for (int i = t * 4; i < 32 * 128; i += 1024) {
        int r = i >> 7, c = i & 127;
        int n = n0 + r;
        float4 v = (n < NN) ? *(const float4*)&X[(size_t)n * 128 + c] : make_float4(0, 0, 0, 0);
        *(float4*)&xl[r * 132 + c] = v;
    }
    __syncthreads();
    int cg = (t & 15) * 4;
    int ng = (t >> 4) * 2;
    float acc[2][4] = {};
    for (int k = 0; k < 128; ++k) {
        float4 w4 = *(float4*)&wl[k * 64 + cg];
        #pragma unroll
        for (int j = 0; j < 2; ++j) {
            float xv = xl[(ng + j) * 132 + k];
            acc[j][0] += xv * w4.x; acc[j][1] += xv * w4.y;
            acc[j][2] += xv * w4.z; acc[j][3] += xv * w4.w;
        }
    }
    #pragma unroll
    for (int j = 0; j < 2; ++j) {
        int n = n0 + ng + j;
        if (n < NN)
            *(float4*)&H[(size_t)n * 64 + cg] =
                make_float4(acc[j][0], acc[j][1], acc[j][2], acc[j][3]);
    }
}

// ---------------- per-node attention scores ----------------

__global__ void scores_kernel(const float* __restrict__ H, const float* __restrict__ a_s,
                              const float* __restrict__ a_d, float* __restrict__ SS,
                              float* __restrict__ SD, int HEADS, int C) {
    int idx = blockIdx.x * blockDim.x + threadIdx.x;
    if (idx >= NN * HEADS) return;
    int n = idx / HEADS, h = idx % HEADS;
    const float* row = H + (size_t)n * HEADS * C + h * C;
    float s1 = 0.f, s2 = 0.f;
    for (int c = 0; c < C; ++c) {
        float v = row[c];
        s1 += v * a_s[h * C + c];
        s2 += v * a_d[h * C + c];
    }
    SS[idx] = s1;
    SD[idx] = s2;
}

// ---------------- GAT gather: one wave per dst node, online softmax, 4x unroll ----------------

template <int HEADS, int C, int PL>
__global__ __launch_bounds__(256) void gat_kernel(const float* __restrict__ H,
                                                  const float* __restrict__ SS,
                                                  const float* __restrict__ SD,
                                                  const int* __restrict__ offsets,
                                                  const int* __restrict__ srcs,
                                                  const float* __restrict__ bias,
                                                  float* __restrict__ GO) {
    constexpr int CH = HEADS * C;  // 64 or 96
    int wid = blockIdx.x * (blockDim.x >> 6) + (threadIdx.x >> 6);
    int lane = threadIdx.x & 63;
    if (wid >= NN) return;
    int ch0 = lane * PL;
    bool active = ch0 < CH;
    int head = active ? (ch0 / C) : 0;
    float sdv = active ? SD[(unsigned)wid * HEADS + head] : 0.f;
    float m = -1e30f, s = 0.f, a0 = 0.f, a1 = 0.f;
    int beg = offsets[wid], end = offsets[wid + 1];
    int e = beg;
    for (; e + 4 <= end; e += 4) {
        int sv[4];
        #pragma unroll
        for (int i = 0; i < 4; ++i) sv[i] = srcs[e + i];
        float cc[4];
        #pragma unroll
        for (int i = 0; i < 4; ++i) {
            float c = SS[(unsigned)(sv[i] * HEADS) + head] + sdv;
            cc[i] = c > 0.f ? c : 0.2f * c;
        }
        float hv0[4], hv1[4];
        #pragma unroll
        for (int i = 0; i < 4; ++i) {
            hv0[i] = 0.f; hv1[i] = 0.f;
            if (active) {
                if (PL == 2) {
                    float2 hp = *(const float2*)&H[(unsigned)(sv[i] * CH) + ch0];
                    hv0[i] = hp.x; hv1[i] = hp.y;
                } else {
                    hv0[i] = H[(unsigned)(sv[i] * CH) + ch0];
                }
            }
        }
        float mloc = fmaxf(fmaxf(cc[0], cc[1]), fmaxf(cc[2], cc[3]));
        mloc = fmaxf(mloc, m);
        float f = __expf(m - mloc);
        float w[4];
        #pragma unroll
        for (int i = 0; i < 4; ++i) w[i] = __expf(cc[i] - mloc);
        s = s * f + ((w[0] + w[1]) + (w[2] + w[3]));
        a0 = a0 * f + ((w[0] * hv0[0] + w[1] * hv0[1]) + (w[2] * hv0[2] + w[3] * hv0[3]));
        if (PL == 2)
            a1 = a1 * f + ((w[0] * hv1[0] + w[1] * hv1[1]) + (w[2] * hv1[2] + w[3] * hv1[3]));
        m = mloc;
    }
    for (; e < end; ++e) {
        int src = srcs[e];
        float sc = SS[(unsigned)(src * HEADS) + head] + sdv;
        sc = sc > 0.f ? sc : 0.2f * sc;
        float mn = fmaxf(m, sc);
        float f = __expf(m - mn);
        float w = __expf(sc - mn);
        s = s * f + w;
        float h0 = 0.f, h1 = 0.f;
        if (active) {
            if (PL == 2) {
                float2 hp = *(const float2*)&H[(unsigned)(src * CH) + ch0];
                h0 = hp.x; h1 = hp.y;
            } else {
                h0 = H[(unsigned)(src * CH) + ch0];
            }
        }
        a0 = a0 * f + w * h0;
        if (PL == 2) a1 = a1 * f + w * h1;
        m = mn;
    }
    if (active) {
        float inv = 1.f / s;
        GO[(unsigned)(wid * CH) + ch0] = a0 * inv + bias[ch0];
        if (PL == 2) GO[(unsigned)(wid * CH) + ch0 + 1] = a1 * inv + bias[ch0 + 1];
    }
}

// ---------------- BN stats (deterministic two-stage) ----------------

__global__ void stats_kernel(const float* __restrict__ X, int Nn, int C,
                             float* __restrict__ partial) {
    int t = threadIdx.x;
    int c = t % C;
    int grp = t / C;
    int G_ = blockDim.x / C;
    float s = 0.f, q = 0.f;
    for (int n = blockIdx.x * G_ + grp; n < Nn; n += gridDim.x * G_) {
        float v = X[(size_t)n * C + c];
        s += v; q += v * v;
    }
    extern __shared__ float lds[];
    lds[t] = s; lds[blockDim.x + t] = q;
    __syncthreads();
    for (int off = blockDim.x >> 1; off >= C; off >>= 1) {
        if (t < off) {
            lds[t] += lds[t + off];
            lds[blockDim.x + t] += lds[blockDim.x + t + off];
        }
        __syncthreads();
    }
    if (t < C) {
        partial[(size_t)blockIdx.x * 2 * C + t] = lds[t];
        partial[(size_t)blockIdx.x * 2 * C + C + t] = lds[blockDim.x + t];
    }
}

__global__ void bn_finalize(const float* __restrict__ partial, int nb, int C, float invN,
                            const float* __restrict__ g, const float* __restrict__ be,
                            float* __restrict__ scale, float* __restrict__ shift) {
    int c = threadIdx.x;
    if (c >= C) return;
    float s = 0.f, q = 0.f;
    for (int b = 0; b < nb; ++b) {
        s += partial[(size_t)b * 2 * C + c];
        q += partial[(size_t)b * 2 * C + C + c];
    }
    float mean = s * invN;
    float var = fmaxf(q * invN - mean * mean, 0.f);
    float rs = rsqrtf(var + 1e-5f);
    float sc = g[c] * rs;
    scale[c] = sc;
    shift[c] = be[c] - mean * sc;
}

// ---------------- relu(bn(X[N,64])) @ Lw(64,KOUT) + lb -> U ----------------

template <int KOUT>
__global__ __launch_bounds__(256) void bnrelu_linear(const float* __restrict__ X,
                                                     const float* __restrict__ scale,
                                                     const float* __restrict__ shift,
                                                     const float* __restrict__ Lw,
                                                     const float* __restrict__ lb,
                                                     float* __restrict__ U) {
    __shared__ float tl[64 * 65];
    int t = threadIdx.x;
    int n0 = blockIdx.x * 64;
    for (int i = t * 4; i < 64 * 64; i += 1024) {
        int r = i >> 6, cc = i & 63;
        int n = n0 + r;
        float4 v = (n < NN) ? *(const float4*)&X[(size_t)n * 64 + cc] : make_float4(0, 0, 0, 0);
        float vv[4] = {v.x, v.y, v.z, v.w};
        #pragma unroll
        for (int j = 0; j < 4; ++j)
            tl[r * 65 + cc + j] = fmaxf(vv[j] * scale[cc + j] + shift[cc + j], 0.f);
    }
    __syncthreads();
    int nl = t & 63;
    int kg = (t >> 6) * (KOUT / 4);
    float acc[KOUT / 4] = {};
    for (int l = 0; l < 64; ++l) {
        float v = tl[nl * 65 + l];
        #pragma unroll
        for (int j = 0; j < KOUT / 4; ++j) acc[j] += v * Lw[l * KOUT + kg + j];
    }
    int n = n0 + nl;
    if (n < NN)
        #pragma unroll
        for (int j = 0; j < KOUT / 4; ++j)
            U[(size_t)n * KOUT + kg + j] = acc[j] + lb[kg + j];
}

// ---------------- relu(bn(U[N,CIN])) @ W(CIN,COUT) -> H ----------------

template <int CIN, int COUT>
__global__ __launch_bounds__(256) void bnrelu_gemm(const float* __restrict__ U,
                                                   const float* __restrict__ scale,
                                                   const float* __restrict__ shift,
                                                   const float* __restrict__ W,
                                                   float* __restrict__ H) {
    int t = threadIdx.x;
    int nl = t >> 2;
    int q = t & 3;
    int n = blockIdx.x * 64 + nl;
    if (n >= NN) return;
    constexpr int CPT = COUT / 4;
    float v[CIN];
    #pragma unroll
    for (int c = 0; c < CIN; ++c)
        v[c] = fmaxf(U[(size_t)n * CIN + c] * scale[c] + shift[c], 0.f);
    float acc[CPT] = {};
    #pragma unroll
    for (int c = 0; c < CIN; ++c) {
        #pragma unroll
        for (int j = 0; j < CPT; ++j) acc[j] += v[c] * W[c * COUT + q * CPT + j];
    }
    #pragma unroll
    for (int j = 0; j < CPT; ++j) H[(size_t)n * COUT + q * CPT + j] = acc[j];
}

// ---------------- mean-pool per graph (batch sorted -> contiguous ranges) ----------------

__global__ void pool_kernel(const float* __restrict__ GO, const float* __restrict__ scale,
                            const float* __restrict__ shift, const int* __restrict__ goff,
                            float* __restrict__ pooled) {
    int g = blockIdx.x;
    int t = threadIdx.x;
    if (t >= 96) return;
    int beg = goff[g], end = goff[g + 1];
    float s = 0.f;
    for (int n = beg; n < end; ++n)
        s += fmaxf(GO[(size_t)n * 96 + t] * scale[t] + shift[t], 0.f);
    float cnt = (float)(end - beg);
    pooled[g * 96 + t] = s / fmaxf(cnt, 1.f);
}

__global__ void final_gemm(const float* __restrict__ pooled, const float* __restrict__ oW,
                           const float* __restrict__ ob, float* __restrict__ out) {
    int idx = blockIdx.x * blockDim.x + threadIdx.x;
    if (idx >= NG * 10) return;
    int g = idx / 10, k = idx % 10;
    float s = ob[k];
    for (int c = 0; c < 96; ++c) s += pooled[g * 96 + c] * oW[c * 10 + k];
    out[idx] = s;
}

// ---------------- launch ----------------

extern "C" void kernel_launch(void* const* d_in, const int* in_sizes, int n_in,
                              void* d_out, int out_size, void* d_ws, size_t ws_size,
                              hipStream_t stream) {
    const float* x   = (const float*)d_in[0];
    const int*   ei  = (const int*)d_in[1];
    const int*   bat = (const int*)d_in[2];
    const float *W1 = (const float*)d_in[3], *a1s = (const float*)d_in[4],
                *a1d = (const float*)d_in[5], *b1 = (const float*)d_in[6],
                *g1 = (const float*)d_in[7], *be1 = (const float*)d_in[8],
                *lW1 = (const float*)d_in[9], *lb1 = (const float*)d_in[10],
                *gl1 = (const float*)d_in[11], *bel1 = (const float*)d_in[12],
                *W2 = (const float*)d_in[13], *a2s = (const float*)d_in[14],
                *a2d = (const float*)d_in[15], *b2 = (const float*)d_in[16],
                *g2 = (const float*)d_in[17], *be2 = (const float*)d_in[18],
                *lW2 = (const float*)d_in[19], *lb2 = (const float*)d_in[20],
                *gl2 = (const float*)d_in[21], *bel2 = (const float*)d_in[22],
                *W3 = (const float*)d_in[23], *a3s = (const float*)d_in[24],
                *a3d = (const float*)d_in[25], *b3 = (const float*)d_in[26],
                *g3 = (const float*)d_in[27], *be3 = (const float*)d_in[28],
                *oW = (const float*)d_in[29], *ob = (const float*)d_in[30];
    float* out = (float*)d_out;

    // workspace layout
    int* iw      = (int*)d_ws;
    int* counts  = iw;                   // NN
    int* gcounts = counts + NN;          // NG
    int* offsets = gcounts + NG;         // NN+1
    int* goff    = offsets + NN + 1;     // NG+1
    int* cursor  = goff + NG + 1;        // NN
    int* bsum    = cursor + NN;          // SCAN_NB
    int* boff    = bsum + SCAN_NB;       // SCAN_NB+1
    int* srcs    = boff + SCAN_NB + 1;   // ET
    float* fw      = (float*)(srcs + ET);
    float* Hb      = fw;                         // NN*96
    float* GOb     = Hb + (size_t)NN * 96;       // NN*96
    float* Ub      = GOb + (size_t)NN * 96;      // NN*16
    float* SSb     = Ub + (size_t)NN * 16;       // NN*8
    float* SDb     = SSb + (size_t)NN * 8;       // NN*8
    float* partial = SDb + (size_t)NN * 8;       // STATS_BLOCKS*192
    float* scaleA  = partial + STATS_BLOCKS * 192;
    float* shiftA  = scaleA + 96;
    float* scaleB  = shiftA + 96;
    float* shiftB  = scaleB + 16;
    float* pooled  = shiftB + 16;                // NG*96

    const float invN = 1.0f / (float)NN;

    // ---- edge sort (shared by all layers) ----
    hipMemsetAsync(counts, 0, (NN + NG) * sizeof(int), stream);
    hist_edges<<<(ET + 255) / 256, 256, 0, stream>>>(ei, counts);
    hist_batch<<<(NN + 255) / 256, 256, 0, stream>>>(bat, gcounts);
    scan_reduce<<<SCAN_NB, 256, 0, stream>>>(counts, bsum);
    scan_bsums<<<1, 128, 0, stream>>>(bsum, SCAN_NB, boff, &offsets[NN]);
    scan_final<<<SCAN_NB, SCAN_B, 0, stream>>>(counts, boff, offsets, cursor);
    scan_small<<<1, 1024, 0, stream>>>(gcounts, NG, goff);
    scatter_edges<<<(ET + 255) / 256, 256, 0, stream>>>(ei, cursor, srcs);

    // ---- layer 1 ----
    gemm1<<<(NN + 31) / 32, 256, 0, stream>>>(x, W1, Hb);
    scores_kernel<<<(NN * 8 + 255) / 256, 256, 0, stream>>>(Hb, a1s, a1d, SSb, SDb, 8, 8);
    gat_kernel<8, 8, 1><<<(NN + 3) / 4, 256, 0, stream>>>(Hb, SSb, SDb, offsets, srcs, b1, GOb);
    stats_kernel<<<STATS_BLOCKS, 256, 2 * 256 * sizeof(float), stream>>>(GOb, NN, 64, partial);
    bn_finalize<<<1, 128, 0, stream>>>(partial, STATS_BLOCKS, 64, invN, g1, be1, scaleA, shiftA);
    bnrelu_linear<8><<<(NN + 63) / 64, 256, 0, stream>>>(GOb, scaleA, shiftA, lW1, lb1, Ub);
    stats_kernel<<<STATS_BLOCKS, 256, 2 * 256 * sizeof(float), stream>>>(Ub, NN, 8, partial);
    bn_finalize<<<1, 128, 0, stream>>>(partial, STATS_BLOCKS, 8, invN, gl1, bel1, scaleB, shiftB);

    // ---- layer 2 ----
    bnrelu_gemm<8, 64><<<(NN + 63) / 64, 256, 0, stream>>>(Ub, scaleB, shiftB, W2, Hb);
    scores_kernel<<<(NN * 4 + 255) / 256, 256, 0, stream>>>(Hb, a2s, a2d, SSb, SDb, 4, 16);
    gat_kernel<4, 16, 1><<<(NN + 3) / 4, 256, 0, stream>>>(Hb, SSb, SDb, offsets, srcs, b2, GOb);
    stats_kernel<<<STATS_BLOCKS, 256, 2 * 256 * sizeof(float), stream>>>(GOb, NN, 64, partial);
    bn_finalize<<<1, 128, 0, stream>>>(partial, STATS_BLOCKS, 64, invN, g2, be2, scaleA, shiftA);
    bnrelu_linear<16><<<(NN + 63) / 64, 256, 0, stream>>>(GOb, scaleA, shiftA, lW2, lb2, Ub);
    stats_kernel<<<STATS_BLOCKS, 256, 2 * 256 * sizeof(float), stream>>>(Ub, NN, 16, partial);
    bn_finalize<<<1, 128, 0, stream>>>(partial, STATS_BLOCKS, 16, invN, gl2, bel2, scaleB, shiftB);

    // ---- layer 3 ----
    bnrelu_gemm<16, 96><<<(NN + 63) / 64, 256, 0, stream>>>(Ub, scaleB, shiftB, W3, Hb);
    scores_kernel<<<(NN * 4 + 255) / 256, 256, 0, stream>>>(Hb, a3s, a3d, SSb, SDb, 4, 24);
    gat_kernel<4, 24, 2><<<(NN + 3) / 4, 256, 0, stream>>>(Hb, SSb, SDb, offsets, srcs, b3, GOb);
    stats_kernel<<<STATS_BLOCKS, 192, 2 * 192 * sizeof(float), stream>>>(GOb, NN, 96, partial);
    bn_finalize<<<1, 128, 0, stream>>>(partial, STATS_BLOCKS, 96, invN, g3, be3, scaleA, shiftA);

    // ---- pool + head ----
    pool_kernel<<<NG, 128, 0, stream>>>(GOb, scaleA, shiftA, goff, pooled);
    final_gemm<<<(NG * 10 + 255) / 256, 256, 0, stream>>>(pooled, oW, ob, out);
}

// Round 3
// 1181.363 us; speedup vs baseline: 1.4346x; 1.1330x over previous
//
#include <hip/hip_runtime.h>
#include <hip/hip_fp16.h>
#include <math.h>

#define NN 100000
#define NE 1600000
#define ET (NE + NN)      // edges + self loops
#define NG 512
#define STATS_BLOCKS 240
#define SCAN_B 1024
#define SCAN_NB ((NN + SCAN_B - 1) / SCAN_B)   // 98

// ---------------- edge sort (counting sort by dst) ----------------

__global__ void hist_edges(const int* __restrict__ ei, int* __restrict__ counts) {
    int e = blockIdx.x * blockDim.x + threadIdx.x;
    if (e >= ET) return;
    int d = (e < NE) ? ei[NE + e] : (e - NE);
    atomicAdd(&counts[d], 1);
}

__global__ void hist_batch(const int* __restrict__ batch, int* __restrict__ gcounts) {
    int n = blockIdx.x * blockDim.x + threadIdx.x;
    if (n >= NN) return;
    atomicAdd(&gcounts[batch[n]], 1);
}

// multi-block exclusive scan: phase A (per-block reduce)
__global__ void scan_reduce(const int* __restrict__ in, int* __restrict__ bsum) {
    __shared__ int lds[256];
    int b = blockIdx.x, t = threadIdx.x;
    int s = 0;
    for (int i = t; i < SCAN_B; i += 256) {
        int idx = b * SCAN_B + i;
        if (idx < NN) s += in[idx];
    }
    lds[t] = s;
    __syncthreads();
    for (int off = 128; off > 0; off >>= 1) {
        if (t < off) lds[t] += lds[t + off];
        __syncthreads();
    }
    if (t == 0) bsum[b] = lds[0];
}

// phase B: single block scans block sums (nb <= 128)
__global__ void scan_bsums(const int* __restrict__ bsum, int nb, int* __restrict__ boff,
                           int* __restrict__ total_loc) {
    __shared__ int lds[128];
    int t = threadIdx.x;
    int v = (t < nb) ? bsum[t] : 0;
    lds[t] = v;
    __syncthreads();
    for (int off = 1; off < 128; off <<= 1) {
        int x = (t >= off) ? lds[t - off] : 0;
        __syncthreads();
        lds[t] += x;
        __syncthreads();
    }
    if (t < nb) boff[t] = lds[t] - v;
    if (t == nb - 1) {
        boff[nb] = lds[t];
        if (total_loc) *total_loc = lds[t];
    }
}

// phase C: per-block scan + base add
__global__ void scan_final(const int* __restrict__ in, const int* __restrict__ boff,
                           int* __restrict__ out, int* __restrict__ cursor) {
    __shared__ int lds[SCAN_B];
    int b = blockIdx.x, t = threadIdx.x;
    int idx = b * SCAN_B + t;
    int v = (idx < NN) ? in[idx] : 0;
    lds[t] = v;
    __syncthreads();
    for (int off = 1; off < SCAN_B; off <<= 1) {
        int x = (t >= off) ? lds[t - off] : 0;
        __syncthreads();
        lds[t] += x;
        __syncthreads();
    }
    if (idx < NN) {
        int ex = boff[b] + lds[t] - v;
        out[idx] = ex;
        cursor[idx] = ex;
    }
}

// small single-block scan for graph offsets (NG=512)
__global__ void scan_small(const int* __restrict__ in, int n, int* __restrict__ out) {
    __shared__ int lds[1024];
    int t = threadIdx.x;
    int v = (t < n) ? in[t] : 0;
    lds[t] = v;
    __syncthreads();
    for (int off = 1; off < 1024; off <<= 1) {
        int x = (t >= off) ? lds[t - off] : 0;
        __syncthreads();
        lds[t] += x;
        __syncthreads();
    }
    if (t < n) out[t] = lds[t] - v;
    if (t == n - 1) out[n] = lds[t];
}

__global__ void scatter_edges(const int* __restrict__ ei, int* __restrict__ cursor,
                              int* __restrict__ srcs) {
    int e = blockIdx.x * blockDim.x + threadIdx.x;
    if (e >= ET) return;
    int s, d;
    if (e < NE) { s = ei[e]; d = ei[NE + e]; }
    else        { s = d = e - NE; }
    int pos = atomicAdd(&cursor[d], 1);
    srcs[pos] = s;
}

// ---------------- gemm1: Hh = fp16( X(N,128) @ W(128,64) ) ----------------

__global__ __launch_bounds__(256) void gemm1(const float* __restrict__ X,
                                             const float* __restrict__ W,
                                             __half* __restrict__ Hh) {
    __shared__ float wl[128 * 64];      // 32 KB
    __shared__ float xl[32 * 132];      // padded, ~16.9 KB
    int t = threadIdx.x;
    int n0 = blockIdx.x * 32;
    for (int i = t * 4; i < 128 * 64; i += 1024)
        *(float4*)&wl[i] = *(const float4*)&W[i];
    for (int i = t * 4; i < 32 * 128; i += 1024) {
        int r = i >> 7, c = i & 127;
        int n = n0 + r;
        float4 v = (n < NN) ? *(const float4*)&X[(size_t)n * 128 + c] : make_float4(0, 0, 0, 0);
        *(float4*)&xl[r * 132 + c] = v;
    }
    __syncthreads();
    int cg = (t & 15) * 4;
    int ng = (t >> 4) * 2;
    float acc[2][4] = {};
    for (int k = 0; k < 128; ++k) {
        float4 w4 = *(float4*)&wl[k * 64 + cg];
        #pragma unroll
        for (int j = 0; j < 2; ++j) {
            float xv = xl[(ng + j) * 132 + k];
            acc[j][0] += xv * w4.x; acc[j][1] += xv * w4.y;
            acc[j][2] += xv * w4.z; acc[j][3] += xv * w4.w;
        }
    }
    #pragma unroll
    for (int j = 0; j < 2; ++j) {
        int n = n0 + ng + j;
        if (n < NN) {
            __half2 p0 = __floats2half2_rn(acc[j][0], acc[j][1]);
            __half2 p1 = __floats2half2_rn(acc[j][2], acc[j][3]);
            *(__half2*)&Hh[(size_t)n * 64 + cg] = p0;
            *(__half2*)&Hh[(size_t)n * 64 + cg + 2] = p1;
        }
    }
}

// ---------------- per-node attention scores (from fp16 H) ----------------

__global__ void scores_kernel(const __half* __restrict__ Hh, const float* __restrict__ a_s,
                              const float* __restrict__ a_d, float* __restrict__ SS,
                              float* __restrict__ SD, int HEADS, int C) {
    int idx = blockIdx.x * blockDim.x + threadIdx.x;
    if (idx >= NN * HEADS) return;
    int n = idx / HEADS, h = idx % HEADS;
    const __half* row = Hh + (size_t)n * HEADS * C + h * C;
    float s1 = 0.f, s2 = 0.f;
    for (int c = 0; c < C; c += 2) {
        float2 v = __half22float2(*(const __half2*)&row[c]);
        s1 += v.x * a_s[h * C + c] + v.y * a_s[h * C + c + 1];
        s2 += v.x * a_d[h * C + c] + v.y * a_d[h * C + c + 1];
    }
    SS[idx] = s1;
    SD[idx] = s2;
}

// ---------------- GAT gather: one wave per dst node, online softmax, 8x unroll ----------------

template <int HEADS, int C, int PL>
__global__ __launch_bounds__(256) void gat_kernel(const __half* __restrict__ Hh,
                                                  const float* __restrict__ SS,
                                                  const float* __restrict__ SD,
                                                  const int* __restrict__ offsets,
                                                  const int* __restrict__ srcs,
                                                  const float* __restrict__ bias,
                                                  float* __restrict__ GO) {
    constexpr int CH = HEADS * C;  // 64 or 96
    int wid = blockIdx.x * (blockDim.x >> 6) + (threadIdx.x >> 6);
    int lane = threadIdx.x & 63;
    if (wid >= NN) return;
    int ch0 = lane * PL;
    bool active = ch0 < CH;
    int ch0l = active ? ch0 : 0;            // clamped for safe junk loads on idle lanes
    int head = active ? (ch0 / C) : 0;
    float sdv = active ? SD[(unsigned)wid * HEADS + head] : 0.f;
    float m = -1e30f, s = 0.f, a0 = 0.f, a1 = 0.f;
    int beg = offsets[wid], end = offsets[wid + 1];
    int e = beg;
    for (; e + 8 <= end; e += 8) {
        int sv[8];
        #pragma unroll
        for (int i = 0; i < 8; ++i) sv[i] = srcs[e + i];
        float cc[8];
        #pragma unroll
        for (int i = 0; i < 8; ++i) {
            float c = SS[(unsigned)(sv[i] * HEADS) + head] + sdv;
            cc[i] = c > 0.f ? c : 0.2f * c;
        }
        float hv0[8], hv1[8];
        #pragma unroll
        for (int i = 0; i < 8; ++i) {
            if (PL == 2) {
                __half2 hp = *(const __half2*)&Hh[(unsigned)(sv[i] * CH) + ch0l];
                hv0[i] = __low2float(hp); hv1[i] = __high2float(hp);
            } else {
                hv0[i] = __half2float(Hh[(unsigned)(sv[i] * CH) + ch0l]);
                hv1[i] = 0.f;
            }
        }
        float m01 = fmaxf(cc[0], cc[1]), m23 = fmaxf(cc[2], cc[3]);
        float m45 = fmaxf(cc[4], cc[5]), m67 = fmaxf(cc[6], cc[7]);
        float mloc = fmaxf(fmaxf(m01, m23), fmaxf(m45, m67));
        mloc = fmaxf(mloc, m);
        float f = __expf(m - mloc);
        float w[8];
        #pragma unroll
        for (int i = 0; i < 8; ++i) w[i] = __expf(cc[i] - mloc);
        float ws = ((w[0] + w[1]) + (w[2] + w[3])) + ((w[4] + w[5]) + (w[6] + w[7]));
        float as0 = ((w[0] * hv0[0] + w[1] * hv0[1]) + (w[2] * hv0[2] + w[3] * hv0[3]))
                  + ((w[4] * hv0[4] + w[5] * hv0[5]) + (w[6] * hv0[6] + w[7] * hv0[7]));
        s = s * f + ws;
        a0 = a0 * f + as0;
        if (PL == 2) {
            float as1 = ((w[0] * hv1[0] + w[1] * hv1[1]) + (w[2] * hv1[2] + w[3] * hv1[3]))
                      + ((w[4] * hv1[4] + w[5] * hv1[5]) + (w[6] * hv1[6] + w[7] * hv1[7]));
            a1 = a1 * f + as1;
        }
        m = mloc;
    }
    for (; e < end; ++e) {
        int src = srcs[e];
        float sc = SS[(unsigned)(src * HEADS) + head] + sdv;
        sc = sc > 0.f ? sc : 0.2f * sc;
        float mn = fmaxf(m, sc);
        float f = __expf(m - mn);
        float w = __expf(sc - mn);
        s = s * f + w;
        float h0, h1 = 0.f;
        if (PL == 2) {
            __half2 hp = *(const __half2*)&Hh[(unsigned)(src * CH) + ch0l];
            h0 = __low2float(hp); h1 = __high2float(hp);
        } else {
            h0 = __half2float(Hh[(unsigned)(src * CH) + ch0l]);
        }
        a0 = a0 * f + w * h0;
        if (PL == 2) a1 = a1 * f + w * h1;
        m = mn;
    }
    if (active) {
        float inv = 1.f / s;
        GO[(unsigned)(wid * CH) + ch0] = a0 * inv + bias[ch0];
        if (PL == 2) GO[(unsigned)(wid * CH) + ch0 + 1] = a1 * inv + bias[ch0 + 1];
    }
}

// ---------------- BN stats (deterministic two-stage) ----------------

__global__ void stats_kernel(const float* __restrict__ X, int Nn, int C,
                             float* __restrict__ partial) {
    int t = threadIdx.x;
    int c = t % C;
    int grp = t / C;
    int G_ = blockDim.x / C;
    float s = 0.f, q = 0.f;
    for (int n = blockIdx.x * G_ + grp; n < Nn; n += gridDim.x * G_) {
        float v = X[(size_t)n * C + c];
        s += v; q += v * v;
    }
    extern __shared__ float lds[];
    lds[t] = s; lds[blockDim.x + t] = q;
    __syncthreads();
    for (int off = blockDim.x >> 1; off >= C; off >>= 1) {
        if (t < off) {
            lds[t] += lds[t + off];
            lds[blockDim.x + t] += lds[blockDim.x + t + off];
        }
        __syncthreads();
    }
    if (t < C) {
        partial[(size_t)blockIdx.x * 2 * C + t] = lds[t];
        partial[(size_t)blockIdx.x * 2 * C + C + t] = lds[blockDim.x + t];
    }
}

__global__ void bn_finalize(const float* __restrict__ partial, int nb, int C, float invN,
                            const float* __restrict__ g, const float* __restrict__ be,
                            float* __restrict__ scale, float* __restrict__ shift) {
    int c = threadIdx.x;
    if (c >= C) return;
    float s = 0.f, q = 0.f;
    for (int b = 0; b < nb; ++b) {
        s += partial[(size_t)b * 2 * C + c];
        q += partial[(size_t)b * 2 * C + C + c];
    }
    float mean = s * invN;
    float var = fmaxf(q * invN - mean * mean, 0.f);
    float rs = rsqrtf(var + 1e-5f);
    float sc = g[c] * rs;
    scale[c] = sc;
    shift[c] = be[c] - mean * sc;
}

// ---------------- relu(bn(X[N,64])) @ Lw(64,KOUT) + lb -> U ----------------

template <int KOUT>
__global__ __launch_bounds__(256) void bnrelu_linear(const float* __restrict__ X,
                                                     const float* __restrict__ scale,
                                                     const float* __restrict__ shift,
                                                     const float* __restrict__ Lw,
                                                     const float* __restrict__ lb,
                                                     float* __restrict__ U) {
    __shared__ float tl[64 * 65];
    int t = threadIdx.x;
    int n0 = blockIdx.x * 64;
    for (int i = t * 4; i < 64 * 64; i += 1024) {
        int r = i >> 6, cc = i & 63;
        int n = n0 + r;
        float4 v = (n < NN) ? *(const float4*)&X[(size_t)n * 64 + cc] : make_float4(0, 0, 0, 0);
        float vv[4] = {v.x, v.y, v.z, v.w};
        #pragma unroll
        for (int j = 0; j < 4; ++j)
            tl[r * 65 + cc + j] = fmaxf(vv[j] * scale[cc + j] + shift[cc + j], 0.f);
    }
    __syncthreads();
    int nl = t & 63;
    int kg = (t >> 6) * (KOUT / 4);
    float acc[KOUT / 4] = {};
    for (int l = 0; l < 64; ++l) {
        float v = tl[nl * 65 + l];
        #pragma unroll
        for (int j = 0; j < KOUT / 4; ++j) acc[j] += v * Lw[l * KOUT + kg + j];
    }
    int n = n0 + nl;
    if (n < NN)
        #pragma unroll
        for (int j = 0; j < KOUT / 4; ++j)
            U[(size_t)n * KOUT + kg + j] = acc[j] + lb[kg + j];
}

// ---------------- relu(bn(U[N,CIN])) @ W(CIN,COUT) -> Hh (fp16) ----------------

template <int CIN, int COUT>
__global__ __launch_bounds__(256) void bnrelu_gemm(const float* __restrict__ U,
                                                   const float* __restrict__ scale,
                                                   const float* __restrict__ shift,
                                                   const float* __restrict__ W,
                                                   __half* __restrict__ Hh) {
    int t = threadIdx.x;
    int nl = t >> 2;
    int q = t & 3;
    int n = blockIdx.x * 64 + nl;
    if (n >= NN) return;
    constexpr int CPT = COUT / 4;
    float v[CIN];
    #pragma unroll
    for (int c = 0; c < CIN; ++c)
        v[c] = fmaxf(U[(size_t)n * CIN + c] * scale[c] + shift[c], 0.f);
    float acc[CPT] = {};
    #pragma unroll
    for (int c = 0; c < CIN; ++c) {
        #pragma unroll
        for (int j = 0; j < CPT; ++j) acc[j] += v[c] * W[c * COUT + q * CPT + j];
    }
    #pragma unroll
    for (int j = 0; j < CPT; j += 2)
        *(__half2*)&Hh[(size_t)n * COUT + q * CPT + j] = __floats2half2_rn(acc[j], acc[j + 1]);
}

// ---------------- mean-pool per graph (batch sorted -> contiguous ranges) ----------------

__global__ void pool_kernel(const float* __restrict__ GO, const float* __restrict__ scale,
                            const float* __restrict__ shift, const int* __restrict__ goff,
                            float* __restrict__ pooled) {
    int g = blockIdx.x;
    int t = threadIdx.x;
    if (t >= 96) return;
    int beg = goff[g], end = goff[g + 1];
    float s = 0.f;
    for (int n = beg; n < end; ++n)
        s += fmaxf(GO[(size_t)n * 96 + t] * scale[t] + shift[t], 0.f);
    float cnt = (float)(end - beg);
    pooled[g * 96 + t] = s / fmaxf(cnt, 1.f);
}

__global__ void final_gemm(const float* __restrict__ pooled, const float* __restrict__ oW,
                           const float* __restrict__ ob, float* __restrict__ out) {
    int idx = blockIdx.x * blockDim.x + threadIdx.x;
    if (idx >= NG * 10) return;
    int g = idx / 10, k = idx % 10;
    float s = ob[k];
    for (int c = 0; c < 96; ++c) s += pooled[g * 96 + c] * oW[c * 10 + k];
    out[idx] = s;
}

// ---------------- launch ----------------

extern "C" void kernel_launch(void* const* d_in, const int* in_sizes, int n_in,
                              void* d_out, int out_size, void* d_ws, size_t ws_size,
                              hipStream_t stream) {
    const float* x   = (const float*)d_in[0];
    const int*   ei  = (const int*)d_in[1];
    const int*   bat = (const int*)d_in[2];
    const float *W1 = (const float*)d_in[3], *a1s = (const float*)d_in[4],
                *a1d = (const float*)d_in[5], *b1 = (const float*)d_in[6],
                *g1 = (const float*)d_in[7], *be1 = (const float*)d_in[8],
                *lW1 = (const float*)d_in[9], *lb1 = (const float*)d_in[10],
                *gl1 = (const float*)d_in[11], *bel1 = (const float*)d_in[12],
                *W2 = (const float*)d_in[13], *a2s = (const float*)d_in[14],
                *a2d = (const float*)d_in[15], *b2 = (const float*)d_in[16],
                *g2 = (const float*)d_in[17], *be2 = (const float*)d_in[18],
                *lW2 = (const float*)d_in[19], *lb2 = (const float*)d_in[20],
                *gl2 = (const float*)d_in[21], *bel2 = (const float*)d_in[22],
                *W3 = (const float*)d_in[23], *a3s = (const float*)d_in[24],
                *a3d = (const float*)d_in[25], *b3 = (const float*)d_in[26],
                *g3 = (const float*)d_in[27], *be3 = (const float*)d_in[28],
                *oW = (const float*)d_in[29], *ob = (const float*)d_in[30];
    float* out = (float*)d_out;

    // workspace layout
    int* iw      = (int*)d_ws;
    int* counts  = iw;                   // NN
    int* gcounts = counts + NN;          // NG
    int* offsets = gcounts + NG;         // NN+1
    int* goff    = offsets + NN + 1;     // NG+1
    int* cursor  = goff + NG + 1;        // NN
    int* bsum    = cursor + NN;          // SCAN_NB
    int* boff    = bsum + SCAN_NB;       // SCAN_NB+1
    int* srcs    = boff + SCAN_NB + 1;   // ET
    float* fw      = (float*)(srcs + ET);
    float* GOb     = fw;                         // NN*96
    float* Ub      = GOb + (size_t)NN * 96;      // NN*16
    float* SSb     = Ub + (size_t)NN * 16;       // NN*8
    float* SDb     = SSb + (size_t)NN * 8;       // NN*8
    float* partial = SDb + (size_t)NN * 8;       // STATS_BLOCKS*192
    float* scaleA  = partial + STATS_BLOCKS * 192;
    float* shiftA  = scaleA + 96;
    float* scaleB  = shiftA + 96;
    float* shiftB  = scaleB + 16;
    float* pooled  = shiftB + 16;                // NG*96
    __half* Hh     = (__half*)(pooled + NG * 96); // NN*96 halves

    const float invN = 1.0f / (float)NN;

    // ---- edge sort (shared by all layers) ----
    hipMemsetAsync(counts, 0, (NN + NG) * sizeof(int), stream);
    hist_edges<<<(ET + 255) / 256, 256, 0, stream>>>(ei, counts);
    hist_batch<<<(NN + 255) / 256, 256, 0, stream>>>(bat, gcounts);
    scan_reduce<<<SCAN_NB, 256, 0, stream>>>(counts, bsum);
    scan_bsums<<<1, 128, 0, stream>>>(bsum, SCAN_NB, boff, &offsets[NN]);
    scan_final<<<SCAN_NB, SCAN_B, 0, stream>>>(counts, boff, offsets, cursor);
    scan_small<<<1, 1024, 0, stream>>>(gcounts, NG, goff);
    scatter_edges<<<(ET + 255) / 256, 256, 0, stream>>>(ei, cursor, srcs);

    // ---- layer 1 ----
    gemm1<<<(NN + 31) / 32, 256, 0, stream>>>(x, W1, Hh);
    scores_kernel<<<(NN * 8 + 255) / 256, 256, 0, stream>>>(Hh, a1s, a1d, SSb, SDb, 8, 8);
    gat_kernel<8, 8, 1><<<(NN + 3) / 4, 256, 0, stream>>>(Hh, SSb, SDb, offsets, srcs, b1, GOb);
    stats_kernel<<<STATS_BLOCKS, 256, 2 * 256 * sizeof(float), stream>>>(GOb, NN, 64, partial);
    bn_finalize<<<1, 128, 0, stream>>>(partial, STATS_BLOCKS, 64, invN, g1, be1, scaleA, shiftA);
    bnrelu_linear<8><<<(NN + 63) / 64, 256, 0, stream>>>(GOb, scaleA, shiftA, lW1, lb1, Ub);
    stats_kernel<<<STATS_BLOCKS, 256, 2 * 256 * sizeof(float), stream>>>(Ub, NN, 8, partial);
    bn_finalize<<<1, 128, 0, stream>>>(partial, STATS_BLOCKS, 8, invN, gl1, bel1, scaleB, shiftB);

    // ---- layer 2 ----
    bnrelu_gemm<8, 64><<<(NN + 63) / 64, 256, 0, stream>>>(Ub, scaleB, shiftB, W2, Hh);
    scores_kernel<<<(NN * 4 + 255) / 256, 256, 0, stream>>>(Hh, a2s, a2d, SSb, SDb, 4, 16);
    gat_kernel<4, 16, 1><<<(NN + 3) / 4, 256, 0, stream>>>(Hh, SSb, SDb, offsets, srcs, b2, GOb);
    stats_kernel<<<STATS_BLOCKS, 256, 2 * 256 * sizeof(float), stream>>>(GOb, NN, 64, partial);
    bn_finalize<<<1, 128, 0, stream>>>(partial, STATS_BLOCKS, 64, invN, g2, be2, scaleA, shiftA);
    bnrelu_linear<16><<<(NN + 63) / 64, 256, 0, stream>>>(GOb, scaleA, shiftA, lW2, lb2, Ub);
    stats_kernel<<<STATS_BLOCKS, 256, 2 * 256 * sizeof(float), stream>>>(Ub, NN, 16, partial);
    bn_finalize<<<1, 128, 0, stream>>>(partial, STATS_BLOCKS, 16, invN, gl2, bel2, scaleB, shiftB);

    // ---- layer 3 ----
    bnrelu_gemm<16, 96><<<(NN + 63) / 64, 256, 0, stream>>>(Ub, scaleB, shiftB, W3, Hh);
    scores_kernel<<<(NN * 4 + 255) / 256, 256, 0, stream>>>(Hh, a3s, a3d, SSb, SDb, 4, 24);
    gat_kernel<4, 24, 2><<<(NN + 3) / 4, 256, 0, stream>>>(Hh, SSb, SDb, offsets, srcs, b3, GOb);
    stats_kernel<<<STATS_BLOCKS, 192, 2 * 192 * sizeof(float), stream>>>(GOb, NN, 96, partial);
    bn_finalize<<<1, 128, 0, stream>>>(partial, STATS_BLOCKS, 96, invN, g3, be3, scaleA, shiftA);

    // ---- pool + head ----
    pool_kernel<<<NG, 128, 0, stream>>>(GOb, scaleA, shiftA, goff, pooled);
    final_gemm<<<(NG * 10 + 255) / 256, 256, 0, stream>>>(pooled, oW, ob, out);
}

// Round 4
// 1018.585 us; speedup vs baseline: 1.6638x; 1.1598x over previous
//
#include <hip/hip_runtime.h>
#include <hip/hip_fp16.h>
#include <math.h>

#define NN 100000
#define NE 1600000
#define ET (NE + NN)      // edges + self loops
#define NG 512
#define STATS_BLOCKS 240
#define SCAN_B 1024
#define SCAN_NB ((NN + SCAN_B - 1) / SCAN_B)   // 98

// bucket sort params
#define BSH 9                      // 512 nodes per bucket
#define NB  ((NN + 511) / 512)     // 196 buckets
#define BCAP 12288                 // cap per bucket (mean ~8700, sigma ~92)
#define CHUNK 4096

// ---------------- pass1: partition edges into coarse buckets ----------------

__global__ __launch_bounds__(256) void part_pass1(const int* __restrict__ ei,
                                                  int* __restrict__ bcur,
                                                  unsigned* __restrict__ pairs) {
    __shared__ unsigned pck[CHUNK];
    __shared__ unsigned ordv[CHUNK];
    __shared__ unsigned char bkt[CHUNK];
    __shared__ unsigned char obkt[CHUNK];
    __shared__ int hist[NB + 1];
    __shared__ int lofs[NB + 1];
    __shared__ int cur[NB + 1];
    __shared__ int gpos[NB];
    __shared__ int lh[256];

    int t = threadIdx.x;
    int base = blockIdx.x * CHUNK;
    for (int i = t; i <= NB; i += 256) hist[i] = 0;
    __syncthreads();
    // load + bin
    for (int i = t; i < CHUNK; i += 256) {
        int e = base + i;
        int b;
        unsigned p = 0;
        if (e < ET) {
            int s, d;
            if (e < NE) { s = ei[e]; d = ei[NE + e]; }
            else        { s = d = e - NE; }
            b = d >> BSH;
            p = ((unsigned)s << BSH) | (unsigned)(d & 511);
        } else b = NB;
        bkt[i] = (unsigned char)b;
        pck[i] = p;
        atomicAdd(&hist[b], 1);
    }
    __syncthreads();
    // exclusive scan of hist[0..NB] (NB+1 = 197 <= 256 threads)
    int v = (t <= NB) ? hist[t] : 0;
    lh[t] = v;
    __syncthreads();
    for (int off = 1; off < 256; off <<= 1) {
        int x = (t >= off) ? lh[t - off] : 0;
        __syncthreads();
        lh[t] += x;
        __syncthreads();
    }
    if (t <= NB) { lofs[t] = lh[t] - v; cur[t] = lh[t] - v; }
    __syncthreads();
    // reserve global space per bucket
    if (t < NB) {
        int h = hist[t];
        gpos[t] = (h > 0) ? atomicAdd(&bcur[t], h) : 0;
    }
    __syncthreads();
    // local ordered scatter (LDS)
    for (int i = t; i < CHUNK; i += 256) {
        int b = bkt[i];
        int pos = atomicAdd(&cur[b], 1);
        ordv[pos] = pck[i];
        obkt[pos] = (unsigned char)b;
    }
    __syncthreads();
    // flush bucket-contiguous runs to global
    int nvalid = lofs[NB];
    for (int i = t; i < nvalid; i += 256) {
        int b = obkt[i];
        int dst = gpos[b] + (i - lofs[b]);
        if (dst < BCAP) pairs[(size_t)b * BCAP + dst] = ordv[i];
    }
}

// ---------------- pass2a: per-bucket node counts (replaces global-atomic hist) ----------------

__global__ __launch_bounds__(256) void bucket_counts(const unsigned* __restrict__ pairs,
                                                     const int* __restrict__ bcur,
                                                     int* __restrict__ counts) {
    __shared__ int lhist[512];
    int b = blockIdx.x;
    int t = threadIdx.x;
    for (int i = t; i < 512; i += 256) lhist[i] = 0;
    __syncthreads();
    int cnt = min(bcur[b], BCAP);
    const unsigned* seg = pairs + (size_t)b * BCAP;
    for (int i = t; i < cnt; i += 256)
        atomicAdd(&lhist[seg[i] & 511], 1);
    __syncthreads();
    int nbase = b << BSH;
    for (int i = t; i < 512; i += 256) {
        int n = nbase + i;
        if (n < NN) counts[n] = lhist[i];
    }
}

// ---------------- pass2b: per-bucket scatter into final srcs ----------------

__global__ __launch_bounds__(256) void bucket_scatter(const unsigned* __restrict__ pairs,
                                                      const int* __restrict__ bcur,
                                                      const int* __restrict__ offsets,
                                                      int* __restrict__ srcs) {
    __shared__ int cur[512];
    int b = blockIdx.x;
    int t = threadIdx.x;
    int nbase = b << BSH;
    for (int i = t; i < 512; i += 256) {
        int n = nbase + i;
        cur[i] = (n < NN) ? offsets[n] : 0;
    }
    __syncthreads();
    int cnt = min(bcur[b], BCAP);
    const unsigned* seg = pairs + (size_t)b * BCAP;
    for (int i = t; i < cnt; i += 256) {
        unsigned p = seg[i];
        int pos = atomicAdd(&cur[p & 511], 1);
        srcs[pos] = (int)(p >> BSH);
    }
}

// ---------------- batch histogram ----------------

__global__ void hist_batch(const int* __restrict__ batch, int* __restrict__ gcounts) {
    int n = blockIdx.x * blockDim.x + threadIdx.x;
    if (n >= NN) return;
    atomicAdd(&gcounts[batch[n]], 1);
}

// multi-block exclusive scan: phase A (per-block reduce)
__global__ void scan_reduce(const int* __restrict__ in, int* __restrict__ bsum) {
    __shared__ int lds[256];
    int b = blockIdx.x, t = threadIdx.x;
    int s = 0;
    for (int i = t; i < SCAN_B; i += 256) {
        int idx = b * SCAN_B + i;
        if (idx < NN) s += in[idx];
    }
    lds[t] = s;
    __syncthreads();
    for (int off = 128; off > 0; off >>= 1) {
        if (t < off) lds[t] += lds[t + off];
        __syncthreads();
    }
    if (t == 0) bsum[b] = lds[0];
}

// phase B: single block scans block sums (nb <= 128)
__global__ void scan_bsums(const int* __restrict__ bsum, int nb, int* __restrict__ boff,
                           int* __restrict__ total_loc) {
    __shared__ int lds[128];
    int t = threadIdx.x;
    int v = (t < nb) ? bsum[t] : 0;
    lds[t] = v;
    __syncthreads();
    for (int off = 1; off < 128; off <<= 1) {
        int x = (t >= off) ? lds[t - off] : 0;
        __syncthreads();
        lds[t] += x;
        __syncthreads();
    }
    if (t < nb) boff[t] = lds[t] - v;
    if (t == nb - 1) {
        boff[nb] = lds[t];
        if (total_loc) *total_loc = lds[t];
    }
}

// phase C: per-block scan + base add
__global__ void scan_final(const int* __restrict__ in, const int* __restrict__ boff,
                           int* __restrict__ out) {
    __shared__ int lds[SCAN_B];
    int b = blockIdx.x, t = threadIdx.x;
    int idx = b * SCAN_B + t;
    int v = (idx < NN) ? in[idx] : 0;
    lds[t] = v;
    __syncthreads();
    for (int off = 1; off < SCAN_B; off <<= 1) {
        int x = (t >= off) ? lds[t - off] : 0;
        __syncthreads();
        lds[t] += x;
        __syncthreads();
    }
    if (idx < NN) out[idx] = boff[b] + lds[t] - v;
}

// small single-block scan for graph offsets (NG=512)
__global__ void scan_small(const int* __restrict__ in, int n, int* __restrict__ out) {
    __shared__ int lds[1024];
    int t = threadIdx.x;
    int v = (t < n) ? in[t] : 0;
    lds[t] = v;
    __syncthreads();
    for (int off = 1; off < 1024; off <<= 1) {
        int x = (t >= off) ? lds[t - off] : 0;
        __syncthreads();
        lds[t] += x;
        __syncthreads();
    }
    if (t < n) out[t] = lds[t] - v;
    if (t == n - 1) out[n] = lds[t];
}

// ---------------- gemm1: Hh = fp16( X(N,128) @ W(128,64) ) ----------------

__global__ __launch_bounds__(256) void gemm1(const float* __restrict__ X,
                                             const float* __restrict__ W,
                                             __half* __restrict__ Hh) {
    __shared__ float wl[128 * 64];      // 32 KB
    __shared__ float xl[32 * 132];      // padded, ~16.9 KB
    int t = threadIdx.x;
    int n0 = blockIdx.x * 32;
    for (int i = t * 4; i < 128 * 64; i += 1024)
        *(float4*)&wl[i] = *(const float4*)&W[i];
    for (int i = t * 4; i < 32 * 128; i += 1024) {
        int r = i >> 7, c = i & 127;
        int n = n0 + r;
        float4 v = (n < NN) ? *(const float4*)&X[(size_t)n * 128 + c] : make_float4(0, 0, 0, 0);
        *(float4*)&xl[r * 132 + c] = v;
    }
    __syncthreads();
    int cg = (t & 15) * 4;
    int ng = (t >> 4) * 2;
    float acc[2][4] = {};
    for (int k = 0; k < 128; ++k) {
        float4 w4 = *(float4*)&wl[k * 64 + cg];
        #pragma unroll
        for (int j = 0; j < 2; ++j) {
            float xv = xl[(ng + j) * 132 + k];
            acc[j][0] += xv * w4.x; acc[j][1] += xv * w4.y;
            acc[j][2] += xv * w4.z; acc[j][3] += xv * w4.w;
        }
    }
    #pragma unroll
    for (int j = 0; j < 2; ++j) {
        int n = n0 + ng + j;
        if (n < NN) {
            __half2 p0 = __floats2half2_rn(acc[j][0], acc[j][1]);
            __half2 p1 = __floats2half2_rn(acc[j][2], acc[j][3]);
            *(__half2*)&Hh[(size_t)n * 64 + cg] = p0;
            *(__half2*)&Hh[(size_t)n * 64 + cg + 2] = p1;
        }
    }
}

// ---------------- per-node attention scores (from fp16 H) ----------------

__global__ void scores_kernel(const __half* __restrict__ Hh, const float* __restrict__ a_s,
                              const float* __restrict__ a_d, float* __restrict__ SS,
                              float* __restrict__ SD, int HEADS, int C) {
    int idx = blockIdx.x * blockDim.x + threadIdx.x;
    if (idx >= NN * HEADS) return;
    int n = idx / HEADS, h = idx % HEADS;
    const __half* row = Hh + (size_t)n * HEADS * C + h * C;
    float s1 = 0.f, s2 = 0.f;
    for (int c = 0; c < C; c += 2) {
        float2 v = __half22float2(*(const __half2*)&row[c]);
        s1 += v.x * a_s[h * C + c] + v.y * a_s[h * C + c + 1];
        s2 += v.x * a_d[h * C + c] + v.y * a_d[h * C + c + 1];
    }
    SS[idx] = s1;
    SD[idx] = s2;
}

// ---------------- GAT gather: one wave per dst node, online softmax, padded 8-groups ----------------

template <int HEADS, int C, int PL>
__global__ __launch_bounds__(256) void gat_kernel(const __half* __restrict__ Hh,
                                                  const float* __restrict__ SS,
                                                  const float* __restrict__ SD,
                                                  const int* __restrict__ offsets,
                                                  const int* __restrict__ srcs,
                                                  const float* __restrict__ bias,
                                                  float* __restrict__ GO) {
    constexpr int CH = HEADS * C;  // 64 or 96
    int wid = blockIdx.x * (blockDim.x >> 6) + (threadIdx.x >> 6);
    int lane = threadIdx.x & 63;
    if (wid >= NN) return;
    int ch0 = lane * PL;
    bool active = ch0 < CH;
    int ch0l = active ? ch0 : 0;            // clamped for safe junk loads on idle lanes
    int head = active ? (ch0 / C) : 0;
    float sdv = active ? SD[(unsigned)wid * HEADS + head] : 0.f;
    float m = -1e30f, s = 0.f, a0 = 0.f, a1 = 0.f;
    int beg = offsets[wid], end = offsets[wid + 1];
    for (int e = beg; e < end; e += 8) {
        int sv[8];
        float cc[8];
        #pragma unroll
        for (int i = 0; i < 8; ++i) {
            int idx = e + i;
            bool val = idx < end;
            sv[i] = srcs[val ? idx : beg];
            float c = SS[(unsigned)(sv[i] * HEADS) + head] + sdv;
            c = c > 0.f ? c : 0.2f * c;
            cc[i] = val ? c : -1e30f;
        }
        float hv0[8], hv1[8];
        #pragma unroll
        for (int i = 0; i < 8; ++i) {
            if (PL == 2) {
                __half2 hp = *(const __half2*)&Hh[(unsigned)(sv[i] * CH) + ch0l];
                hv0[i] = __low2float(hp); hv1[i] = __high2float(hp);
            } else {
                hv0[i] = __half2float(Hh[(unsigned)(sv[i] * CH) + ch0l]);
                hv1[i] = 0.f;
            }
        }
        float m01 = fmaxf(cc[0], cc[1]), m23 = fmaxf(cc[2], cc[3]);
        float m45 = fmaxf(cc[4], cc[5]), m67 = fmaxf(cc[6], cc[7]);
        float mloc = fmaxf(fmaxf(m01, m23), fmaxf(m45, m67));
        mloc = fmaxf(mloc, m);
        float f = __expf(m - mloc);
        float w[8];
        #pragma unroll
        for (int i = 0; i < 8; ++i) w[i] = __expf(cc[i] - mloc);
        float ws = ((w[0] + w[1]) + (w[2] + w[3])) + ((w[4] + w[5]) + (w[6] + w[7]));
        float as0 = ((w[0] * hv0[0] + w[1] * hv0[1]) + (w[2] * hv0[2] + w[3] * hv0[3]))
                  + ((w[4] * hv0[4] + w[5] * hv0[5]) + (w[6] * hv0[6] + w[7] * hv0[7]));
        s = s * f + ws;
        a0 = a0 * f + as0;
        if (PL == 2) {
            float as1 = ((w[0] * hv1[0] + w[1] * hv1[1]) + (w[2] * hv1[2] + w[3] * hv1[3]))
                      + ((w[4] * hv1[4] + w[5] * hv1[5]) + (w[6] * hv1[6] + w[7] * hv1[7]));
            a1 = a1 * f + as1;
        }
        m = mloc;
    }
    if (active) {
        float inv = 1.f / s;
        GO[(unsigned)(wid * CH) + ch0] = a0 * inv + bias[ch0];
        if (PL == 2) GO[(unsigned)(wid * CH) + ch0 + 1] = a1 * inv + bias[ch0 + 1];
    }
}

// ---------------- BN stats (deterministic two-stage) ----------------

__global__ void stats_kernel(const float* __restrict__ X, int Nn, int C,
                             float* __restrict__ partial) {
    int t = threadIdx.x;
    int c = t % C;
    int grp = t / C;
    int G_ = blockDim.x / C;
    float s = 0.f, q = 0.f;
    for (int n = blockIdx.x * G_ + grp; n < Nn; n += gridDim.x * G_) {
        float v = X[(size_t)n * C + c];
        s += v; q += v * v;
    }
    extern __shared__ float lds[];
    lds[t] = s; lds[blockDim.x + t] = q;
    __syncthreads();
    for (int off = blockDim.x >> 1; off >= C; off >>= 1) {
        if (t < off) {
            lds[t] += lds[t + off];
            lds[blockDim.x + t] += lds[blockDim.x + t + off];
        }
        __syncthreads();
    }
    if (t < C) {
        partial[(size_t)blockIdx.x * 2 * C + t] = lds[t];
        partial[(size_t)blockIdx.x * 2 * C + C + t] = lds[blockDim.x + t];
    }
}

__global__ void bn_finalize(const float* __restrict__ partial, int nb, int C, float invN,
                            const float* __restrict__ g, const float* __restrict__ be,
                            float* __restrict__ scale, float* __restrict__ shift) {
    int c = threadIdx.x;
    if (c >= C) return;
    float s = 0.f, q = 0.f;
    for (int b = 0; b < nb; ++b) {
        s += partial[(size_t)b * 2 * C + c];
        q += partial[(size_t)b * 2 * C + C + c];
    }
    float mean = s * invN;
    float var = fmaxf(q * invN - mean * mean, 0.f);
    float rs = rsqrtf(var + 1e-5f);
    float sc = g[c] * rs;
    scale[c] = sc;
    shift[c] = be[c] - mean * sc;
}

// ---------------- relu(bn(X[N,64])) @ Lw(64,KOUT) + lb -> U ----------------

template <int KOUT>
__global__ __launch_bounds__(256) void bnrelu_linear(const float* __restrict__ X,
                                                     const float* __restrict__ scale,
                                                     const float* __restrict__ shift,
                                                     const float* __restrict__ Lw,
                                                     const float* __restrict__ lb,
                                                     float* __restrict__ U) {
    __shared__ float tl[64 * 65];
    int t = threadIdx.x;
    int n0 = blockIdx.x * 64;
    for (int i = t * 4; i < 64 * 64; i += 1024) {
        int r = i >> 6, cc = i & 63;
        int n = n0 + r;
        float4 v = (n < NN) ? *(const float4*)&X[(size_t)n * 64 + cc] : make_float4(0, 0, 0, 0);
        float vv[4] = {v.x, v.y, v.z, v.w};
        #pragma unroll
        for (int j = 0; j < 4; ++j)
            tl[r * 65 + cc + j] = fmaxf(vv[j] * scale[cc + j] + shift[cc + j], 0.f);
    }
    __syncthreads();
    int nl = t & 63;
    int kg = (t >> 6) * (KOUT / 4);
    float acc[KOUT / 4] = {};
    for (int l = 0; l < 64; ++l) {
        float v = tl[nl * 65 + l];
        #pragma unroll
        for (int j = 0; j < KOUT / 4; ++j) acc[j] += v * Lw[l * KOUT + kg + j];
    }
    int n = n0 + nl;
    if (n < NN)
        #pragma unroll
        for (int j = 0; j < KOUT / 4; ++j)
            U[(size_t)n * KOUT + kg + j] = acc[j] + lb[kg + j];
}

// ---------------- relu(bn(U[N,CIN])) @ W(CIN,COUT) -> Hh (fp16) ----------------

template <int CIN, int COUT>
__global__ __launch_bounds__(256) void bnrelu_gemm(const float* __restrict__ U,
                                                   const float* __restrict__ scale,
                                                   const float* __restrict__ shift,
                                                   const float* __restrict__ W,
                                                   __half* __restrict__ Hh) {
    int t = threadIdx.x;
    int nl = t >> 2;
    int q = t & 3;
    int n = blockIdx.x * 64 + nl;
    if (n >= NN) return;
    constexpr int CPT = COUT / 4;
    float v[CIN];
    #pragma unroll
    for (int c = 0; c < CIN; ++c)
        v[c] = fmaxf(U[(size_t)n * CIN + c] * scale[c] + shift[c], 0.f);
    float acc[CPT] = {};
    #pragma unroll
    for (int c = 0; c < CIN; ++c) {
        #pragma unroll
        for (int j = 0; j < CPT; ++j) acc[j] += v[c] * W[c * COUT + q * CPT + j];
    }
    #pragma unroll
    for (int j = 0; j < CPT; j += 2)
        *(__half2*)&Hh[(size_t)n * COUT + q * CPT + j] = __floats2half2_rn(acc[j], acc[j + 1]);
}

// ---------------- mean-pool per graph (batch sorted -> contiguous ranges) ----------------

__global__ void pool_kernel(const float* __restrict__ GO, const float* __restrict__ scale,
                            const float* __restrict__ shift, const int* __restrict__ goff,
                            float* __restrict__ pooled) {
    int g = blockIdx.x;
    int t = threadIdx.x;
    if (t >= 96) return;
    int beg = goff[g], end = goff[g + 1];
    float s = 0.f;
    for (int n = beg; n < end; ++n)
        s += fmaxf(GO[(size_t)n * 96 + t] * scale[t] + shift[t], 0.f);
    float cnt = (float)(end - beg);
    pooled[g * 96 + t] = s / fmaxf(cnt, 1.f);
}

__global__ void final_gemm(const float* __restrict__ pooled, const float* __restrict__ oW,
                           const float* __restrict__ ob, float* __restrict__ out) {
    int idx = blockIdx.x * blockDim.x + threadIdx.x;
    if (idx >= NG * 10) return;
    int g = idx / 10, k = idx % 10;
    float s = ob[k];
    for (int c = 0; c < 96; ++c) s += pooled[g * 96 + c] * oW[c * 10 + k];
    out[idx] = s;
}

// ---------------- launch ----------------

extern "C" void kernel_launch(void* const* d_in, const int* in_sizes, int n_in,
                              void* d_out, int out_size, void* d_ws, size_t ws_size,
                              hipStream_t stream) {
    const float* x   = (const float*)d_in[0];
    const int*   ei  = (const int*)d_in[1];
    const int*   bat = (const int*)d_in[2];
    const float *W1 = (const float*)d_in[3], *a1s = (const float*)d_in[4],
                *a1d = (const float*)d_in[5], *b1 = (const float*)d_in[6],
                *g1 = (const float*)d_in[7], *be1 = (const float*)d_in[8],
                *lW1 = (const float*)d_in[9], *lb1 = (const float*)d_in[10],
                *gl1 = (const float*)d_in[11], *bel1 = (const float*)d_in[12],
                *W2 = (const float*)d_in[13], *a2s = (const float*)d_in[14],
                *a2d = (const float*)d_in[15], *b2 = (const float*)d_in[16],
                *g2 = (const float*)d_in[17], *be2 = (const float*)d_in[18],
                *lW2 = (const float*)d_in[19], *lb2 = (const float*)d_in[20],
                *gl2 = (const float*)d_in[21], *bel2 = (const float*)d_in[22],
                *W3 = (const float*)d_in[23], *a3s = (const float*)d_in[24],
                *a3d = (const float*)d_in[25], *b3 = (const float*)d_in[26],
                *g3 = (const float*)d_in[27], *be3 = (const float*)d_in[28],
                *oW = (const float*)d_in[29], *ob = (const float*)d_in[30];
    float* out = (float*)d_out;

    // workspace layout
    int* iw      = (int*)d_ws;
    int* gcounts = iw;                   // NG       (memset together with bcur)
    int* bcur    = gcounts + NG;         // NB
    int* counts  = bcur + NB;            // NN       (fully overwritten by bucket_counts)
    int* offsets = counts + NN;          // NN+1
    int* goff    = offsets + NN + 1;     // NG+1
    int* bsum    = goff + NG + 1;        // SCAN_NB
    int* boff    = bsum + SCAN_NB;       // SCAN_NB+1
    int* srcs    = boff + SCAN_NB + 1;   // ET
    float* fw      = (float*)(srcs + ET);
    float* GOb     = fw;                         // NN*96
    float* Ub      = GOb + (size_t)NN * 96;      // NN*16
    float* SSb     = Ub + (size_t)NN * 16;       // NN*8
    float* SDb     = SSb + (size_t)NN * 8;       // NN*8
    float* partial = SDb + (size_t)NN * 8;       // STATS_BLOCKS*192
    float* scaleA  = partial + STATS_BLOCKS * 192;
    float* shiftA  = scaleA + 96;
    float* scaleB  = shiftA + 96;
    float* shiftB  = scaleB + 16;
    float* pooled  = shiftB + 16;                // NG*96
    __half* Hh     = (__half*)(pooled + NG * 96); // NN*96 halves
    // pairs buffer aliases GOb (preprocessing finishes before layer 1 writes GOb)
    unsigned* pairs = (unsigned*)GOb;            // NB*BCAP u32 (~9.6MB < 38.4MB)

    const float invN = 1.0f / (float)NN;

    // ---- edge bucket sort (shared by all layers) ----
    hipMemsetAsync(gcounts, 0, (NG + NB) * sizeof(int), stream);
    part_pass1<<<(ET + CHUNK - 1) / CHUNK, 256, 0, stream>>>(ei, bcur, pairs);
    hist_batch<<<(NN + 255) / 256, 256, 0, stream>>>(bat, gcounts);
    bucket_counts<<<NB, 256, 0, stream>>>(pairs, bcur, counts);
    scan_reduce<<<SCAN_NB, 256, 0, stream>>>(counts, bsum);
    scan_bsums<<<1, 128, 0, stream>>>(bsum, SCAN_NB, boff, &offsets[NN]);
    scan_final<<<SCAN_NB, SCAN_B, 0, stream>>>(counts, boff, offsets);
    scan_small<<<1, 1024, 0, stream>>>(gcounts, NG, goff);
    bucket_scatter<<<NB, 256, 0, stream>>>(pairs, bcur, offsets, srcs);

    // ---- layer 1 ----
    gemm1<<<(NN + 31) / 32, 256, 0, stream>>>(x, W1, Hh);
    scores_kernel<<<(NN * 8 + 255) / 256, 256, 0, stream>>>(Hh, a1s, a1d, SSb, SDb, 8, 8);
    gat_kernel<8, 8, 1><<<(NN + 3) / 4, 256, 0, stream>>>(Hh, SSb, SDb, offsets, srcs, b1, GOb);
    stats_kernel<<<STATS_BLOCKS, 256, 2 * 256 * sizeof(float), stream>>>(GOb, NN, 64, partial);
    bn_finalize<<<1, 128, 0, stream>>>(partial, STATS_BLOCKS, 64, invN, g1, be1, scaleA, shiftA);
    bnrelu_linear<8><<<(NN + 63) / 64, 256, 0, stream>>>(GOb, scaleA, shiftA, lW1, lb1, Ub);
    stats_kernel<<<STATS_BLOCKS, 256, 2 * 256 * sizeof(float), stream>>>(Ub, NN, 8, partial);
    bn_finalize<<<1, 128, 0, stream>>>(partial, STATS_BLOCKS, 8, invN, gl1, bel1, scaleB, shiftB);

    // ---- layer 2 ----
    bnrelu_gemm<8, 64><<<(NN + 63) / 64, 256, 0, stream>>>(Ub, scaleB, shiftB, W2, Hh);
    scores_kernel<<<(NN * 4 + 255) / 256, 256, 0, stream>>>(Hh, a2s, a2d, SSb, SDb, 4, 16);
    gat_kernel<4, 16, 1><<<(NN + 3) / 4, 256, 0, stream>>>(Hh, SSb, SDb, offsets, srcs, b2, GOb);
    stats_kernel<<<STATS_BLOCKS, 256, 2 * 256 * sizeof(float), stream>>>(GOb, NN, 64, partial);
    bn_finalize<<<1, 128, 0, stream>>>(partial, STATS_BLOCKS, 64, invN, g2, be2, scaleA, shiftA);
    bnrelu_linear<16><<<(NN + 63) / 64, 256, 0, stream>>>(GOb, scaleA, shiftA, lW2, lb2, Ub);
    stats_kernel<<<STATS_BLOCKS, 256, 2 * 256 * sizeof(float), stream>>>(Ub, NN, 16, partial);
    bn_finalize<<<1, 128, 0, stream>>>(partial, STATS_BLOCKS, 16, invN, gl2, bel2, scaleB, shiftB);

    // ---- layer 3 ----
    bnrelu_gemm<16, 96><<<(NN + 63) / 64, 256, 0, stream>>>(Ub, scaleB, shiftB, W3, Hh);
    scores_kernel<<<(NN * 4 + 255) / 256, 256, 0, stream>>>(Hh, a3s, a3d, SSb, SDb, 4, 24);
    gat_kernel<4, 24, 2><<<(NN + 3) / 4, 256, 0, stream>>>(Hh, SSb, SDb, offsets, srcs, b3, GOb);
    stats_kernel<<<STATS_BLOCKS, 192, 2 * 192 * sizeof(float), stream>>>(GOb, NN, 96, partial);
    bn_finalize<<<1, 128, 0, stream>>>(partial, STATS_BLOCKS, 96, invN, g3, be3, scaleA, shiftA);

    // ---- pool + head ----
    pool_kernel<<<NG, 128, 0, stream>>>(GOb, scaleA, shiftA, goff, pooled);
    final_gemm<<<(NG * 10 + 255) / 256, 256, 0, stream>>>(pooled, oW, ob, out);
}

// Round 6
// 834.598 us; speedup vs baseline: 2.0306x; 1.2204x over previous
//
#include <hip/hip_runtime.h>
#include <hip/hip_fp16.h>
#include <math.h>

#define NN 100000
#define NE 1600000
#define ET (NE + NN)      // edges + self loops
#define NG 512
#define STATS_BLOCKS 240
#define SCAN_B 1024
#define SCAN_NB ((NN + SCAN_B - 1) / SCAN_B)   // 98
#define PSLOTS (ET + 7 * NN)                   // padded edge-slot capacity (2.4M)

// bucket sort params
#define BSH 9                      // 512 nodes per bucket
#define NB  ((NN + 511) / 512)     // 196 buckets
#define BCAP 12288                 // cap per bucket (mean ~8700)
#define CHUNK 4096

// ---------------- pass1: partition edges into coarse buckets ----------------

__global__ __launch_bounds__(256) void part_pass1(const int* __restrict__ ei,
                                                  int* __restrict__ bcur,
                                                  unsigned* __restrict__ pairs) {
    __shared__ unsigned pck[CHUNK];
    __shared__ unsigned ordv[CHUNK];
    __shared__ unsigned char bkt[CHUNK];
    __shared__ unsigned char obkt[CHUNK];
    __shared__ int hist[NB + 1];
    __shared__ int lofs[NB + 1];
    __shared__ int cur[NB + 1];
    __shared__ int gpos[NB];
    __shared__ int lh[256];

    int t = threadIdx.x;
    int base = blockIdx.x * CHUNK;
    for (int i = t; i <= NB; i += 256) hist[i] = 0;
    __syncthreads();
    for (int i = t; i < CHUNK; i += 256) {
        int e = base + i;
        int b;
        unsigned p = 0;
        if (e < ET) {
            int s, d;
            if (e < NE) { s = ei[e]; d = ei[NE + e]; }
            else        { s = d = e - NE; }
            b = d >> BSH;
            p = ((unsigned)s << BSH) | (unsigned)(d & 511);
        } else b = NB;
        bkt[i] = (unsigned char)b;
        pck[i] = p;
        atomicAdd(&hist[b], 1);
    }
    __syncthreads();
    int v = (t <= NB) ? hist[t] : 0;
    lh[t] = v;
    __syncthreads();
    for (int off = 1; off < 256; off <<= 1) {
        int x = (t >= off) ? lh[t - off] : 0;
        __syncthreads();
        lh[t] += x;
        __syncthreads();
    }
    if (t <= NB) { lofs[t] = lh[t] - v; cur[t] = lh[t] - v; }
    __syncthreads();
    if (t < NB) {
        int h = hist[t];
        gpos[t] = (h > 0) ? atomicAdd(&bcur[t], h) : 0;
    }
    __syncthreads();
    for (int i = t; i < CHUNK; i += 256) {
        int b = bkt[i];
        int pos = atomicAdd(&cur[b], 1);
        ordv[pos] = pck[i];
        obkt[pos] = (unsigned char)b;
    }
    __syncthreads();
    int nvalid = lofs[NB];
    for (int i = t; i < nvalid; i += 256) {
        int b = obkt[i];
        int dst = gpos[b] + (i - lofs[b]);
        if (dst < BCAP) pairs[(size_t)b * BCAP + dst] = ordv[i];
    }
}

// ---------------- pass2a: per-bucket node counts ----------------

__global__ __launch_bounds__(256) void bucket_counts(const unsigned* __restrict__ pairs,
                                                     const int* __restrict__ bcur,
                                                     int* __restrict__ counts) {
    __shared__ int lhist[512];
    int b = blockIdx.x;
    int t = threadIdx.x;
    for (int i = t; i < 512; i += 256) lhist[i] = 0;
    __syncthreads();
    int cnt = min(bcur[b], BCAP);
    const unsigned* seg = pairs + (size_t)b * BCAP;
    for (int i = t; i < cnt; i += 256)
        atomicAdd(&lhist[seg[i] & 511], 1);
    __syncthreads();
    int nbase = b << BSH;
    for (int i = t; i < 512; i += 256) {
        int n = nbase + i;
        if (n < NN) counts[n] = lhist[i];
    }
}

// ---------------- pass2b: per-bucket scatter into padded srcs ----------------

__global__ __launch_bounds__(256) void bucket_scatter(const unsigned* __restrict__ pairs,
                                                      const int* __restrict__ bcur,
                                                      const int* __restrict__ offsets,
                                                      int* __restrict__ srcs) {
    __shared__ int cur[512];
    int b = blockIdx.x;
    int t = threadIdx.x;
    int nbase = b << BSH;
    for (int i = t; i < 512; i += 256) {
        int n = nbase + i;
        cur[i] = (n < NN) ? offsets[n] : 0;
    }
    __syncthreads();
    int cnt = min(bcur[b], BCAP);
    const unsigned* seg = pairs + (size_t)b * BCAP;
    for (int i = t; i < cnt; i += 256) {
        unsigned p = seg[i];
        int pos = atomicAdd(&cur[p & 511], 1);
        srcs[pos] = (int)(p >> BSH);
    }
}

// ---------------- batch histogram ----------------

__global__ void hist_batch(const int* __restrict__ batch, int* __restrict__ gcounts) {
    int n = blockIdx.x * blockDim.x + threadIdx.x;
    if (n >= NN) return;
    atomicAdd(&gcounts[batch[n]], 1);
}

// ---------------- scans (counts rounded up to x8 inline -> padded offsets) ----------------

__global__ void scan_reduce(const int* __restrict__ in, int* __restrict__ bsum) {
    __shared__ int lds[256];
    int b = blockIdx.x, t = threadIdx.x;
    int s = 0;
    for (int i = t; i < SCAN_B; i += 256) {
        int idx = b * SCAN_B + i;
        if (idx < NN) s += (in[idx] + 7) & ~7;
    }
    lds[t] = s;
    __syncthreads();
    for (int off = 128; off > 0; off >>= 1) {
        if (t < off) lds[t] += lds[t + off];
        __syncthreads();
    }
    if (t == 0) bsum[b] = lds[0];
}

__global__ void scan_bsums(const int* __restrict__ bsum, int nb, int* __restrict__ boff,
                           int* __restrict__ total_loc) {
    __shared__ int lds[128];
    int t = threadIdx.x;
    int v = (t < nb) ? bsum[t] : 0;
    lds[t] = v;
    __syncthreads();
    for (int off = 1; off < 128; off <<= 1) {
        int x = (t >= off) ? lds[t - off] : 0;
        __syncthreads();
        lds[t] += x;
        __syncthreads();
    }
    if (t < nb) boff[t] = lds[t] - v;
    if (t == nb - 1) {
        boff[nb] = lds[t];
        if (total_loc) *total_loc = lds[t];
    }
}

__global__ void scan_final(const int* __restrict__ in, const int* __restrict__ boff,
                           int* __restrict__ out) {
    __shared__ int lds[SCAN_B];
    int b = blockIdx.x, t = threadIdx.x;
    int idx = b * SCAN_B + t;
    int v = (idx < NN) ? ((in[idx] + 7) & ~7) : 0;
    lds[t] = v;
    __syncthreads();
    for (int off = 1; off < SCAN_B; off <<= 1) {
        int x = (t >= off) ? lds[t - off] : 0;
        __syncthreads();
        lds[t] += x;
        __syncthreads();
    }
    if (idx < NN) out[idx] = boff[b] + lds[t] - v;
}

__global__ void scan_small(const int* __restrict__ in, int n, int* __restrict__ out) {
    __shared__ int lds[1024];
    int t = threadIdx.x;
    int v = (t < n) ? in[t] : 0;
    lds[t] = v;
    __syncthreads();
    for (int off = 1; off < 1024; off <<= 1) {
        int x = (t >= off) ? lds[t - off] : 0;
        __syncthreads();
        lds[t] += x;
        __syncthreads();
    }
    if (t < n) out[t] = lds[t] - v;
    if (t == n - 1) out[n] = lds[t];
}

// ---------------- gemm1: Hh = fp16( X(N,128) @ W(128,64) ) ----------------

__global__ __launch_bounds__(256) void gemm1(const float* __restrict__ X,
                                             const float* __restrict__ W,
                                             __half* __restrict__ Hh) {
    __shared__ float wl[128 * 64];
    __shared__ float xl[32 * 132];
    int t = threadIdx.x;
    int n0 = blockIdx.x * 32;
    for (int i = t * 4; i < 128 * 64; i += 1024)
        *(float4*)&wl[i] = *(const float4*)&W[i];
    for (int i = t * 4; i < 32 * 128; i += 1024) {
        int r = i >> 7, c = i & 127;
        int n = n0 + r;
        float4 v = (n < NN) ? *(const float4*)&X[(size_t)n * 128 + c] : make_float4(0, 0, 0, 0);
        *(float4*)&xl[r * 132 + c] = v;
    }
    __syncthreads();
    int cg = (t & 15) * 4;
    int ng = (t >> 4) * 2;
    float acc[2][4] = {};
    for (int k = 0; k < 128; ++k) {
        float4 w4 = *(float4*)&wl[k * 64 + cg];
        #pragma unroll
        for (int j = 0; j < 2; ++j) {
            float xv = xl[(ng + j) * 132 + k];
            acc[j][0] += xv * w4.x; acc[j][1] += xv * w4.y;
            acc[j][2] += xv * w4.z; acc[j][3] += xv * w4.w;
        }
    }
    #pragma unroll
    for (int j = 0; j < 2; ++j) {
        int n = n0 + ng + j;
        if (n < NN) {
            __half2 p0 = __floats2half2_rn(acc[j][0], acc[j][1]);
            __half2 p1 = __floats2half2_rn(acc[j][2], acc[j][3]);
            *(__half2*)&Hh[(size_t)n * 64 + cg] = p0;
            *(__half2*)&Hh[(size_t)n * 64 + cg + 2] = p1;
        }
    }
}

// ---------------- per-node attention scores (from fp16 H) ----------------

__global__ void scores_kernel(const __half* __restrict__ Hh, const float* __restrict__ a_s,
                              const float* __restrict__ a_d, float* __restrict__ SS,
                              float* __restrict__ SD, int HEADS, int C) {
    int idx = blockIdx.x * blockDim.x + threadIdx.x;
    if (idx >= NN * HEADS) return;
    int n = idx / HEADS, h = idx % HEADS;
    const __half* row = Hh + (size_t)n * HEADS * C + h * C;
    float s1 = 0.f, s2 = 0.f;
    for (int c = 0; c < C; c += 2) {
        float2 v = __half22float2(*(const __half2*)&row[c]);
        s1 += v.x * a_s[h * C + c] + v.y * a_s[h * C + c + 1];
        s2 += v.x * a_d[h * C + c] + v.y * a_d[h * C + c + 1];
    }
    SS[idx] = s1;
    SD[idx] = s2;
}

// ---------------- per-(edge,head) softmax numerators, wave per dst node ----------------
// NOTE: SPG=64/H may exceed the 8-slot padding granularity, so the last group of a
// node can reach into the next node's slots — the `slot < end` guard prevents the
// cross-node write race that broke round 5.

template <int H>
__global__ __launch_bounds__(256) void weights_kernel(const float* __restrict__ SS,
                                                      const float* __restrict__ SD,
                                                      const int* __restrict__ offsets,
                                                      const int* __restrict__ counts,
                                                      const int* __restrict__ srcs,
                                                      __half* __restrict__ w) {
    int wid = blockIdx.x * 4 + (threadIdx.x >> 6);
    if (wid >= NN) return;
    int lane = threadIdx.x & 63;
    constexpr int SPG = 64 / H;        // slots per iteration
    int so = lane / H, h = lane % H;
    int beg = offsets[wid], end = offsets[wid + 1];
    int deg = counts[wid];
    float sdv = SD[(unsigned)wid * H + h];
    for (int g = beg; g < end; g += SPG) {
        int slot = g + so;
        if (slot < end) {
            int src = srcs[slot];
            float sc = SS[(unsigned)src * H + h] + sdv;
            sc = sc > 0.f ? sc : 0.2f * sc;
            float wv = (slot - beg) < deg ? __expf(sc) : 0.f;
            w[(unsigned)slot * H + h] = __float2half(wv);
        }
    }
}

// ---------------- GAT gather: pure streaming weighted sum, no masks ----------------

template <int HEADS, int C, int PL>
__global__ __launch_bounds__(256) void gat_kernel(const __half* __restrict__ Hh,
                                                  const __half* __restrict__ w,
                                                  const int* __restrict__ offsets,
                                                  const int* __restrict__ srcs,
                                                  const float* __restrict__ bias,
                                                  float* __restrict__ GO) {
    constexpr int CH = HEADS * C;  // 64 or 96
    int wid = blockIdx.x * (blockDim.x >> 6) + (threadIdx.x >> 6);
    int lane = threadIdx.x & 63;
    if (wid >= NN) return;
    int ch0 = lane * PL;
    bool active = ch0 < CH;
    int ch0l = active ? ch0 : 0;
    int head = active ? (ch0 / C) : 0;
    int beg = offsets[wid], end = offsets[wid + 1];
    const int* sp = srcs + beg;
    const __half* wp = w + (unsigned)beg * HEADS + head;
    float s = 0.f, a0 = 0.f, a1 = 0.f;
    for (int e = beg; e < end; e += 8) {
        int sv[8];
        float wv[8];
        #pragma unroll
        for (int i = 0; i < 8; ++i) {
            sv[i] = sp[i];
            wv[i] = __half2float(wp[i * HEADS]);
        }
        float hv0[8], hv1[8];
        #pragma unroll
        for (int i = 0; i < 8; ++i) {
            if (PL == 2) {
                __half2 hp = *(const __half2*)&Hh[(unsigned)(sv[i] * CH) + ch0l];
                hv0[i] = __low2float(hp); hv1[i] = __high2float(hp);
            } else {
                hv0[i] = __half2float(Hh[(unsigned)(sv[i] * CH) + ch0l]);
                hv1[i] = 0.f;
            }
        }
        float ws = ((wv[0] + wv[1]) + (wv[2] + wv[3])) + ((wv[4] + wv[5]) + (wv[6] + wv[7]));
        float as0 = ((wv[0] * hv0[0] + wv[1] * hv0[1]) + (wv[2] * hv0[2] + wv[3] * hv0[3]))
                  + ((wv[4] * hv0[4] + wv[5] * hv0[5]) + (wv[6] * hv0[6] + wv[7] * hv0[7]));
        s += ws;
        a0 += as0;
        if (PL == 2) {
            float as1 = ((wv[0] * hv1[0] + wv[1] * hv1[1]) + (wv[2] * hv1[2] + wv[3] * hv1[3]))
                      + ((wv[4] * hv1[4] + wv[5] * hv1[5]) + (wv[6] * hv1[6] + wv[7] * hv1[7]));
            a1 += as1;
        }
        sp += 8;
        wp += 8 * HEADS;
    }
    if (active) {
        float inv = 1.f / s;
        GO[(unsigned)(wid * CH) + ch0] = a0 * inv + bias[ch0];
        if (PL == 2) GO[(unsigned)(wid * CH) + ch0 + 1] = a1 * inv + bias[ch0 + 1];
    }
}

// ---------------- BN stats (deterministic two-stage) ----------------

__global__ void stats_kernel(const float* __restrict__ X, int Nn, int C,
                             float* __restrict__ partial) {
    int t = threadIdx.x;
    int c = t % C;
    int grp = t / C;
    int G_ = blockDim.x / C;
    float s = 0.f, q = 0.f;
    for (int n = blockIdx.x * G_ + grp; n < Nn; n += gridDim.x * G_) {
        float v = X[(size_t)n * C + c];
        s += v; q += v * v;
    }
    extern __shared__ float lds[];
    lds[t] = s; lds[blockDim.x + t] = q;
    __syncthreads();
    for (int off = blockDim.x >> 1; off >= C; off >>= 1) {
        if (t < off) {
            lds[t] += lds[t + off];
            lds[blockDim.x + t] += lds[blockDim.x + t + off];
        }
        __syncthreads();
    }
    if (t < C) {
        partial[(size_t)blockIdx.x * 2 * C + t] = lds[t];
        partial[(size_t)blockIdx.x * 2 * C + C + t] = lds[blockDim.x + t];
    }
}

// parallel finalize: blockDim = C * G (G pow2), LDS tree reduce
__global__ void bn_finalize(const float* __restrict__ partial, int nb, int C, float invN,
                            const float* __restrict__ g, const float* __restrict__ be,
                            float* __restrict__ scale, float* __restrict__ shift) {
    extern __shared__ float red[];
    int t = threadIdx.x;
    int c = t % C;
    int grp = t / C;
    int G_ = blockDim.x / C;
    float s = 0.f, q = 0.f;
    for (int b = grp; b < nb; b += G_) {
        s += partial[(size_t)b * 2 * C + c];
        q += partial[(size_t)b * 2 * C + C + c];
    }
    red[t] = s; red[blockDim.x + t] = q;
    __syncthreads();
    for (int off = blockDim.x >> 1; off >= C; off >>= 1) {
        if (t < off) {
            red[t] += red[t + off];
            red[blockDim.x + t] += red[blockDim.x + t + off];
        }
        __syncthreads();
    }
    if (t < C) {
        float mean = red[t] * invN;
        float var = fmaxf(red[blockDim.x + t] * invN - mean * mean, 0.f);
        float rs = rsqrtf(var + 1e-5f);
        float sc = g[t] * rs;
        scale[t] = sc;
        shift[t] = be[t] - mean * sc;
    }
}

// ---------------- relu(bn(X[N,64])) @ Lw(64,KOUT) + lb -> U ----------------

template <int KOUT>
__global__ __launch_bounds__(256) void bnrelu_linear(const float* __restrict__ X,
                                                     const float* __restrict__ scale,
                                                     const float* __restrict__ shift,
                                                     const float* __restrict__ Lw,
                                                     const float* __restrict__ lb,
                                                     float* __restrict__ U) {
    __shared__ float tl[64 * 65];
    int t = threadIdx.x;
    int n0 = blockIdx.x * 64;
    for (int i = t * 4; i < 64 * 64; i += 1024) {
        int r = i >> 6, cc = i & 63;
        int n = n0 + r;
        float4 v = (n < NN) ? *(const float4*)&X[(size_t)n * 64 + cc] : make_float4(0, 0, 0, 0);
        float vv[4] = {v.x, v.y, v.z, v.w};
        #pragma unroll
        for (int j = 0; j < 4; ++j)
            tl[r * 65 + cc + j] = fmaxf(vv[j] * scale[cc + j] + shift[cc + j], 0.f);
    }
    __syncthreads();
    int nl = t & 63;
    int kg = (t >> 6) * (KOUT / 4);
    float acc[KOUT / 4] = {};
    for (int l = 0; l < 64; ++l) {
        float v = tl[nl * 65 + l];
        #pragma unroll
        for (int j = 0; j < KOUT / 4; ++j) acc[j] += v * Lw[l * KOUT + kg + j];
    }
    int n = n0 + nl;
    if (n < NN)
        #pragma unroll
        for (int j = 0; j < KOUT / 4; ++j)
            U[(size_t)n * KOUT + kg + j] = acc[j] + lb[kg + j];
}

// ---------------- relu(bn(U[N,CIN])) @ W(CIN,COUT) -> Hh (fp16) ----------------

template <int CIN, int COUT>
__global__ __launch_bounds__(256) void bnrelu_gemm(const float* __restrict__ U,
                                                   const float* __restrict__ scale,
                                                   const float* __restrict__ shift,
                                                   const float* __restrict__ W,
                                                   __half* __restrict__ Hh) {
    int t = threadIdx.x;
    int nl = t >> 2;
    int q = t & 3;
    int n = blockIdx.x * 64 + nl;
    if (n >= NN) return;
    constexpr int CPT = COUT / 4;
    float v[CIN];
    #pragma unroll
    for (int c = 0; c < CIN; ++c)
        v[c] = fmaxf(U[(size_t)n * CIN + c] * scale[c] + shift[c], 0.f);
    float acc[CPT] = {};
    #pragma unroll
    for (int c = 0; c < CIN; ++c) {
        #pragma unroll
        for (int j = 0; j < CPT; ++j) acc[j] += v[c] * W[c * COUT + q * CPT + j];
    }
    #pragma unroll
    for (int j = 0; j < CPT; j += 2)
        *(__half2*)&Hh[(size_t)n * COUT + q * CPT + j] = __floats2half2_rn(acc[j], acc[j + 1]);
}

// ---------------- mean-pool per graph ----------------

__global__ void pool_kernel(const float* __restrict__ GO, const float* __restrict__ scale,
                            const float* __restrict__ shift, const int* __restrict__ goff,
                            float* __restrict__ pooled) {
    int g = blockIdx.x;
    int t = threadIdx.x;
    if (t >= 96) return;
    int beg = goff[g], end = goff[g + 1];
    float s = 0.f;
    for (int n = beg; n < end; ++n)
        s += fmaxf(GO[(size_t)n * 96 + t] * scale[t] + shift[t], 0.f);
    float cnt = (float)(end - beg);
    pooled[g * 96 + t] = s / fmaxf(cnt, 1.f);
}

__global__ void final_gemm(const float* __restrict__ pooled, const float* __restrict__ oW,
                           const float* __restrict__ ob, float* __restrict__ out) {
    int idx = blockIdx.x * blockDim.x + threadIdx.x;
    if (idx >= NG * 10) return;
    int g = idx / 10, k = idx % 10;
    float s = ob[k];
    for (int c = 0; c < 96; ++c) s += pooled[g * 96 + c] * oW[c * 10 + k];
    out[idx] = s;
}

// ---------------- launch ----------------

extern "C" void kernel_launch(void* const* d_in, const int* in_sizes, int n_in,
                              void* d_out, int out_size, void* d_ws, size_t ws_size,
                              hipStream_t stream) {
    const float* x   = (const float*)d_in[0];
    const int*   ei  = (const int*)d_in[1];
    const int*   bat = (const int*)d_in[2];
    const float *W1 = (const float*)d_in[3], *a1s = (const float*)d_in[4],
                *a1d = (const float*)d_in[5], *b1 = (const float*)d_in[6],
                *g1 = (const float*)d_in[7], *be1 = (const float*)d_in[8],
                *lW1 = (const float*)d_in[9], *lb1 = (const float*)d_in[10],
                *gl1 = (const float*)d_in[11], *bel1 = (const float*)d_in[12],
                *W2 = (const float*)d_in[13], *a2s = (const float*)d_in[14],
                *a2d = (const float*)d_in[15], *b2 = (const float*)d_in[16],
                *g2 = (const float*)d_in[17], *be2 = (const float*)d_in[18],
                *lW2 = (const float*)d_in[19], *lb2 = (const float*)d_in[20],
                *gl2 = (const float*)d_in[21], *bel2 = (const float*)d_in[22],
                *W3 = (const float*)d_in[23], *a3s = (const float*)d_in[24],
                *a3d = (const float*)d_in[25], *b3 = (const float*)d_in[26],
                *g3 = (const float*)d_in[27], *be3 = (const float*)d_in[28],
                *oW = (const float*)d_in[29], *ob = (const float*)d_in[30];
    float* out = (float*)d_out;

    // workspace layout
    int* iw      = (int*)d_ws;
    int* gcounts = iw;                   // NG  (memset with bcur)
    int* bcur    = gcounts + NG;         // NB
    int* counts  = bcur + NB;            // NN
    int* offsets = counts + NN;          // NN+1 (padded offsets)
    int* goff    = offsets + NN + 1;     // NG+1
    int* bsum    = goff + NG + 1;        // SCAN_NB
    int* boff    = bsum + SCAN_NB;       // SCAN_NB+1
    int* srcs    = boff + SCAN_NB + 1;   // PSLOTS
    float* fw      = (float*)(srcs + PSLOTS);
    float* GOb     = fw;                         // NN*96
    float* Ub      = GOb + (size_t)NN * 96;      // NN*16
    float* SSb     = Ub + (size_t)NN * 16;       // NN*8
    float* SDb     = SSb + (size_t)NN * 8;       // NN*8
    float* partial = SDb + (size_t)NN * 8;       // STATS_BLOCKS*192
    float* scaleA  = partial + STATS_BLOCKS * 192;
    float* shiftA  = scaleA + 96;
    float* scaleB  = shiftA + 96;
    float* shiftB  = scaleB + 16;
    float* pooled  = shiftB + 16;                // NG*96
    __half* Hh     = (__half*)(pooled + NG * 96);     // NN*96 halves
    __half* wbuf   = (__half*)(Hh + (size_t)NN * 96); // PSLOTS*8 halves (layer1 max)
    unsigned* pairs = (unsigned*)GOb;            // aliases GOb during preprocessing

    const float invN = 1.0f / (float)NN;

    // ---- edge bucket sort -> padded CSR (shared by all layers) ----
    hipMemsetAsync(gcounts, 0, (NG + NB) * sizeof(int), stream);
    hipMemsetAsync(srcs, 0, (size_t)PSLOTS * sizeof(int), stream);
    part_pass1<<<(ET + CHUNK - 1) / CHUNK, 256, 0, stream>>>(ei, bcur, pairs);
    hist_batch<<<(NN + 255) / 256, 256, 0, stream>>>(bat, gcounts);
    bucket_counts<<<NB, 256, 0, stream>>>(pairs, bcur, counts);
    scan_reduce<<<SCAN_NB, 256, 0, stream>>>(counts, bsum);
    scan_bsums<<<1, 128, 0, stream>>>(bsum, SCAN_NB, boff, &offsets[NN]);
    scan_final<<<SCAN_NB, SCAN_B, 0, stream>>>(counts, boff, offsets);
    scan_small<<<1, 1024, 0, stream>>>(gcounts, NG, goff);
    bucket_scatter<<<NB, 256, 0, stream>>>(pairs, bcur, offsets, srcs);

    // ---- layer 1 ----
    gemm1<<<(NN + 31) / 32, 256, 0, stream>>>(x, W1, Hh);
    scores_kernel<<<(NN * 8 + 255) / 256, 256, 0, stream>>>(Hh, a1s, a1d, SSb, SDb, 8, 8);
    weights_kernel<8><<<(NN + 3) / 4, 256, 0, stream>>>(SSb, SDb, offsets, counts, srcs, wbuf);
    gat_kernel<8, 8, 1><<<(NN + 3) / 4, 256, 0, stream>>>(Hh, wbuf, offsets, srcs, b1, GOb);
    stats_kernel<<<STATS_BLOCKS, 256, 2 * 256 * sizeof(float), stream>>>(GOb, NN, 64, partial);
    bn_finalize<<<1, 512, 2 * 512 * sizeof(float), stream>>>(partial, STATS_BLOCKS, 64, invN, g1, be1, scaleA, shiftA);
    bnrelu_linear<8><<<(NN + 63) / 64, 256, 0, stream>>>(GOb, scaleA, shiftA, lW1, lb1, Ub);
    stats_kernel<<<STATS_BLOCKS, 256, 2 * 256 * sizeof(float), stream>>>(Ub, NN, 8, partial);
    bn_finalize<<<1, 512, 2 * 512 * sizeof(float), stream>>>(partial, STATS_BLOCKS, 8, invN, gl1, bel1, scaleB, shiftB);

    // ---- layer 2 ----
    bnrelu_gemm<8, 64><<<(NN + 63) / 64, 256, 0, stream>>>(Ub, scaleB, shiftB, W2, Hh);
    scores_kernel<<<(NN * 4 + 255) / 256, 256, 0, stream>>>(Hh, a2s, a2d, SSb, SDb, 4, 16);
    weights_kernel<4><<<(NN + 3) / 4, 256, 0, stream>>>(SSb, SDb, offsets, counts, srcs, wbuf);
    gat_kernel<4, 16, 1><<<(NN + 3) / 4, 256, 0, stream>>>(Hh, wbuf, offsets, srcs, b2, GOb);
    stats_kernel<<<STATS_BLOCKS, 256, 2 * 256 * sizeof(float), stream>>>(GOb, NN, 64, partial);
    bn_finalize<<<1, 512, 2 * 512 * sizeof(float), stream>>>(partial, STATS_BLOCKS, 64, invN, g2, be2, scaleA, shiftA);
    bnrelu_linear<16><<<(NN + 63) / 64, 256, 0, stream>>>(GOb, scaleA, shiftA, lW2, lb2, Ub);
    stats_kernel<<<STATS_BLOCKS, 256, 2 * 256 * sizeof(float), stream>>>(Ub, NN, 16, partial);
    bn_finalize<<<1, 512, 2 * 512 * sizeof(float), stream>>>(partial, STATS_BLOCKS, 16, invN, gl2, bel2, scaleB, shiftB);

    // ---- layer 3 ----
    bnrelu_gemm<16, 96><<<(NN + 63) / 64, 256, 0, stream>>>(Ub, scaleB, shiftB, W3, Hh);
    scores_kernel<<<(NN * 4 + 255) / 256, 256, 0, stream>>>(Hh, a3s, a3d, SSb, SDb, 4, 24);
    weights_kernel<4><<<(NN + 3) / 4, 256, 0, stream>>>(SSb, SDb, offsets, counts, srcs, wbuf);
    gat_kernel<4, 24, 2><<<(NN + 3) / 4, 256, 0, stream>>>(Hh, wbuf, offsets, srcs, b3, GOb);
    stats_kernel<<<STATS_BLOCKS, 192, 2 * 192 * sizeof(float), stream>>>(GOb, NN, 96, partial);
    bn_finalize<<<1, 768, 2 * 768 * sizeof(float), stream>>>(partial, STATS_BLOCKS, 96, invN, g3, be3, scaleA, shiftA);

    // ---- pool + head ----
    pool_kernel<<<NG, 128, 0, stream>>>(GOb, scaleA, shiftA, goff, pooled);
    final_gemm<<<(NG * 10 + 255) / 256, 256, 0, stream>>>(pooled, oW, ob, out);
}

// Round 7
// 833.727 us; speedup vs baseline: 2.0327x; 1.0010x over previous
//
#include <hip/hip_runtime.h>
#include <hip/hip_fp16.h>
#include <math.h>

#define NN 100000
#define NE 1600000
#define ET (NE + NN)      // edges + self loops
#define NG 512
#define STATS_BLOCKS 240
#define SCAN_B 1024
#define SCAN_NB ((NN + SCAN_B - 1) / SCAN_B)   // 98
#define PSLOTS (ET + 7 * NN)                   // padded edge-slot capacity (2.4M)

// bucket sort params
#define BSH 9                      // 512 nodes per bucket
#define NB  ((NN + 511) / 512)     // 196 buckets
#define BCAP 12288                 // cap per bucket (mean ~8700)
#define CHUNK 4096

// ---------------- pass1: partition edges into coarse buckets ----------------

__global__ __launch_bounds__(256) void part_pass1(const int* __restrict__ ei,
                                                  int* __restrict__ bcur,
                                                  unsigned* __restrict__ pairs) {
    __shared__ unsigned pck[CHUNK];
    __shared__ unsigned ordv[CHUNK];
    __shared__ unsigned char bkt[CHUNK];
    __shared__ unsigned char obkt[CHUNK];
    __shared__ int hist[NB + 1];
    __shared__ int lofs[NB + 1];
    __shared__ int cur[NB + 1];
    __shared__ int gpos[NB];
    __shared__ int lh[256];

    int t = threadIdx.x;
    int base = blockIdx.x * CHUNK;
    for (int i = t; i <= NB; i += 256) hist[i] = 0;
    __syncthreads();
    for (int i = t; i < CHUNK; i += 256) {
        int e = base + i;
        int b;
        unsigned p = 0;
        if (e < ET) {
            int s, d;
            if (e < NE) { s = ei[e]; d = ei[NE + e]; }
            else        { s = d = e - NE; }
            b = d >> BSH;
            p = ((unsigned)s << BSH) | (unsigned)(d & 511);
        } else b = NB;
        bkt[i] = (unsigned char)b;
        pck[i] = p;
        atomicAdd(&hist[b], 1);
    }
    __syncthreads();
    int v = (t <= NB) ? hist[t] : 0;
    lh[t] = v;
    __syncthreads();
    for (int off = 1; off < 256; off <<= 1) {
        int x = (t >= off) ? lh[t - off] : 0;
        __syncthreads();
        lh[t] += x;
        __syncthreads();
    }
    if (t <= NB) { lofs[t] = lh[t] - v; cur[t] = lh[t] - v; }
    __syncthreads();
    if (t < NB) {
        int h = hist[t];
        gpos[t] = (h > 0) ? atomicAdd(&bcur[t], h) : 0;
    }
    __syncthreads();
    for (int i = t; i < CHUNK; i += 256) {
        int b = bkt[i];
        int pos = atomicAdd(&cur[b], 1);
        ordv[pos] = pck[i];
        obkt[pos] = (unsigned char)b;
    }
    __syncthreads();
    int nvalid = lofs[NB];
    for (int i = t; i < nvalid; i += 256) {
        int b = obkt[i];
        int dst = gpos[b] + (i - lofs[b]);
        if (dst < BCAP) pairs[(size_t)b * BCAP + dst] = ordv[i];
    }
}

// ---------------- pass2a: per-bucket node counts ----------------

__global__ __launch_bounds__(256) void bucket_counts(const unsigned* __restrict__ pairs,
                                                     const int* __restrict__ bcur,
                                                     int* __restrict__ counts) {
    __shared__ int lhist[512];
    int b = blockIdx.x;
    int t = threadIdx.x;
    for (int i = t; i < 512; i += 256) lhist[i] = 0;
    __syncthreads();
    int cnt = min(bcur[b], BCAP);
    const unsigned* seg = pairs + (size_t)b * BCAP;
    for (int i = t; i < cnt; i += 256)
        atomicAdd(&lhist[seg[i] & 511], 1);
    __syncthreads();
    int nbase = b << BSH;
    for (int i = t; i < 512; i += 256) {
        int n = nbase + i;
        if (n < NN) counts[n] = lhist[i];
    }
}

// ---------------- pass2b: per-bucket scatter into padded srcs ----------------

__global__ __launch_bounds__(256) void bucket_scatter(const unsigned* __restrict__ pairs,
                                                      const int* __restrict__ bcur,
                                                      const int* __restrict__ offsets,
                                                      int* __restrict__ srcs) {
    __shared__ int cur[512];
    int b = blockIdx.x;
    int t = threadIdx.x;
    int nbase = b << BSH;
    for (int i = t; i < 512; i += 256) {
        int n = nbase + i;
        cur[i] = (n < NN) ? offsets[n] : 0;
    }
    __syncthreads();
    int cnt = min(bcur[b], BCAP);
    const unsigned* seg = pairs + (size_t)b * BCAP;
    for (int i = t; i < cnt; i += 256) {
        unsigned p = seg[i];
        int pos = atomicAdd(&cur[p & 511], 1);
        srcs[pos] = (int)(p >> BSH);
    }
}

// ---------------- batch histogram ----------------

__global__ void hist_batch(const int* __restrict__ batch, int* __restrict__ gcounts) {
    int n = blockIdx.x * blockDim.x + threadIdx.x;
    if (n >= NN) return;
    atomicAdd(&gcounts[batch[n]], 1);
}

// ---------------- scans (counts rounded up to x8 inline -> padded offsets) ----------------

__global__ void scan_reduce(const int* __restrict__ in, int* __restrict__ bsum) {
    __shared__ int lds[256];
    int b = blockIdx.x, t = threadIdx.x;
    int s = 0;
    for (int i = t; i < SCAN_B; i += 256) {
        int idx = b * SCAN_B + i;
        if (idx < NN) s += (in[idx] + 7) & ~7;
    }
    lds[t] = s;
    __syncthreads();
    for (int off = 128; off > 0; off >>= 1) {
        if (t < off) lds[t] += lds[t + off];
        __syncthreads();
    }
    if (t == 0) bsum[b] = lds[0];
}

__global__ void scan_bsums(const int* __restrict__ bsum, int nb, int* __restrict__ boff,
                           int* __restrict__ total_loc) {
    __shared__ int lds[128];
    int t = threadIdx.x;
    int v = (t < nb) ? bsum[t] : 0;
    lds[t] = v;
    __syncthreads();
    for (int off = 1; off < 128; off <<= 1) {
        int x = (t >= off) ? lds[t - off] : 0;
        __syncthreads();
        lds[t] += x;
        __syncthreads();
    }
    if (t < nb) boff[t] = lds[t] - v;
    if (t == nb - 1) {
        boff[nb] = lds[t];
        if (total_loc) *total_loc = lds[t];
    }
}

__global__ void scan_final(const int* __restrict__ in, const int* __restrict__ boff,
                           int* __restrict__ out) {
    __shared__ int lds[SCAN_B];
    int b = blockIdx.x, t = threadIdx.x;
    int idx = b * SCAN_B + t;
    int v = (idx < NN) ? ((in[idx] + 7) & ~7) : 0;
    lds[t] = v;
    __syncthreads();
    for (int off = 1; off < SCAN_B; off <<= 1) {
        int x = (t >= off) ? lds[t - off] : 0;
        __syncthreads();
        lds[t] += x;
        __syncthreads();
    }
    if (idx < NN) out[idx] = boff[b] + lds[t] - v;
}

__global__ void scan_small(const int* __restrict__ in, int n, int* __restrict__ out) {
    __shared__ int lds[1024];
    int t = threadIdx.x;
    int v = (t < n) ? in[t] : 0;
    lds[t] = v;
    __syncthreads();
    for (int off = 1; off < 1024; off <<= 1) {
        int x = (t >= off) ? lds[t - off] : 0;
        __syncthreads();
        lds[t] += x;
        __syncthreads();
    }
    if (t < n) out[t] = lds[t] - v;
    if (t == n - 1) out[n] = lds[t];
}

// ---------------- gemm1: Hh = fp16( X(N,128) @ W(128,64) ) ----------------

__global__ __launch_bounds__(256) void gemm1(const float* __restrict__ X,
                                             const float* __restrict__ W,
                                             __half* __restrict__ Hh) {
    __shared__ float wl[128 * 64];
    __shared__ float xl[32 * 132];
    int t = threadIdx.x;
    int n0 = blockIdx.x * 32;
    for (int i = t * 4; i < 128 * 64; i += 1024)
        *(float4*)&wl[i] = *(const float4*)&W[i];
    for (int i = t * 4; i < 32 * 128; i += 1024) {
        int r = i >> 7, c = i & 127;
        int n = n0 + r;
        float4 v = (n < NN) ? *(const float4*)&X[(size_t)n * 128 + c] : make_float4(0, 0, 0, 0);
        *(float4*)&xl[r * 132 + c] = v;
    }
    __syncthreads();
    int cg = (t & 15) * 4;
    int ng = (t >> 4) * 2;
    float acc[2][4] = {};
    for (int k = 0; k < 128; ++k) {
        float4 w4 = *(float4*)&wl[k * 64 + cg];
        #pragma unroll
        for (int j = 0; j < 2; ++j) {
            float xv = xl[(ng + j) * 132 + k];
            acc[j][0] += xv * w4.x; acc[j][1] += xv * w4.y;
            acc[j][2] += xv * w4.z; acc[j][3] += xv * w4.w;
        }
    }
    #pragma unroll
    for (int j = 0; j < 2; ++j) {
        int n = n0 + ng + j;
        if (n < NN) {
            __half2 p0 = __floats2half2_rn(acc[j][0], acc[j][1]);
            __half2 p1 = __floats2half2_rn(acc[j][2], acc[j][3]);
            *(__half2*)&Hh[(size_t)n * 64 + cg] = p0;
            *(__half2*)&Hh[(size_t)n * 64 + cg + 2] = p1;
        }
    }
}

// ---------------- per-node attention scores (from fp16 H) ----------------

__global__ void scores_kernel(const __half* __restrict__ Hh, const float* __restrict__ a_s,
                              const float* __restrict__ a_d, float* __restrict__ SS,
                              float* __restrict__ SD, int HEADS, int C) {
    int idx = blockIdx.x * blockDim.x + threadIdx.x;
    if (idx >= NN * HEADS) return;
    int n = idx / HEADS, h = idx % HEADS;
    const __half* row = Hh + (size_t)n * HEADS * C + h * C;
    float s1 = 0.f, s2 = 0.f;
    for (int c = 0; c < C; c += 2) {
        float2 v = __half22float2(*(const __half2*)&row[c]);
        s1 += v.x * a_s[h * C + c] + v.y * a_s[h * C + c + 1];
        s2 += v.x * a_d[h * C + c] + v.y * a_d[h * C + c + 1];
    }
    SS[idx] = s1;
    SD[idx] = s2;
}

// ---------------- per-(edge,head) softmax numerators, wave per dst node ----------------
// NOTE: SPG=64/H may exceed the 8-slot padding granularity, so the last group of a
// node can reach into the next node's slots — the `slot < end` guard prevents the
// cross-node write race that broke round 5.

template <int H>
__global__ __launch_bounds__(256) void weights_kernel(const float* __restrict__ SS,
                                                      const float* __restrict__ SD,
                                                      const int* __restrict__ offsets,
                                                      const int* __restrict__ counts,
                                                      const int* __restrict__ srcs,
                                                      __half* __restrict__ w) {
    int wid = blockIdx.x * 4 + (threadIdx.x >> 6);
    if (wid >= NN) return;
    int lane = threadIdx.x & 63;
    constexpr int SPG = 64 / H;        // slots per iteration
    int so = lane / H, h = lane % H;
    int beg = offsets[wid], end = offsets[wid + 1];
    int deg = counts[wid];
    float sdv = SD[(unsigned)wid * H + h];
    for (int g = beg; g < end; g += SPG) {
        int slot = g + so;
        if (slot < end) {
            int src = srcs[slot];
            float sc = SS[(unsigned)src * H + h] + sdv;
            sc = sc > 0.f ? sc : 0.2f * sc;
            float wv = (slot - beg) < deg ? __expf(sc) : 0.f;
            w[(unsigned)slot * H + h] = __float2half(wv);
        }
    }
}

// ---------------- GAT gather: pure streaming weighted sum, no masks ----------------

template <int HEADS, int C, int PL>
__global__ __launch_bounds__(256) void gat_kernel(const __half* __restrict__ Hh,
                                                  const __half* __restrict__ w,
                                                  const int* __restrict__ offsets,
                                                  const int* __restrict__ srcs,
                                                  const float* __restrict__ bias,
                                                  float* __restrict__ GO) {
    constexpr int CH = HEADS * C;  // 64 or 96
    int wid = blockIdx.x * (blockDim.x >> 6) + (threadIdx.x >> 6);
    int lane = threadIdx.x & 63;
    if (wid >= NN) return;
    int ch0 = lane * PL;
    bool active = ch0 < CH;
    int ch0l = active ? ch0 : 0;
    int head = active ? (ch0 / C) : 0;
    int beg = offsets[wid], end = offsets[wid + 1];
    const int* sp = srcs + beg;
    const __half* wp = w + (unsigned)beg * HEADS + head;
    float s = 0.f, a0 = 0.f, a1 = 0.f;
    for (int e = beg; e < end; e += 8) {
        int sv[8];
        float wv[8];
        #pragma unroll
        for (int i = 0; i < 8; ++i) {
            sv[i] = sp[i];
            wv[i] = __half2float(wp[i * HEADS]);
        }
        float hv0[8], hv1[8];
        #pragma unroll
        for (int i = 0; i < 8; ++i) {
            if (PL == 2) {
                __half2 hp = *(const __half2*)&Hh[(unsigned)(sv[i] * CH) + ch0l];
                hv0[i] = __low2float(hp); hv1[i] = __high2float(hp);
            } else {
                hv0[i] = __half2float(Hh[(unsigned)(sv[i] * CH) + ch0l]);
                hv1[i] = 0.f;
            }
        }
        float ws = ((wv[0] + wv[1]) + (wv[2] + wv[3])) + ((wv[4] + wv[5]) + (wv[6] + wv[7]));
        float as0 = ((wv[0] * hv0[0] + wv[1] * hv0[1]) + (wv[2] * hv0[2] + wv[3] * hv0[3]))
                  + ((wv[4] * hv0[4] + wv[5] * hv0[5]) + (wv[6] * hv0[6] + wv[7] * hv0[7]));
        s += ws;
        a0 += as0;
        if (PL == 2) {
            float as1 = ((wv[0] * hv1[0] + wv[1] * hv1[1]) + (wv[2] * hv1[2] + wv[3] * hv1[3]))
                      + ((wv[4] * hv1[4] + wv[5] * hv1[5]) + (wv[6] * hv1[6] + wv[7] * hv1[7]));
            a1 += as1;
        }
        sp += 8;
        wp += 8 * HEADS;
    }
    if (active) {
        float inv = 1.f / s;
        GO[(unsigned)(wid * CH) + ch0] = a0 * inv + bias[ch0];
        if (PL == 2) GO[(unsigned)(wid * CH) + ch0 + 1] = a1 * inv + bias[ch0 + 1];
    }
}

// ---------------- BN stats (deterministic two-stage) ----------------

__global__ void stats_kernel(const float* __restrict__ X, int Nn, int C,
                             float* __restrict__ partial) {
    int t = threadIdx.x;
    int c = t % C;
    int grp = t / C;
    int G_ = blockDim.x / C;
    float s = 0.f, q = 0.f;
    for (int n = blockIdx.x * G_ + grp; n < Nn; n += gridDim.x * G_) {
        float v = X[(size_t)n * C + c];
        s += v; q += v * v;
    }
    extern __shared__ float lds[];
    lds[t] = s; lds[blockDim.x + t] = q;
    __syncthreads();
    for (int off = blockDim.x >> 1; off >= C; off >>= 1) {
        if (t < off) {
            lds[t] += lds[t + off];
            lds[blockDim.x + t] += lds[blockDim.x + t + off];
        }
        __syncthreads();
    }
    if (t < C) {
        partial[(size_t)blockIdx.x * 2 * C + t] = lds[t];
        partial[(size_t)blockIdx.x * 2 * C + C + t] = lds[blockDim.x + t];
    }
}

// parallel finalize: blockDim = C * G (G pow2), LDS tree reduce
__global__ void bn_finalize(const float* __restrict__ partial, int nb, int C, float invN,
                            const float* __restrict__ g, const float* __restrict__ be,
                            float* __restrict__ scale, float* __restrict__ shift) {
    extern __shared__ float red[];
    int t = threadIdx.x;
    int c = t % C;
    int grp = t / C;
    int G_ = blockDim.x / C;
    float s = 0.f, q = 0.f;
    for (int b = grp; b < nb; b += G_) {
        s += partial[(size_t)b * 2 * C + c];
        q += partial[(size_t)b * 2 * C + C + c];
    }
    red[t] = s; red[blockDim.x + t] = q;
    __syncthreads();
    for (int off = blockDim.x >> 1; off >= C; off >>= 1) {
        if (t < off) {
            red[t] += red[t + off];
            red[blockDim.x + t] += red[blockDim.x + t + off];
        }
        __syncthreads();
    }
    if (t < C) {
        float mean = red[t] * invN;
        float var = fmaxf(red[blockDim.x + t] * invN - mean * mean, 0.f);
        float rs = rsqrtf(var + 1e-5f);
        float sc = g[t] * rs;
        scale[t] = sc;
        shift[t] = be[t] - mean * sc;
    }
}

// ---------------- relu(bn(X[N,64])) @ Lw(64,KOUT) + lb -> U ----------------

template <int KOUT>
__global__ __launch_bounds__(256) void bnrelu_linear(const float* __restrict__ X,
                                                     const float* __restrict__ scale,
                                                     const float* __restrict__ shift,
                                                     const float* __restrict__ Lw,
                                                     const float* __restrict__ lb,
                                                     float* __restrict__ U) {
    __shared__ float tl[64 * 65];
    int t = threadIdx.x;
    int n0 = blockIdx.x * 64;
    for (int i = t * 4; i < 64 * 64; i += 1024) {
        int r = i >> 6, cc = i & 63;
        int n = n0 + r;
        float4 v = (n < NN) ? *(const float4*)&X[(size_t)n * 64 + cc] : make_float4(0, 0, 0, 0);
        float vv[4] = {v.x, v.y, v.z, v.w};
        #pragma unroll
        for (int j = 0; j < 4; ++j)
            tl[r * 65 + cc + j] = fmaxf(vv[j] * scale[cc + j] + shift[cc + j], 0.f);
    }
    __syncthreads();
    int nl = t & 63;
    int kg = (t >> 6) * (KOUT / 4);
    float acc[KOUT / 4] = {};
    for (int l = 0; l < 64; ++l) {
        float v = tl[nl * 65 + l];
        #pragma unroll
        for (int j = 0; j < KOUT / 4; ++j) acc[j] += v * Lw[l * KOUT + kg + j];
    }
    int n = n0 + nl;
    if (n < NN)
        #pragma unroll
        for (int j = 0; j < KOUT / 4; ++j)
            U[(size_t)n * KOUT + kg + j] = acc[j] + lb[kg + j];
}

// ---------------- relu(bn(U[N,CIN])) @ W(CIN,COUT) -> Hh (fp16) ----------------

template <int CIN, int COUT>
__global__ __launch_bounds__(256) void bnrelu_gemm(const float* __restrict__ U,
                                                   const float* __restrict__ scale,
                                                   const float* __restrict__ shift,
                                                   const float* __restrict__ W,
                                                   __half* __restrict__ Hh) {
    int t = threadIdx.x;
    int nl = t >> 2;
    int q = t & 3;
    int n = blockIdx.x * 64 + nl;
    if (n >= NN) return;
    constexpr int CPT = COUT / 4;
    float v[CIN];
    #pragma unroll
    for (int c = 0; c < CIN; ++c)
        v[c] = fmaxf(U[(size_t)n * CIN + c] * scale[c] + shift[c], 0.f);
    float acc[CPT] = {};
    #pragma unroll
    for (int c = 0; c < CIN; ++c) {
        #pragma unroll
        for (int j = 0; j < CPT; ++j) acc[j] += v[c] * W[c * COUT + q * CPT + j];
    }
    #pragma unroll
    for (int j = 0; j < CPT; j += 2)
        *(__half2*)&Hh[(size_t)n * COUT + q * CPT + j] = __floats2half2_rn(acc[j], acc[j + 1]);
}

// ---------------- mean-pool per graph ----------------

__global__ void pool_kernel(const float* __restrict__ GO, const float* __restrict__ scale,
                            const float* __restrict__ shift, const int* __restrict__ goff,
                            float* __restrict__ pooled) {
    int g = blockIdx.x;
    int t = threadIdx.x;
    if (t >= 96) return;
    int beg = goff[g], end = goff[g + 1];
    float s = 0.f;
    for (int n = beg; n < end; ++n)
        s += fmaxf(GO[(size_t)n * 96 + t] * scale[t] + shift[t], 0.f);
    float cnt = (float)(end - beg);
    pooled[g * 96 + t] = s / fmaxf(cnt, 1.f);
}

__global__ void final_gemm(const float* __restrict__ pooled, const float* __restrict__ oW,
                           const float* __restrict__ ob, float* __restrict__ out) {
    int idx = blockIdx.x * blockDim.x + threadIdx.x;
    if (idx >= NG * 10) return;
    int g = idx / 10, k = idx % 10;
    float s = ob[k];
    for (int c = 0; c < 96; ++c) s += pooled[g * 96 + c] * oW[c * 10 + k];
    out[idx] = s;
}

// ---------------- launch ----------------

extern "C" void kernel_launch(void* const* d_in, const int* in_sizes, int n_in,
                              void* d_out, int out_size, void* d_ws, size_t ws_size,
                              hipStream_t stream) {
    const float* x   = (const float*)d_in[0];
    const int*   ei  = (const int*)d_in[1];
    const int*   bat = (const int*)d_in[2];
    const float *W1 = (const float*)d_in[3], *a1s = (const float*)d_in[4],
                *a1d = (const float*)d_in[5], *b1 = (const float*)d_in[6],
                *g1 = (const float*)d_in[7], *be1 = (const float*)d_in[8],
                *lW1 = (const float*)d_in[9], *lb1 = (const float*)d_in[10],
                *gl1 = (const float*)d_in[11], *bel1 = (const float*)d_in[12],
                *W2 = (const float*)d_in[13], *a2s = (const float*)d_in[14],
                *a2d = (const float*)d_in[15], *b2 = (const float*)d_in[16],
                *g2 = (const float*)d_in[17], *be2 = (const float*)d_in[18],
                *lW2 = (const float*)d_in[19], *lb2 = (const float*)d_in[20],
                *gl2 = (const float*)d_in[21], *bel2 = (const float*)d_in[22],
                *W3 = (const float*)d_in[23], *a3s = (const float*)d_in[24],
                *a3d = (const float*)d_in[25], *b3 = (const float*)d_in[26],
                *g3 = (const float*)d_in[27], *be3 = (const float*)d_in[28],
                *oW = (const float*)d_in[29], *ob = (const float*)d_in[30];
    float* out = (float*)d_out;

    // workspace layout
    int* iw      = (int*)d_ws;
    int* gcounts = iw;                   // NG  (memset with bcur)
    int* bcur    = gcounts + NG;         // NB
    int* counts  = bcur + NB;            // NN
    int* offsets = counts + NN;          // NN+1 (padded offsets)
    int* goff    = offsets + NN + 1;     // NG+1
    int* bsum    = goff + NG + 1;        // SCAN_NB
    int* boff    = bsum + SCAN_NB;       // SCAN_NB+1
    int* srcs    = boff + SCAN_NB + 1;   // PSLOTS
    float* fw      = (float*)(srcs + PSLOTS);
    float* GOb     = fw;                         // NN*96
    float* Ub      = GOb + (size_t)NN * 96;      // NN*16
    float* SSb     = Ub + (size_t)NN * 16;       // NN*8
    float* SDb     = SSb + (size_t)NN * 8;       // NN*8
    float* partial = SDb + (size_t)NN * 8;       // STATS_BLOCKS*192
    float* scaleA  = partial + STATS_BLOCKS * 192;
    float* shiftA  = scaleA + 96;
    float* scaleB  = shiftA + 96;
    float* shiftB  = scaleB + 16;
    float* pooled  = shiftB + 16;                // NG*96
    __half* Hh     = (__half*)(pooled + NG * 96);     // NN*96 halves
    __half* wbuf   = (__half*)(Hh + (size_t)NN * 96); // PSLOTS*8 halves (layer1 max)
    unsigned* pairs = (unsigned*)GOb;            // aliases GOb during preprocessing

    const float invN = 1.0f / (float)NN;

    // ---- edge bucket sort -> padded CSR (shared by all layers) ----
    hipMemsetAsync(gcounts, 0, (NG + NB) * sizeof(int), stream);
    hipMemsetAsync(srcs, 0, (size_t)PSLOTS * sizeof(int), stream);
    part_pass1<<<(ET + CHUNK - 1) / CHUNK, 256, 0, stream>>>(ei, bcur, pairs);
    hist_batch<<<(NN + 255) / 256, 256, 0, stream>>>(bat, gcounts);
    bucket_counts<<<NB, 256, 0, stream>>>(pairs, bcur, counts);
    scan_reduce<<<SCAN_NB, 256, 0, stream>>>(counts, bsum);
    scan_bsums<<<1, 128, 0, stream>>>(bsum, SCAN_NB, boff, &offsets[NN]);
    scan_final<<<SCAN_NB, SCAN_B, 0, stream>>>(counts, boff, offsets);
    scan_small<<<1, 1024, 0, stream>>>(gcounts, NG, goff);
    bucket_scatter<<<NB, 256, 0, stream>>>(pairs, bcur, offsets, srcs);

    // ---- layer 1 ----
    gemm1<<<(NN + 31) / 32, 256, 0, stream>>>(x, W1, Hh);
    scores_kernel<<<(NN * 8 + 255) / 256, 256, 0, stream>>>(Hh, a1s, a1d, SSb, SDb, 8, 8);
    weights_kernel<8><<<(NN + 3) / 4, 256, 0, stream>>>(SSb, SDb, offsets, counts, srcs, wbuf);
    gat_kernel<8, 8, 1><<<(NN + 3) / 4, 256, 0, stream>>>(Hh, wbuf, offsets, srcs, b1, GOb);
    stats_kernel<<<STATS_BLOCKS, 256, 2 * 256 * sizeof(float), stream>>>(GOb, NN, 64, partial);
    bn_finalize<<<1, 512, 2 * 512 * sizeof(float), stream>>>(partial, STATS_BLOCKS, 64, invN, g1, be1, scaleA, shiftA);
    bnrelu_linear<8><<<(NN + 63) / 64, 256, 0, stream>>>(GOb, scaleA, shiftA, lW1, lb1, Ub);
    stats_kernel<<<STATS_BLOCKS, 256, 2 * 256 * sizeof(float), stream>>>(Ub, NN, 8, partial);
    bn_finalize<<<1, 512, 2 * 512 * sizeof(float), stream>>>(partial, STATS_BLOCKS, 8, invN, gl1, bel1, scaleB, shiftB);

    // ---- layer 2 ----
    bnrelu_gemm<8, 64><<<(NN + 63) / 64, 256, 0, stream>>>(Ub, scaleB, shiftB, W2, Hh);
    scores_kernel<<<(NN * 4 + 255) / 256, 256, 0, stream>>>(Hh, a2s, a2d, SSb, SDb, 4, 16);
    weights_kernel<4><<<(NN + 3) / 4, 256, 0, stream>>>(SSb, SDb, offsets, counts, srcs, wbuf);
    gat_kernel<4, 16, 1><<<(NN + 3) / 4, 256, 0, stream>>>(Hh, wbuf, offsets, srcs, b2, GOb);
    stats_kernel<<<STATS_BLOCKS, 256, 2 * 256 * sizeof(float), stream>>>(GOb, NN, 64, partial);
    bn_finalize<<<1, 512, 2 * 512 * sizeof(float), stream>>>(partial, STATS_BLOCKS, 64, invN, g2, be2, scaleA, shiftA);
    bnrelu_linear<16><<<(NN + 63) / 64, 256, 0, stream>>>(GOb, scaleA, shiftA, lW2, lb2, Ub);
    stats_kernel<<<STATS_BLOCKS, 256, 2 * 256 * sizeof(float), stream>>>(Ub, NN, 16, partial);
    bn_finalize<<<1, 512, 2 * 512 * sizeof(float), stream>>>(partial, STATS_BLOCKS, 16, invN, gl2, bel2, scaleB, shiftB);

    // ---- layer 3 ----
    bnrelu_gemm<16, 96><<<(NN + 63) / 64, 256, 0, stream>>>(Ub, scaleB, shiftB, W3, Hh);
    scores_kernel<<<(NN * 4 + 255) / 256, 256, 0, stream>>>(Hh, a3s, a3d, SSb, SDb, 4, 24);
    weights_kernel<4><<<(NN + 3) / 4, 256, 0, stream>>>(SSb, SDb, offsets, counts, srcs, wbuf);
    gat_kernel<4, 24, 2><<<(NN + 3) / 4, 256, 0, stream>>>(Hh, wbuf, offsets, srcs, b3, GOb);
    stats_kernel<<<STATS_BLOCKS, 192, 2 * 192 * sizeof(float), stream>>>(GOb, NN, 96, partial);
    bn_finalize<<<1, 768, 2 * 768 * sizeof(float), stream>>>(partial, STATS_BLOCKS, 96, invN, g3, be3, scaleA, shiftA);

    // ---- pool + head ----
    pool_kernel<<<NG, 128, 0, stream>>>(GOb, scaleA, shiftA, goff, pooled);
    final_gemm<<<(NG * 10 + 255) / 256, 256, 0, stream>>>(pooled, oW, ob, out);
}

// Round 8
// 758.365 us; speedup vs baseline: 2.2347x; 1.0994x over previous
//
#include <hip/hip_runtime.h>
#include <hip/hip_fp16.h>
#include <math.h>

#define NN 100000
#define NE 1600000
#define ET (NE + NN)      // edges + self loops
#define NG 512
#define STATS_BLOCKS 240
#define SCAN_B 1024
#define SCAN_NB ((NN + SCAN_B - 1) / SCAN_B)   // 98
#define PSLOTS (ET + 7 * NN)                   // padded edge-slot capacity (2.4M)

// bucket sort params
#define BSH 9                      // 512 nodes per bucket
#define NB  ((NN + 511) / 512)     // 196 buckets
#define BCAP 12288                 // cap per bucket (mean ~8700)
#define CHUNK 4096

// ---------------- pass1: partition edges into coarse buckets ----------------

__global__ __launch_bounds__(256) void part_pass1(const int* __restrict__ ei,
                                                  int* __restrict__ bcur,
                                                  unsigned* __restrict__ pairs) {
    __shared__ unsigned pck[CHUNK];
    __shared__ unsigned ordv[CHUNK];
    __shared__ unsigned char bkt[CHUNK];
    __shared__ unsigned char obkt[CHUNK];
    __shared__ int hist[NB + 1];
    __shared__ int lofs[NB + 1];
    __shared__ int cur[NB + 1];
    __shared__ int gpos[NB];
    __shared__ int lh[256];

    int t = threadIdx.x;
    int base = blockIdx.x * CHUNK;
    for (int i = t; i <= NB; i += 256) hist[i] = 0;
    __syncthreads();
    for (int i = t; i < CHUNK; i += 256) {
        int e = base + i;
        int b;
        unsigned p = 0;
        if (e < ET) {
            int s, d;
            if (e < NE) { s = ei[e]; d = ei[NE + e]; }
            else        { s = d = e - NE; }
            b = d >> BSH;
            p = ((unsigned)s << BSH) | (unsigned)(d & 511);
        } else b = NB;
        bkt[i] = (unsigned char)b;
        pck[i] = p;
        atomicAdd(&hist[b], 1);
    }
    __syncthreads();
    int v = (t <= NB) ? hist[t] : 0;
    lh[t] = v;
    __syncthreads();
    for (int off = 1; off < 256; off <<= 1) {
        int x = (t >= off) ? lh[t - off] : 0;
        __syncthreads();
        lh[t] += x;
        __syncthreads();
    }
    if (t <= NB) { lofs[t] = lh[t] - v; cur[t] = lh[t] - v; }
    __syncthreads();
    if (t < NB) {
        int h = hist[t];
        gpos[t] = (h > 0) ? atomicAdd(&bcur[t], h) : 0;
    }
    __syncthreads();
    for (int i = t; i < CHUNK; i += 256) {
        int b = bkt[i];
        int pos = atomicAdd(&cur[b], 1);
        ordv[pos] = pck[i];
        obkt[pos] = (unsigned char)b;
    }
    __syncthreads();
    int nvalid = lofs[NB];
    for (int i = t; i < nvalid; i += 256) {
        int b = obkt[i];
        int dst = gpos[b] + (i - lofs[b]);
        if (dst < BCAP) pairs[(size_t)b * BCAP + dst] = ordv[i];
    }
}

// ---------------- pass2a: per-bucket node counts ----------------

__global__ __launch_bounds__(256) void bucket_counts(const unsigned* __restrict__ pairs,
                                                     const int* __restrict__ bcur,
                                                     int* __restrict__ counts) {
    __shared__ int lhist[512];
    int b = blockIdx.x;
    int t = threadIdx.x;
    for (int i = t; i < 512; i += 256) lhist[i] = 0;
    __syncthreads();
    int cnt = min(bcur[b], BCAP);
    const unsigned* seg = pairs + (size_t)b * BCAP;
    for (int i = t; i < cnt; i += 256)
        atomicAdd(&lhist[seg[i] & 511], 1);
    __syncthreads();
    int nbase = b << BSH;
    for (int i = t; i < 512; i += 256) {
        int n = nbase + i;
        if (n < NN) counts[n] = lhist[i];
    }
}

// ---------------- pass2b: per-bucket scatter into padded srcs ----------------

__global__ __launch_bounds__(256) void bucket_scatter(const unsigned* __restrict__ pairs,
                                                      const int* __restrict__ bcur,
                                                      const int* __restrict__ offsets,
                                                      int* __restrict__ srcs) {
    __shared__ int cur[512];
    int b = blockIdx.x;
    int t = threadIdx.x;
    int nbase = b << BSH;
    for (int i = t; i < 512; i += 256) {
        int n = nbase + i;
        cur[i] = (n < NN) ? offsets[n] : 0;
    }
    __syncthreads();
    int cnt = min(bcur[b], BCAP);
    const unsigned* seg = pairs + (size_t)b * BCAP;
    for (int i = t; i < cnt; i += 256) {
        unsigned p = seg[i];
        int pos = atomicAdd(&cur[p & 511], 1);
        srcs[pos] = (int)(p >> BSH);
    }
}

// ---------------- graph boundaries via binary search (batch is sorted) ----------------

__global__ void graph_bounds(const int* __restrict__ batch, int* __restrict__ goff) {
    int g = blockIdx.x * blockDim.x + threadIdx.x;
    if (g > NG) return;
    // first index with batch[idx] >= g
    int lo = 0, hi = NN;
    while (lo < hi) {
        int mid = (lo + hi) >> 1;
        if (batch[mid] < g) lo = mid + 1; else hi = mid;
    }
    goff[g] = lo;
}

// ---------------- scans (counts rounded up to x8 inline -> padded offsets) ----------------

__global__ void scan_reduce(const int* __restrict__ in, int* __restrict__ bsum) {
    __shared__ int lds[256];
    int b = blockIdx.x, t = threadIdx.x;
    int s = 0;
    for (int i = t; i < SCAN_B; i += 256) {
        int idx = b * SCAN_B + i;
        if (idx < NN) s += (in[idx] + 7) & ~7;
    }
    lds[t] = s;
    __syncthreads();
    for (int off = 128; off > 0; off >>= 1) {
        if (t < off) lds[t] += lds[t + off];
        __syncthreads();
    }
    if (t == 0) bsum[b] = lds[0];
}

__global__ void scan_bsums(const int* __restrict__ bsum, int nb, int* __restrict__ boff,
                           int* __restrict__ total_loc) {
    __shared__ int lds[128];
    int t = threadIdx.x;
    int v = (t < nb) ? bsum[t] : 0;
    lds[t] = v;
    __syncthreads();
    for (int off = 1; off < 128; off <<= 1) {
        int x = (t >= off) ? lds[t - off] : 0;
        __syncthreads();
        lds[t] += x;
        __syncthreads();
    }
    if (t < nb) boff[t] = lds[t] - v;
    if (t == nb - 1) {
        boff[nb] = lds[t];
        if (total_loc) *total_loc = lds[t];
    }
}

__global__ void scan_final(const int* __restrict__ in, const int* __restrict__ boff,
                           int* __restrict__ out) {
    __shared__ int lds[SCAN_B];
    int b = blockIdx.x, t = threadIdx.x;
    int idx = b * SCAN_B + t;
    int v = (idx < NN) ? ((in[idx] + 7) & ~7) : 0;
    lds[t] = v;
    __syncthreads();
    for (int off = 1; off < SCAN_B; off <<= 1) {
        int x = (t >= off) ? lds[t - off] : 0;
        __syncthreads();
        lds[t] += x;
        __syncthreads();
    }
    if (idx < NN) out[idx] = boff[b] + lds[t] - v;
}

// ---------------- gemm1: Hh = fp16( X(N,128) @ W(128,64) ) ----------------

__global__ __launch_bounds__(256) void gemm1(const float* __restrict__ X,
                                             const float* __restrict__ W,
                                             __half* __restrict__ Hh) {
    __shared__ float wl[128 * 64];
    __shared__ float xl[32 * 132];
    int t = threadIdx.x;
    int n0 = blockIdx.x * 32;
    for (int i = t * 4; i < 128 * 64; i += 1024)
        *(float4*)&wl[i] = *(const float4*)&W[i];
    for (int i = t * 4; i < 32 * 128; i += 1024) {
        int r = i >> 7, c = i & 127;
        int n = n0 + r;
        float4 v = (n < NN) ? *(const float4*)&X[(size_t)n * 128 + c] : make_float4(0, 0, 0, 0);
        *(float4*)&xl[r * 132 + c] = v;
    }
    __syncthreads();
    int cg = (t & 15) * 4;
    int ng = (t >> 4) * 2;
    float acc[2][4] = {};
    for (int k = 0; k < 128; ++k) {
        float4 w4 = *(float4*)&wl[k * 64 + cg];
        #pragma unroll
        for (int j = 0; j < 2; ++j) {
            float xv = xl[(ng + j) * 132 + k];
            acc[j][0] += xv * w4.x; acc[j][1] += xv * w4.y;
            acc[j][2] += xv * w4.z; acc[j][3] += xv * w4.w;
        }
    }
    #pragma unroll
    for (int j = 0; j < 2; ++j) {
        int n = n0 + ng + j;
        if (n < NN) {
            __half2 p0 = __floats2half2_rn(acc[j][0], acc[j][1]);
            __half2 p1 = __floats2half2_rn(acc[j][2], acc[j][3]);
            *(__half2*)&Hh[(size_t)n * 64 + cg] = p0;
            *(__half2*)&Hh[(size_t)n * 64 + cg + 2] = p1;
        }
    }
}

// ---------------- per-node attention scores (from fp16 H) ----------------

__global__ void scores_kernel(const __half* __restrict__ Hh, const float* __restrict__ a_s,
                              const float* __restrict__ a_d, float* __restrict__ SS,
                              float* __restrict__ SD, int HEADS, int C) {
    int idx = blockIdx.x * blockDim.x + threadIdx.x;
    if (idx >= NN * HEADS) return;
    int n = idx / HEADS, h = idx % HEADS;
    const __half* row = Hh + (size_t)n * HEADS * C + h * C;
    float s1 = 0.f, s2 = 0.f;
    for (int c = 0; c < C; c += 2) {
        float2 v = __half22float2(*(const __half2*)&row[c]);
        s1 += v.x * a_s[h * C + c] + v.y * a_s[h * C + c + 1];
        s2 += v.x * a_d[h * C + c] + v.y * a_d[h * C + c + 1];
    }
    SS[idx] = s1;
    SD[idx] = s2;
}

// ---------------- per-(edge,head) softmax numerators, wave per dst node ----------------
// NOTE: SPG=64/H may exceed the 8-slot padding granularity, so the last group of a
// node can reach into the next node's slots — the `slot < end` guard prevents the
// cross-node write race that broke round 5.

template <int H>
__global__ __launch_bounds__(256) void weights_kernel(const float* __restrict__ SS,
                                                      const float* __restrict__ SD,
                                                      const int* __restrict__ offsets,
                                                      const int* __restrict__ counts,
                                                      const int* __restrict__ srcs,
                                                      __half* __restrict__ w) {
    int wid = blockIdx.x * 4 + (threadIdx.x >> 6);
    if (wid >= NN) return;
    int lane = threadIdx.x & 63;
    constexpr int SPG = 64 / H;        // slots per iteration
    int so = lane / H, h = lane % H;
    int beg = offsets[wid], end = offsets[wid + 1];
    int deg = counts[wid];
    float sdv = SD[(unsigned)wid * H + h];
    for (int g = beg; g < end; g += SPG) {
        int slot = g + so;
        if (slot < end) {
            int src = srcs[slot];
            float sc = SS[(unsigned)src * H + h] + sdv;
            sc = sc > 0.f ? sc : 0.2f * sc;
            float wv = (slot - beg) < deg ? __expf(sc) : 0.f;
            w[(unsigned)slot * H + h] = __float2half(wv);
        }
    }
}

// ---------------- GAT gather: pure streaming weighted sum, no masks ----------------

template <int HEADS, int C, int PL>
__global__ __launch_bounds__(256) void gat_kernel(const __half* __restrict__ Hh,
                                                  const __half* __restrict__ w,
                                                  const int* __restrict__ offsets,
                                                  const int* __restrict__ srcs,
                                                  const float* __restrict__ bias,
                                                  float* __restrict__ GO) {
    constexpr int CH = HEADS * C;  // 64 or 96
    int wid = blockIdx.x * (blockDim.x >> 6) + (threadIdx.x >> 6);
    int lane = threadIdx.x & 63;
    if (wid >= NN) return;
    int ch0 = lane * PL;
    bool active = ch0 < CH;
    int ch0l = active ? ch0 : 0;
    int head = active ? (ch0 / C) : 0;
    int beg = offsets[wid], end = offsets[wid + 1];
    const int* sp = srcs + beg;
    const __half* wp = w + (unsigned)beg * HEADS + head;
    float s = 0.f, a0 = 0.f, a1 = 0.f;
    for (int e = beg; e < end; e += 8) {
        int sv[8];
        float wv[8];
        #pragma unroll
        for (int i = 0; i < 8; ++i) {
            sv[i] = sp[i];
            wv[i] = __half2float(wp[i * HEADS]);
        }
        float hv0[8], hv1[8];
        #pragma unroll
        for (int i = 0; i < 8; ++i) {
            if (PL == 2) {
                __half2 hp = *(const __half2*)&Hh[(unsigned)(sv[i] * CH) + ch0l];
                hv0[i] = __low2float(hp); hv1[i] = __high2float(hp);
            } else {
                hv0[i] = __half2float(Hh[(unsigned)(sv[i] * CH) + ch0l]);
                hv1[i] = 0.f;
            }
        }
        float ws = ((wv[0] + wv[1]) + (wv[2] + wv[3])) + ((wv[4] + wv[5]) + (wv[6] + wv[7]));
        float as0 = ((wv[0] * hv0[0] + wv[1] * hv0[1]) + (wv[2] * hv0[2] + wv[3] * hv0[3]))
                  + ((wv[4] * hv0[4] + wv[5] * hv0[5]) + (wv[6] * hv0[6] + wv[7] * hv0[7]));
        s += ws;
        a0 += as0;
        if (PL == 2) {
            float as1 = ((wv[0] * hv1[0] + wv[1] * hv1[1]) + (wv[2] * hv1[2] + wv[3] * hv1[3]))
                      + ((wv[4] * hv1[4] + wv[5] * hv1[5]) + (wv[6] * hv1[6] + wv[7] * hv1[7]));
            a1 += as1;
        }
        sp += 8;
        wp += 8 * HEADS;
    }
    if (active) {
        float inv = 1.f / s;
        GO[(unsigned)(wid * CH) + ch0] = a0 * inv + bias[ch0];
        if (PL == 2) GO[(unsigned)(wid * CH) + ch0 + 1] = a1 * inv + bias[ch0 + 1];
    }
}

// ---------------- BN stats (deterministic two-stage) ----------------

__global__ void stats_kernel(const float* __restrict__ X, int Nn, int C,
                             float* __restrict__ partial) {
    int t = threadIdx.x;
    int c = t % C;
    int grp = t / C;
    int G_ = blockDim.x / C;
    float s = 0.f, q = 0.f;
    for (int n = blockIdx.x * G_ + grp; n < Nn; n += gridDim.x * G_) {
        float v = X[(size_t)n * C + c];
        s += v; q += v * v;
    }
    extern __shared__ float lds[];
    lds[t] = s; lds[blockDim.x + t] = q;
    __syncthreads();
    for (int off = blockDim.x >> 1; off >= C; off >>= 1) {
        if (t < off) {
            lds[t] += lds[t + off];
            lds[blockDim.x + t] += lds[blockDim.x + t + off];
        }
        __syncthreads();
    }
    if (t < C) {
        partial[(size_t)blockIdx.x * 2 * C + t] = lds[t];
        partial[(size_t)blockIdx.x * 2 * C + C + t] = lds[blockDim.x + t];
    }
}

// parallel finalize: blockDim = C * G (G pow2), LDS tree reduce
__global__ void bn_finalize(const float* __restrict__ partial, int nb, int C, float invN,
                            const float* __restrict__ g, const float* __restrict__ be,
                            float* __restrict__ scale, float* __restrict__ shift) {
    extern __shared__ float red[];
    int t = threadIdx.x;
    int c = t % C;
    int grp = t / C;
    int G_ = blockDim.x / C;
    float s = 0.f, q = 0.f;
    for (int b = grp; b < nb; b += G_) {
        s += partial[(size_t)b * 2 * C + c];
        q += partial[(size_t)b * 2 * C + C + c];
    }
    red[t] = s; red[blockDim.x + t] = q;
    __syncthreads();
    for (int off = blockDim.x >> 1; off >= C; off >>= 1) {
        if (t < off) {
            red[t] += red[t + off];
            red[blockDim.x + t] += red[blockDim.x + t + off];
        }
        __syncthreads();
    }
    if (t < C) {
        float mean = red[t] * invN;
        float var = fmaxf(red[blockDim.x + t] * invN - mean * mean, 0.f);
        float rs = rsqrtf(var + 1e-5f);
        float sc = g[t] * rs;
        scale[t] = sc;
        shift[t] = be[t] - mean * sc;
    }
}

// ---------------- relu(bn(X[N,64])) @ Lw(64,KOUT) + lb -> U ----------------

template <int KOUT>
__global__ __launch_bounds__(256) void bnrelu_linear(const float* __restrict__ X,
                                                     const float* __restrict__ scale,
                                                     const float* __restrict__ shift,
                                                     const float* __restrict__ Lw,
                                                     const float* __restrict__ lb,
                                                     float* __restrict__ U) {
    __shared__ float tl[64 * 65];
    int t = threadIdx.x;
    int n0 = blockIdx.x * 64;
    for (int i = t * 4; i < 64 * 64; i += 1024) {
        int r = i >> 6, cc = i & 63;
        int n = n0 + r;
        float4 v = (n < NN) ? *(const float4*)&X[(size_t)n * 64 + cc] : make_float4(0, 0, 0, 0);
        float vv[4] = {v.x, v.y, v.z, v.w};
        #pragma unroll
        for (int j = 0; j < 4; ++j)
            tl[r * 65 + cc + j] = fmaxf(vv[j] * scale[cc + j] + shift[cc + j], 0.f);
    }
    __syncthreads();
    int nl = t & 63;
    int kg = (t >> 6) * (KOUT / 4);
    float acc[KOUT / 4] = {};
    for (int l = 0; l < 64; ++l) {
        float v = tl[nl * 65 + l];
        #pragma unroll
        for (int j = 0; j < KOUT / 4; ++j) acc[j] += v * Lw[l * KOUT + kg + j];
    }
    int n = n0 + nl;
    if (n < NN)
        #pragma unroll
        for (int j = 0; j < KOUT / 4; ++j)
            U[(size_t)n * KOUT + kg + j] = acc[j] + lb[kg + j];
}

// ---------------- relu(bn(U[N,CIN])) @ W(CIN,COUT) -> Hh (fp16) ----------------

template <int CIN, int COUT>
__global__ __launch_bounds__(256) void bnrelu_gemm(const float* __restrict__ U,
                                                   const float* __restrict__ scale,
                                                   const float* __restrict__ shift,
                                                   const float* __restrict__ W,
                                                   __half* __restrict__ Hh) {
    int t = threadIdx.x;
    int nl = t >> 2;
    int q = t & 3;
    int n = blockIdx.x * 64 + nl;
    if (n >= NN) return;
    constexpr int CPT = COUT / 4;
    float v[CIN];
    #pragma unroll
    for (int c = 0; c < CIN; ++c)
        v[c] = fmaxf(U[(size_t)n * CIN + c] * scale[c] + shift[c], 0.f);
    float acc[CPT] = {};
    #pragma unroll
    for (int c = 0; c < CIN; ++c) {
        #pragma unroll
        for (int j = 0; j < CPT; ++j) acc[j] += v[c] * W[c * COUT + q * CPT + j];
    }
    #pragma unroll
    for (int j = 0; j < CPT; j += 2)
        *(__half2*)&Hh[(size_t)n * COUT + q * CPT + j] = __floats2half2_rn(acc[j], acc[j + 1]);
}

// ---------------- mean-pool per graph ----------------

__global__ void pool_kernel(const float* __restrict__ GO, const float* __restrict__ scale,
                            const float* __restrict__ shift, const int* __restrict__ goff,
                            float* __restrict__ pooled) {
    int g = blockIdx.x;
    int t = threadIdx.x;
    if (t >= 96) return;
    int beg = goff[g], end = goff[g + 1];
    float s = 0.f;
    for (int n = beg; n < end; ++n)
        s += fmaxf(GO[(size_t)n * 96 + t] * scale[t] + shift[t], 0.f);
    float cnt = (float)(end - beg);
    pooled[g * 96 + t] = s / fmaxf(cnt, 1.f);
}

__global__ void final_gemm(const float* __restrict__ pooled, const float* __restrict__ oW,
                           const float* __restrict__ ob, float* __restrict__ out) {
    int idx = blockIdx.x * blockDim.x + threadIdx.x;
    if (idx >= NG * 10) return;
    int g = idx / 10, k = idx % 10;
    float s = ob[k];
    for (int c = 0; c < 96; ++c) s += pooled[g * 96 + c] * oW[c * 10 + k];
    out[idx] = s;
}

// ---------------- launch ----------------

extern "C" void kernel_launch(void* const* d_in, const int* in_sizes, int n_in,
                              void* d_out, int out_size, void* d_ws, size_t ws_size,
                              hipStream_t stream) {
    const float* x   = (const float*)d_in[0];
    const int*   ei  = (const int*)d_in[1];
    const int*   bat = (const int*)d_in[2];
    const float *W1 = (const float*)d_in[3], *a1s = (const float*)d_in[4],
                *a1d = (const float*)d_in[5], *b1 = (const float*)d_in[6],
                *g1 = (const float*)d_in[7], *be1 = (const float*)d_in[8],
                *lW1 = (const float*)d_in[9], *lb1 = (const float*)d_in[10],
                *gl1 = (const float*)d_in[11], *bel1 = (const float*)d_in[12],
                *W2 = (const float*)d_in[13], *a2s = (const float*)d_in[14],
                *a2d = (const float*)d_in[15], *b2 = (const float*)d_in[16],
                *g2 = (const float*)d_in[17], *be2 = (const float*)d_in[18],
                *lW2 = (const float*)d_in[19], *lb2 = (const float*)d_in[20],
                *gl2 = (const float*)d_in[21], *bel2 = (const float*)d_in[22],
                *W3 = (const float*)d_in[23], *a3s = (const float*)d_in[24],
                *a3d = (const float*)d_in[25], *b3 = (const float*)d_in[26],
                *g3 = (const float*)d_in[27], *be3 = (const float*)d_in[28],
                *oW = (const float*)d_in[29], *ob = (const float*)d_in[30];
    float* out = (float*)d_out;

    // workspace layout
    int* iw      = (int*)d_ws;
    int* bcur    = iw;                   // NB  (memset)
    int* counts  = bcur + NB;            // NN
    int* offsets = counts + NN;          // NN+1 (padded offsets)
    int* goff    = offsets + NN + 1;     // NG+1
    int* bsum    = goff + NG + 1;        // SCAN_NB
    int* boff    = bsum + SCAN_NB;       // SCAN_NB+1
    int* srcs    = boff + SCAN_NB + 1;   // PSLOTS
    float* fw      = (float*)(srcs + PSLOTS);
    float* GOb     = fw;                         // NN*96
    float* Ub      = GOb + (size_t)NN * 96;      // NN*16
    float* SSb     = Ub + (size_t)NN * 16;       // NN*8
    float* SDb     = SSb + (size_t)NN * 8;       // NN*8
    float* partial = SDb + (size_t)NN * 8;       // STATS_BLOCKS*192
    float* scaleA  = partial + STATS_BLOCKS * 192;
    float* shiftA  = scaleA + 96;
    float* scaleB  = shiftA + 96;
    float* shiftB  = scaleB + 16;
    float* pooled  = shiftB + 16;                // NG*96
    __half* Hh     = (__half*)(pooled + NG * 96);     // NN*96 halves
    __half* wbuf   = (__half*)(Hh + (size_t)NN * 96); // PSLOTS*8 halves (layer1 max)
    unsigned* pairs = (unsigned*)GOb;            // aliases GOb during preprocessing

    const float invN = 1.0f / (float)NN;

    // ---- edge bucket sort -> padded CSR (shared by all layers) ----
    hipMemsetAsync(bcur, 0, NB * sizeof(int), stream);
    hipMemsetAsync(srcs, 0, (size_t)PSLOTS * sizeof(int), stream);
    part_pass1<<<(ET + CHUNK - 1) / CHUNK, 256, 0, stream>>>(ei, bcur, pairs);
    graph_bounds<<<3, 256, 0, stream>>>(bat, goff);
    bucket_counts<<<NB, 256, 0, stream>>>(pairs, bcur, counts);
    scan_reduce<<<SCAN_NB, 256, 0, stream>>>(counts, bsum);
    scan_bsums<<<1, 128, 0, stream>>>(bsum, SCAN_NB, boff, &offsets[NN]);
    scan_final<<<SCAN_NB, SCAN_B, 0, stream>>>(counts, boff, offsets);
    bucket_scatter<<<NB, 256, 0, stream>>>(pairs, bcur, offsets, srcs);

    // ---- layer 1 ----
    gemm1<<<(NN + 31) / 32, 256, 0, stream>>>(x, W1, Hh);
    scores_kernel<<<(NN * 8 + 255) / 256, 256, 0, stream>>>(Hh, a1s, a1d, SSb, SDb, 8, 8);
    weights_kernel<8><<<(NN + 3) / 4, 256, 0, stream>>>(SSb, SDb, offsets, counts, srcs, wbuf);
    gat_kernel<8, 8, 1><<<(NN + 3) / 4, 256, 0, stream>>>(Hh, wbuf, offsets, srcs, b1, GOb);
    stats_kernel<<<STATS_BLOCKS, 256, 2 * 256 * sizeof(float), stream>>>(GOb, NN, 64, partial);
    bn_finalize<<<1, 512, 2 * 512 * sizeof(float), stream>>>(partial, STATS_BLOCKS, 64, invN, g1, be1, scaleA, shiftA);
    bnrelu_linear<8><<<(NN + 63) / 64, 256, 0, stream>>>(GOb, scaleA, shiftA, lW1, lb1, Ub);
    stats_kernel<<<STATS_BLOCKS, 256, 2 * 256 * sizeof(float), stream>>>(Ub, NN, 8, partial);
    bn_finalize<<<1, 512, 2 * 512 * sizeof(float), stream>>>(partial, STATS_BLOCKS, 8, invN, gl1, bel1, scaleB, shiftB);

    // ---- layer 2 ----
    bnrelu_gemm<8, 64><<<(NN + 63) / 64, 256, 0, stream>>>(Ub, scaleB, shiftB, W2, Hh);
    scores_kernel<<<(NN * 4 + 255) / 256, 256, 0, stream>>>(Hh, a2s, a2d, SSb, SDb, 4, 16);
    weights_kernel<4><<<(NN + 3) / 4, 256, 0, stream>>>(SSb, SDb, offsets, counts, srcs, wbuf);
    gat_kernel<4, 16, 1><<<(NN + 3) / 4, 256, 0, stream>>>(Hh, wbuf, offsets, srcs, b2, GOb);
    stats_kernel<<<STATS_BLOCKS, 256, 2 * 256 * sizeof(float), stream>>>(GOb, NN, 64, partial);
    bn_finalize<<<1, 512, 2 * 512 * sizeof(float), stream>>>(partial, STATS_BLOCKS, 64, invN, g2, be2, scaleA, shiftA);
    bnrelu_linear<16><<<(NN + 63) / 64, 256, 0, stream>>>(GOb, scaleA, shiftA, lW2, lb2, Ub);
    stats_kernel<<<STATS_BLOCKS, 256, 2 * 256 * sizeof(float), stream>>>(Ub, NN, 16, partial);
    bn_finalize<<<1, 512, 2 * 512 * sizeof(float), stream>>>(partial, STATS_BLOCKS, 16, invN, gl2, bel2, scaleB, shiftB);

    // ---- layer 3 ----
    bnrelu_gemm<16, 96><<<(NN + 63) / 64, 256, 0, stream>>>(Ub, scaleB, shiftB, W3, Hh);
    scores_kernel<<<(NN * 4 + 255) / 256, 256, 0, stream>>>(Hh, a3s, a3d, SSb, SDb, 4, 24);
    weights_kernel<4><<<(NN + 3) / 4, 256, 0, stream>>>(SSb, SDb, offsets, counts, srcs, wbuf);
    gat_kernel<4, 24, 2><<<(NN + 3) / 4, 256, 0, stream>>>(Hh, wbuf, offsets, srcs, b3, GOb);
    stats_kernel<<<STATS_BLOCKS, 192, 2 * 192 * sizeof(float), stream>>>(GOb, NN, 96, partial);
    bn_finalize<<<1, 768, 2 * 768 * sizeof(float), stream>>>(partial, STATS_BLOCKS, 96, invN, g3, be3, scaleA, shiftA);

    // ---- pool + head ----
    pool_kernel<<<NG, 128, 0, stream>>>(GOb, scaleA, shiftA, goff, pooled);
    final_gemm<<<(NG * 10 + 255) / 256, 256, 0, stream>>>(pooled, oW, ob, out);
}

// Round 9
// 699.114 us; speedup vs baseline: 2.4241x; 1.0848x over previous
//
#include <hip/hip_runtime.h>
#include <hip/hip_fp16.h>
#include <math.h>

#define NN 100000
#define NE 1600000
#define ET (NE + NN)      // edges + self loops
#define NG 512
#define STATS_BLOCKS 240
#define SCAN_B 1024
#define SCAN_NB ((NN + SCAN_B - 1) / SCAN_B)   // 98
#define PSLOTS (ET + 7 * NN)                   // padded edge-slot capacity (2.4M)

// bucket sort params
#define BSH 9                      // 512 nodes per bucket
#define NB  ((NN + 511) / 512)     // 196 buckets
#define BCAP 12288                 // cap per bucket (mean ~8700)
#define CHUNK 4096

// ---------------- pass1: partition edges into coarse buckets ----------------

__global__ __launch_bounds__(256) void part_pass1(const int* __restrict__ ei,
                                                  int* __restrict__ bcur,
                                                  unsigned* __restrict__ pairs) {
    __shared__ unsigned pck[CHUNK];
    __shared__ unsigned ordv[CHUNK];
    __shared__ unsigned char bkt[CHUNK];
    __shared__ unsigned char obkt[CHUNK];
    __shared__ int hist[NB + 1];
    __shared__ int lofs[NB + 1];
    __shared__ int cur[NB + 1];
    __shared__ int gpos[NB];
    __shared__ int lh[256];

    int t = threadIdx.x;
    int base = blockIdx.x * CHUNK;
    for (int i = t; i <= NB; i += 256) hist[i] = 0;
    __syncthreads();
    for (int i = t; i < CHUNK; i += 256) {
        int e = base + i;
        int b;
        unsigned p = 0;
        if (e < ET) {
            int s, d;
            if (e < NE) { s = ei[e]; d = ei[NE + e]; }
            else        { s = d = e - NE; }
            b = d >> BSH;
            p = ((unsigned)s << BSH) | (unsigned)(d & 511);
        } else b = NB;
        bkt[i] = (unsigned char)b;
        pck[i] = p;
        atomicAdd(&hist[b], 1);
    }
    __syncthreads();
    int v = (t <= NB) ? hist[t] : 0;
    lh[t] = v;
    __syncthreads();
    for (int off = 1; off < 256; off <<= 1) {
        int x = (t >= off) ? lh[t - off] : 0;
        __syncthreads();
        lh[t] += x;
        __syncthreads();
    }
    if (t <= NB) { lofs[t] = lh[t] - v; cur[t] = lh[t] - v; }
    __syncthreads();
    if (t < NB) {
        int h = hist[t];
        gpos[t] = (h > 0) ? atomicAdd(&bcur[t], h) : 0;
    }
    __syncthreads();
    for (int i = t; i < CHUNK; i += 256) {
        int b = bkt[i];
        int pos = atomicAdd(&cur[b], 1);
        ordv[pos] = pck[i];
        obkt[pos] = (unsigned char)b;
    }
    __syncthreads();
    int nvalid = lofs[NB];
    for (int i = t; i < nvalid; i += 256) {
        int b = obkt[i];
        int dst = gpos[b] + (i - lofs[b]);
        if (dst < BCAP) pairs[(size_t)b * BCAP + dst] = ordv[i];
    }
}

// ---------------- pass2a: per-bucket node counts ----------------

__global__ __launch_bounds__(256) void bucket_counts(const unsigned* __restrict__ pairs,
                                                     const int* __restrict__ bcur,
                                                     int* __restrict__ counts) {
    __shared__ int lhist[512];
    int b = blockIdx.x;
    int t = threadIdx.x;
    for (int i = t; i < 512; i += 256) lhist[i] = 0;
    __syncthreads();
    int cnt = min(bcur[b], BCAP);
    const unsigned* seg = pairs + (size_t)b * BCAP;
    for (int i = t; i < cnt; i += 256)
        atomicAdd(&lhist[seg[i] & 511], 1);
    __syncthreads();
    int nbase = b << BSH;
    for (int i = t; i < 512; i += 256) {
        int n = nbase + i;
        if (n < NN) counts[n] = lhist[i];
    }
}

// ---------------- pass2b: per-bucket scatter into padded srcs ----------------

__global__ __launch_bounds__(256) void bucket_scatter(const unsigned* __restrict__ pairs,
                                                      const int* __restrict__ bcur,
                                                      const int* __restrict__ offsets,
                                                      int* __restrict__ srcs) {
    __shared__ int cur[512];
    int b = blockIdx.x;
    int t = threadIdx.x;
    int nbase = b << BSH;
    for (int i = t; i < 512; i += 256) {
        int n = nbase + i;
        cur[i] = (n < NN) ? offsets[n] : 0;
    }
    __syncthreads();
    int cnt = min(bcur[b], BCAP);
    const unsigned* seg = pairs + (size_t)b * BCAP;
    for (int i = t; i < cnt; i += 256) {
        unsigned p = seg[i];
        int pos = atomicAdd(&cur[p & 511], 1);
        srcs[pos] = (int)(p >> BSH);
    }
}

// ---------------- graph boundaries via binary search (batch is sorted) ----------------

__global__ void graph_bounds(const int* __restrict__ batch, int* __restrict__ goff) {
    int g = blockIdx.x * blockDim.x + threadIdx.x;
    if (g > NG) return;
    int lo = 0, hi = NN;
    while (lo < hi) {
        int mid = (lo + hi) >> 1;
        if (batch[mid] < g) lo = mid + 1; else hi = mid;
    }
    goff[g] = lo;
}

// ---------------- scans (counts rounded up to x8 inline -> padded offsets) ----------------

__global__ void scan_reduce(const int* __restrict__ in, int* __restrict__ bsum) {
    __shared__ int lds[256];
    int b = blockIdx.x, t = threadIdx.x;
    int s = 0;
    for (int i = t; i < SCAN_B; i += 256) {
        int idx = b * SCAN_B + i;
        if (idx < NN) s += (in[idx] + 7) & ~7;
    }
    lds[t] = s;
    __syncthreads();
    for (int off = 128; off > 0; off >>= 1) {
        if (t < off) lds[t] += lds[t + off];
        __syncthreads();
    }
    if (t == 0) bsum[b] = lds[0];
}

__global__ void scan_bsums(const int* __restrict__ bsum, int nb, int* __restrict__ boff,
                           int* __restrict__ total_loc) {
    __shared__ int lds[128];
    int t = threadIdx.x;
    int v = (t < nb) ? bsum[t] : 0;
    lds[t] = v;
    __syncthreads();
    for (int off = 1; off < 128; off <<= 1) {
        int x = (t >= off) ? lds[t - off] : 0;
        __syncthreads();
        lds[t] += x;
        __syncthreads();
    }
    if (t < nb) boff[t] = lds[t] - v;
    if (t == nb - 1) {
        boff[nb] = lds[t];
        if (total_loc) *total_loc = lds[t];
    }
}

__global__ void scan_final(const int* __restrict__ in, const int* __restrict__ boff,
                           int* __restrict__ out) {
    __shared__ int lds[SCAN_B];
    int b = blockIdx.x, t = threadIdx.x;
    int idx = b * SCAN_B + t;
    int v = (idx < NN) ? ((in[idx] + 7) & ~7) : 0;
    lds[t] = v;
    __syncthreads();
    for (int off = 1; off < SCAN_B; off <<= 1) {
        int x = (t >= off) ? lds[t - off] : 0;
        __syncthreads();
        lds[t] += x;
        __syncthreads();
    }
    if (idx < NN) out[idx] = boff[b] + lds[t] - v;
}

// ---------------- gemm1: Hh = fp16( X(N,128) @ W(128,64) ) ----------------

__global__ __launch_bounds__(256) void gemm1(const float* __restrict__ X,
                                             const float* __restrict__ W,
                                             __half* __restrict__ Hh) {
    __shared__ float wl[128 * 64];
    __shared__ float xl[32 * 132];
    int t = threadIdx.x;
    int n0 = blockIdx.x * 32;
    for (int i = t * 4; i < 128 * 64; i += 1024)
        *(float4*)&wl[i] = *(const float4*)&W[i];
    for (int i = t * 4; i < 32 * 128; i += 1024) {
        int r = i >> 7, c = i & 127;
        int n = n0 + r;
        float4 v = (n < NN) ? *(const float4*)&X[(size_t)n * 128 + c] : make_float4(0, 0, 0, 0);
        *(float4*)&xl[r * 132 + c] = v;
    }
    __syncthreads();
    int cg = (t & 15) * 4;
    int ng = (t >> 4) * 2;
    float acc[2][4] = {};
    for (int k = 0; k < 128; ++k) {
        float4 w4 = *(float4*)&wl[k * 64 + cg];
        #pragma unroll
        for (int j = 0; j < 2; ++j) {
            float xv = xl[(ng + j) * 132 + k];
            acc[j][0] += xv * w4.x; acc[j][1] += xv * w4.y;
            acc[j][2] += xv * w4.z; acc[j][3] += xv * w4.w;
        }
    }
    #pragma unroll
    for (int j = 0; j < 2; ++j) {
        int n = n0 + ng + j;
        if (n < NN) {
            __half2 p0 = __floats2half2_rn(acc[j][0], acc[j][1]);
            __half2 p1 = __floats2half2_rn(acc[j][2], acc[j][3]);
            *(__half2*)&Hh[(size_t)n * 64 + cg] = p0;
            *(__half2*)&Hh[(size_t)n * 64 + cg + 2] = p1;
        }
    }
}

// ---------------- per-node attention scores (from fp16 H) ----------------

__global__ void scores_kernel(const __half* __restrict__ Hh, const float* __restrict__ a_s,
                              const float* __restrict__ a_d, float* __restrict__ SS,
                              float* __restrict__ SD, int HEADS, int C) {
    int idx = blockIdx.x * blockDim.x + threadIdx.x;
    if (idx >= NN * HEADS) return;
    int n = idx / HEADS, h = idx % HEADS;
    const __half* row = Hh + (size_t)n * HEADS * C + h * C;
    float s1 = 0.f, s2 = 0.f;
    for (int c = 0; c < C; c += 2) {
        float2 v = __half22float2(*(const __half2*)&row[c]);
        s1 += v.x * a_s[h * C + c] + v.y * a_s[h * C + c + 1];
        s2 += v.x * a_d[h * C + c] + v.y * a_d[h * C + c + 1];
    }
    SS[idx] = s1;
    SD[idx] = s2;
}

// ---------------- per-(edge,head) softmax numerators, wave per dst node ----------------
// NOTE: SPG=64/H may exceed the 8-slot padding granularity, so the last group of a
// node can reach into the next node's slots — the `slot < end` guard prevents the
// cross-node write race that broke round 5.

template <int H>
__global__ __launch_bounds__(256) void weights_kernel(const float* __restrict__ SS,
                                                      const float* __restrict__ SD,
                                                      const int* __restrict__ offsets,
                                                      const int* __restrict__ counts,
                                                      const int* __restrict__ srcs,
                                                      __half* __restrict__ w) {
    int wid = blockIdx.x * 4 + (threadIdx.x >> 6);
    if (wid >= NN) return;
    int lane = threadIdx.x & 63;
    constexpr int SPG = 64 / H;        // slots per iteration
    int so = lane / H, h = lane % H;
    int beg = offsets[wid], end = offsets[wid + 1];
    int deg = counts[wid];
    float sdv = SD[(unsigned)wid * H + h];
    for (int g = beg; g < end; g += SPG) {
        int slot = g + so;
        if (slot < end) {
            int src = srcs[slot];
            float sc = SS[(unsigned)src * H + h] + sdv;
            sc = sc > 0.f ? sc : 0.2f * sc;
            float wv = (slot - beg) < deg ? __expf(sc) : 0.f;
            w[(unsigned)slot * H + h] = __float2half(wv);
        }
    }
}

// ---------------- GAT gather: pure streaming weighted sum, no masks ----------------

template <int HEADS, int C, int PL>
__global__ __launch_bounds__(256) void gat_kernel(const __half* __restrict__ Hh,
                                                  const __half* __restrict__ w,
                                                  const int* __restrict__ offsets,
                                                  const int* __restrict__ srcs,
                                                  const float* __restrict__ bias,
                                                  float* __restrict__ GO) {
    constexpr int CH = HEADS * C;  // 64 or 96
    int wid = blockIdx.x * (blockDim.x >> 6) + (threadIdx.x >> 6);
    int lane = threadIdx.x & 63;
    if (wid >= NN) return;
    int ch0 = lane * PL;
    bool active = ch0 < CH;
    int ch0l = active ? ch0 : 0;
    int head = active ? (ch0 / C) : 0;
    int beg = offsets[wid], end = offsets[wid + 1];
    const int* sp = srcs + beg;
    const __half* wp = w + (unsigned)beg * HEADS + head;
    float s = 0.f, a0 = 0.f, a1 = 0.f;
    for (int e = beg; e < end; e += 8) {
        int sv[8];
        float wv[8];
        #pragma unroll
        for (int i = 0; i < 8; ++i) {
            sv[i] = sp[i];
            wv[i] = __half2float(wp[i * HEADS]);
        }
        float hv0[8], hv1[8];
        #pragma unroll
        for (int i = 0; i < 8; ++i) {
            if (PL == 2) {
                __half2 hp = *(const __half2*)&Hh[(unsigned)(sv[i] * CH) + ch0l];
                hv0[i] = __low2float(hp); hv1[i] = __high2float(hp);
            } else {
                hv0[i] = __half2float(Hh[(unsigned)(sv[i] * CH) + ch0l]);
                hv1[i] = 0.f;
            }
        }
        float ws = ((wv[0] + wv[1]) + (wv[2] + wv[3])) + ((wv[4] + wv[5]) + (wv[6] + wv[7]));
        float as0 = ((wv[0] * hv0[0] + wv[1] * hv0[1]) + (wv[2] * hv0[2] + wv[3] * hv0[3]))
                  + ((wv[4] * hv0[4] + wv[5] * hv0[5]) + (wv[6] * hv0[6] + wv[7] * hv0[7]));
        s += ws;
        a0 += as0;
        if (PL == 2) {
            float as1 = ((wv[0] * hv1[0] + wv[1] * hv1[1]) + (wv[2] * hv1[2] + wv[3] * hv1[3]))
                      + ((wv[4] * hv1[4] + wv[5] * hv1[5]) + (wv[6] * hv1[6] + wv[7] * hv1[7]));
            a1 += as1;
        }
        sp += 8;
        wp += 8 * HEADS;
    }
    if (active) {
        float inv = 1.f / s;
        GO[(unsigned)(wid * CH) + ch0] = a0 * inv + bias[ch0];
        if (PL == 2) GO[(unsigned)(wid * CH) + ch0 + 1] = a1 * inv + bias[ch0 + 1];
    }
}

// ---------------- BN stats (deterministic two-stage) ----------------

__global__ void stats_kernel(const float* __restrict__ X, int Nn, int C,
                             float* __restrict__ partial) {
    int t = threadIdx.x;
    int c = t % C;
    int grp = t / C;
    int G_ = blockDim.x / C;
    float s = 0.f, q = 0.f;
    for (int n = blockIdx.x * G_ + grp; n < Nn; n += gridDim.x * G_) {
        float v = X[(size_t)n * C + c];
        s += v; q += v * v;
    }
    extern __shared__ float lds[];
    lds[t] = s; lds[blockDim.x + t] = q;
    __syncthreads();
    for (int off = blockDim.x >> 1; off >= C; off >>= 1) {
        if (t < off) {
            lds[t] += lds[t + off];
            lds[blockDim.x + t] += lds[blockDim.x + t + off];
        }
        __syncthreads();
    }
    if (t < C) {
        partial[(size_t)blockIdx.x * 2 * C + t] = lds[t];
        partial[(size_t)blockIdx.x * 2 * C + C + t] = lds[blockDim.x + t];
    }
}

// parallel finalize: blockDim = C * G (G pow2), LDS tree reduce
__global__ void bn_finalize(const float* __restrict__ partial, int nb, int C, float invN,
                            const float* __restrict__ g, const float* __restrict__ be,
                            float* __restrict__ scale, float* __restrict__ shift) {
    extern __shared__ float red[];
    int t = threadIdx.x;
    int c = t % C;
    int grp = t / C;
    int G_ = blockDim.x / C;
    float s = 0.f, q = 0.f;
    for (int b = grp; b < nb; b += G_) {
        s += partial[(size_t)b * 2 * C + c];
        q += partial[(size_t)b * 2 * C + C + c];
    }
    red[t] = s; red[blockDim.x + t] = q;
    __syncthreads();
    for (int off = blockDim.x >> 1; off >= C; off >>= 1) {
        if (t < off) {
            red[t] += red[t + off];
            red[blockDim.x + t] += red[blockDim.x + t + off];
        }
        __syncthreads();
    }
    if (t < C) {
        float mean = red[t] * invN;
        float var = fmaxf(red[blockDim.x + t] * invN - mean * mean, 0.f);
        float rs = rsqrtf(var + 1e-5f);
        float sc = g[t] * rs;
        scale[t] = sc;
        shift[t] = be[t] - mean * sc;
    }
}

// ---------------- relu(bn(X[N,64])) @ Lw(64,KOUT) + lb -> U ----------------

template <int KOUT>
__global__ __launch_bounds__(256) void bnrelu_linear(const float* __restrict__ X,
                                                     const float* __restrict__ scale,
                                                     const float* __restrict__ shift,
                                                     const float* __restrict__ Lw,
                                                     const float* __restrict__ lb,
                                                     float* __restrict__ U) {
    __shared__ float tl[64 * 65];
    int t = threadIdx.x;
    int n0 = blockIdx.x * 64;
    for (int i = t * 4; i < 64 * 64; i += 1024) {
        int r = i >> 6, cc = i & 63;
        int n = n0 + r;
        float4 v = (n < NN) ? *(const float4*)&X[(size_t)n * 64 + cc] : make_float4(0, 0, 0, 0);
        float vv[4] = {v.x, v.y, v.z, v.w};
        #pragma unroll
        for (int j = 0; j < 4; ++j)
            tl[r * 65 + cc + j] = fmaxf(vv[j] * scale[cc + j] + shift[cc + j], 0.f);
    }
    __syncthreads();
    int nl = t & 63;
    int kg = (t >> 6) * (KOUT / 4);
    float acc[KOUT / 4] = {};
    for (int l = 0; l < 64; ++l) {
        float v = tl[nl * 65 + l];
        #pragma unroll
        for (int j = 0; j < KOUT / 4; ++j) acc[j] += v * Lw[l * KOUT + kg + j];
    }
    int n = n0 + nl;
    if (n < NN)
        #pragma unroll
        for (int j = 0; j < KOUT / 4; ++j)
            U[(size_t)n * KOUT + kg + j] = acc[j] + lb[kg + j];
}

// ---------------- relu(bn(U[N,CIN])) @ W(CIN,COUT) -> Hh (fp16) ----------------

template <int CIN, int COUT>
__global__ __launch_bounds__(256) void bnrelu_gemm(const float* __restrict__ U,
                                                   const float* __restrict__ scale,
                                                   const float* __restrict__ shift,
                                                   const float* __restrict__ W,
                                                   __half* __restrict__ Hh) {
    int t = threadIdx.x;
    int nl = t >> 2;
    int q = t & 3;
    int n = blockIdx.x * 64 + nl;
    if (n >= NN) return;
    constexpr int CPT = COUT / 4;
    float v[CIN];
    #pragma unroll
    for (int c = 0; c < CIN; ++c)
        v[c] = fmaxf(U[(size_t)n * CIN + c] * scale[c] + shift[c], 0.f);
    float acc[CPT] = {};
    #pragma unroll
    for (int c = 0; c < CIN; ++c) {
        #pragma unroll
        for (int j = 0; j < CPT; ++j) acc[j] += v[c] * W[c * COUT + q * CPT + j];
    }
    #pragma unroll
    for (int j = 0; j < CPT; j += 2)
        *(__half2*)&Hh[(size_t)n * COUT + q * CPT + j] = __floats2half2_rn(acc[j], acc[j + 1]);
}

// ---------------- mean-pool per graph: grid (NG, 3), block 256 = 8 rows x 32 ch ----------------

__global__ __launch_bounds__(256) void pool_kernel(const float* __restrict__ GO,
                                                   const float* __restrict__ scale,
                                                   const float* __restrict__ shift,
                                                   const int* __restrict__ goff,
                                                   float* __restrict__ pooled) {
    __shared__ float red[8][32];
    int g = blockIdx.x;
    int ch = blockIdx.y * 32 + (threadIdx.x & 31);
    int row = threadIdx.x >> 5;
    int beg = goff[g], end = goff[g + 1];
    float sc = scale[ch], sh = shift[ch];
    float s = 0.f;
    for (int n = beg + row; n < end; n += 8)
        s += fmaxf(GO[(size_t)n * 96 + ch] * sc + sh, 0.f);
    red[row][threadIdx.x & 31] = s;
    __syncthreads();
    if (row == 0) {
        #pragma unroll
        for (int r = 1; r < 8; ++r) s += red[r][threadIdx.x & 31];
        float cnt = (float)(end - beg);
        pooled[g * 96 + ch] = s / fmaxf(cnt, 1.f);
    }
}

__global__ void final_gemm(const float* __restrict__ pooled, const float* __restrict__ oW,
                           const float* __restrict__ ob, float* __restrict__ out) {
    int idx = blockIdx.x * blockDim.x + threadIdx.x;
    if (idx >= NG * 10) return;
    int g = idx / 10, k = idx % 10;
    float s = ob[k];
    for (int c = 0; c < 96; ++c) s += pooled[g * 96 + c] * oW[c * 10 + k];
    out[idx] = s;
}

// ---------------- launch ----------------

extern "C" void kernel_launch(void* const* d_in, const int* in_sizes, int n_in,
                              void* d_out, int out_size, void* d_ws, size_t ws_size,
                              hipStream_t stream) {
    const float* x   = (const float*)d_in[0];
    const int*   ei  = (const int*)d_in[1];
    const int*   bat = (const int*)d_in[2];
    const float *W1 = (const float*)d_in[3], *a1s = (const float*)d_in[4],
                *a1d = (const float*)d_in[5], *b1 = (const float*)d_in[6],
                *g1 = (const float*)d_in[7], *be1 = (const float*)d_in[8],
                *lW1 = (const float*)d_in[9], *lb1 = (const float*)d_in[10],
                *gl1 = (const float*)d_in[11], *bel1 = (const float*)d_in[12],
                *W2 = (const float*)d_in[13], *a2s = (const float*)d_in[14],
                *a2d = (const float*)d_in[15], *b2 = (const float*)d_in[16],
                *g2 = (const float*)d_in[17], *be2 = (const float*)d_in[18],
                *lW2 = (const float*)d_in[19], *lb2 = (const float*)d_in[20],
                *gl2 = (const float*)d_in[21], *bel2 = (const float*)d_in[22],
                *W3 = (const float*)d_in[23], *a3s = (const float*)d_in[24],
                *a3d = (const float*)d_in[25], *b3 = (const float*)d_in[26],
                *g3 = (const float*)d_in[27], *be3 = (const float*)d_in[28],
                *oW = (const float*)d_in[29], *ob = (const float*)d_in[30];
    float* out = (float*)d_out;

    // workspace layout
    int* iw      = (int*)d_ws;
    int* bcur    = iw;                   // NB  (memset)
    int* counts  = bcur + NB;            // NN
    int* offsets = counts + NN;          // NN+1 (padded offsets)
    int* goff    = offsets + NN + 1;     // NG+1
    int* bsum    = goff + NG + 1;        // SCAN_NB
    int* boff    = bsum + SCAN_NB;       // SCAN_NB+1
    int* srcs    = boff + SCAN_NB + 1;   // PSLOTS
    float* fw      = (float*)(srcs + PSLOTS);
    float* GOb     = fw;                         // NN*96
    float* Ub      = GOb + (size_t)NN * 96;      // NN*16
    float* SSb     = Ub + (size_t)NN * 16;       // NN*8
    float* SDb     = SSb + (size_t)NN * 8;       // NN*8
    float* partial = SDb + (size_t)NN * 8;       // STATS_BLOCKS*192
    float* scaleA  = partial + STATS_BLOCKS * 192;
    float* shiftA  = scaleA + 96;
    float* scaleB  = shiftA + 96;
    float* shiftB  = scaleB + 16;
    float* pooled  = shiftB + 16;                // NG*96
    __half* Hh     = (__half*)(pooled + NG * 96);     // NN*96 halves
    __half* wbuf   = (__half*)(Hh + (size_t)NN * 96); // PSLOTS*8 halves (layer1 max)
    unsigned* pairs = (unsigned*)GOb;            // aliases GOb during preprocessing

    const float invN = 1.0f / (float)NN;

    // ---- edge bucket sort -> padded CSR (shared by all layers) ----
    hipMemsetAsync(bcur, 0, NB * sizeof(int), stream);
    hipMemsetAsync(srcs, 0, (size_t)PSLOTS * sizeof(int), stream);
    part_pass1<<<(ET + CHUNK - 1) / CHUNK, 256, 0, stream>>>(ei, bcur, pairs);
    graph_bounds<<<3, 256, 0, stream>>>(bat, goff);
    bucket_counts<<<NB, 256, 0, stream>>>(pairs, bcur, counts);
    scan_reduce<<<SCAN_NB, 256, 0, stream>>>(counts, bsum);
    scan_bsums<<<1, 128, 0, stream>>>(bsum, SCAN_NB, boff, &offsets[NN]);
    scan_final<<<SCAN_NB, SCAN_B, 0, stream>>>(counts, boff, offsets);
    bucket_scatter<<<NB, 256, 0, stream>>>(pairs, bcur, offsets, srcs);

    // ---- layer 1 ----
    gemm1<<<(NN + 31) / 32, 256, 0, stream>>>(x, W1, Hh);
    scores_kernel<<<(NN * 8 + 255) / 256, 256, 0, stream>>>(Hh, a1s, a1d, SSb, SDb, 8, 8);
    weights_kernel<8><<<(NN + 3) / 4, 256, 0, stream>>>(SSb, SDb, offsets, counts, srcs, wbuf);
    gat_kernel<8, 8, 1><<<(NN + 3) / 4, 256, 0, stream>>>(Hh, wbuf, offsets, srcs, b1, GOb);
    stats_kernel<<<STATS_BLOCKS, 256, 2 * 256 * sizeof(float), stream>>>(GOb, NN, 64, partial);
    bn_finalize<<<1, 512, 2 * 512 * sizeof(float), stream>>>(partial, STATS_BLOCKS, 64, invN, g1, be1, scaleA, shiftA);
    bnrelu_linear<8><<<(NN + 63) / 64, 256, 0, stream>>>(GOb, scaleA, shiftA, lW1, lb1, Ub);
    stats_kernel<<<STATS_BLOCKS, 256, 2 * 256 * sizeof(float), stream>>>(Ub, NN, 8, partial);
    bn_finalize<<<1, 512, 2 * 512 * sizeof(float), stream>>>(partial, STATS_BLOCKS, 8, invN, gl1, bel1, scaleB, shiftB);

    // ---- layer 2 ----
    bnrelu_gemm<8, 64><<<(NN + 63) / 64, 256, 0, stream>>>(Ub, scaleB, shiftB, W2, Hh);
    scores_kernel<<<(NN * 4 + 255) / 256, 256, 0, stream>>>(Hh, a2s, a2d, SSb, SDb, 4, 16);
    weights_kernel<4><<<(NN + 3) / 4, 256, 0, stream>>>(SSb, SDb, offsets, counts, srcs, wbuf);
    gat_kernel<4, 16, 1><<<(NN + 3) / 4, 256, 0, stream>>>(Hh, wbuf, offsets, srcs, b2, GOb);
    stats_kernel<<<STATS_BLOCKS, 256, 2 * 256 * sizeof(float), stream>>>(GOb, NN, 64, partial);
    bn_finalize<<<1, 512, 2 * 512 * sizeof(float), stream>>>(partial, STATS_BLOCKS, 64, invN, g2, be2, scaleA, shiftA);
    bnrelu_linear<16><<<(NN + 63) / 64, 256, 0, stream>>>(GOb, scaleA, shiftA, lW2, lb2, Ub);
    stats_kernel<<<STATS_BLOCKS, 256, 2 * 256 * sizeof(float), stream>>>(Ub, NN, 16, partial);
    bn_finalize<<<1, 512, 2 * 512 * sizeof(float), stream>>>(partial, STATS_BLOCKS, 16, invN, gl2, bel2, scaleB, shiftB);

    // ---- layer 3 ----
    bnrelu_gemm<16, 96><<<(NN + 63) / 64, 256, 0, stream>>>(Ub, scaleB, shiftB, W3, Hh);
    scores_kernel<<<(NN * 4 + 255) / 256, 256, 0, stream>>>(Hh, a3s, a3d, SSb, SDb, 4, 24);
    weights_kernel<4><<<(NN + 3) / 4, 256, 0, stream>>>(SSb, SDb, offsets, counts, srcs, wbuf);
    gat_kernel<4, 24, 2><<<(NN + 3) / 4, 256, 0, stream>>>(Hh, wbuf, offsets, srcs, b3, GOb);
    stats_kernel<<<STATS_BLOCKS, 192, 2 * 192 * sizeof(float), stream>>>(GOb, NN, 96, partial);
    bn_finalize<<<1, 768, 2 * 768 * sizeof(float), stream>>>(partial, STATS_BLOCKS, 96, invN, g3, be3, scaleA, shiftA);

    // ---- pool + head ----
    pool_kernel<<<dim3(NG, 3), 256, 0, stream>>>(GOb, scaleA, shiftA, goff, pooled);
    final_gemm<<<(NG * 10 + 255) / 256, 256, 0, stream>>>(pooled, oW, ob, out);
}

// Round 10
// 693.013 us; speedup vs baseline: 2.4455x; 1.0088x over previous
//
#include <hip/hip_runtime.h>
#include <hip/hip_fp16.h>
#include <math.h>

#define NN 100000
#define NE 1600000
#define ET (NE + NN)      // edges + self loops
#define NG 512
#define STATS_BLOCKS 240
#define SCAN_B 1024
#define SCAN_NB ((NN + SCAN_B - 1) / SCAN_B)   // 98
#define PSLOTS (ET + 7 * NN)                   // padded edge-slot capacity (2.4M)

// bucket sort params
#define BSH 9                      // 512 nodes per bucket
#define NB  ((NN + 511) / 512)     // 196 buckets
#define BCAP 12288                 // cap per bucket (mean ~8700)
#define CHUNK 4096

// ---------------- pass1: partition edges into coarse buckets ----------------

__global__ __launch_bounds__(256) void part_pass1(const int* __restrict__ ei,
                                                  int* __restrict__ bcur,
                                                  unsigned* __restrict__ pairs) {
    __shared__ unsigned pck[CHUNK];
    __shared__ unsigned ordv[CHUNK];
    __shared__ unsigned char bkt[CHUNK];
    __shared__ unsigned char obkt[CHUNK];
    __shared__ int hist[NB + 1];
    __shared__ int lofs[NB + 1];
    __shared__ int cur[NB + 1];
    __shared__ int gpos[NB];
    __shared__ int lh[256];

    int t = threadIdx.x;
    int base = blockIdx.x * CHUNK;
    for (int i = t; i <= NB; i += 256) hist[i] = 0;
    __syncthreads();
    for (int i = t; i < CHUNK; i += 256) {
        int e = base + i;
        int b;
        unsigned p = 0;
        if (e < ET) {
            int s, d;
            if (e < NE) { s = ei[e]; d = ei[NE + e]; }
            else        { s = d = e - NE; }
            b = d >> BSH;
            p = ((unsigned)s << BSH) | (unsigned)(d & 511);
        } else b = NB;
        bkt[i] = (unsigned char)b;
        pck[i] = p;
        atomicAdd(&hist[b], 1);
    }
    __syncthreads();
    int v = (t <= NB) ? hist[t] : 0;
    lh[t] = v;
    __syncthreads();
    for (int off = 1; off < 256; off <<= 1) {
        int x = (t >= off) ? lh[t - off] : 0;
        __syncthreads();
        lh[t] += x;
        __syncthreads();
    }
    if (t <= NB) { lofs[t] = lh[t] - v; cur[t] = lh[t] - v; }
    __syncthreads();
    if (t < NB) {
        int h = hist[t];
        gpos[t] = (h > 0) ? atomicAdd(&bcur[t], h) : 0;
    }
    __syncthreads();
    for (int i = t; i < CHUNK; i += 256) {
        int b = bkt[i];
        int pos = atomicAdd(&cur[b], 1);
        ordv[pos] = pck[i];
        obkt[pos] = (unsigned char)b;
    }
    __syncthreads();
    int nvalid = lofs[NB];
    for (int i = t; i < nvalid; i += 256) {
        int b = obkt[i];
        int dst = gpos[b] + (i - lofs[b]);
        if (dst < BCAP) pairs[(size_t)b * BCAP + dst] = ordv[i];
    }
}

// ---------------- pass2a: per-bucket node counts ----------------

__global__ __launch_bounds__(256) void bucket_counts(const unsigned* __restrict__ pairs,
                                                     const int* __restrict__ bcur,
                                                     int* __restrict__ counts) {
    __shared__ int lhist[512];
    int b = blockIdx.x;
    int t = threadIdx.x;
    for (int i = t; i < 512; i += 256) lhist[i] = 0;
    __syncthreads();
    int cnt = min(bcur[b], BCAP);
    const unsigned* seg = pairs + (size_t)b * BCAP;
    for (int i = t; i < cnt; i += 256)
        atomicAdd(&lhist[seg[i] & 511], 1);
    __syncthreads();
    int nbase = b << BSH;
    for (int i = t; i < 512; i += 256) {
        int n = nbase + i;
        if (n < NN) counts[n] = lhist[i];
    }
}

// ---------------- pass2b: per-bucket scatter into padded srcs ----------------

__global__ __launch_bounds__(256) void bucket_scatter(const unsigned* __restrict__ pairs,
                                                      const int* __restrict__ bcur,
                                                      const int* __restrict__ offsets,
                                                      int* __restrict__ srcs) {
    __shared__ int cur[512];
    int b = blockIdx.x;
    int t = threadIdx.x;
    int nbase = b << BSH;
    for (int i = t; i < 512; i += 256) {
        int n = nbase + i;
        cur[i] = (n < NN) ? offsets[n] : 0;
    }
    __syncthreads();
    int cnt = min(bcur[b], BCAP);
    const unsigned* seg = pairs + (size_t)b * BCAP;
    for (int i = t; i < cnt; i += 256) {
        unsigned p = seg[i];
        int pos = atomicAdd(&cur[p & 511], 1);
        srcs[pos] = (int)(p >> BSH);
    }
}

// ---------------- graph boundaries via binary search (batch is sorted) ----------------

__global__ void graph_bounds(const int* __restrict__ batch, int* __restrict__ goff) {
    int g = blockIdx.x * blockDim.x + threadIdx.x;
    if (g > NG) return;
    int lo = 0, hi = NN;
    while (lo < hi) {
        int mid = (lo + hi) >> 1;
        if (batch[mid] < g) lo = mid + 1; else hi = mid;
    }
    goff[g] = lo;
}

// ---------------- scans (counts rounded up to x8 inline -> padded offsets) ----------------

__global__ void scan_reduce(const int* __restrict__ in, int* __restrict__ bsum) {
    __shared__ int lds[256];
    int b = blockIdx.x, t = threadIdx.x;
    int s = 0;
    for (int i = t; i < SCAN_B; i += 256) {
        int idx = b * SCAN_B + i;
        if (idx < NN) s += (in[idx] + 7) & ~7;
    }
    lds[t] = s;
    __syncthreads();
    for (int off = 128; off > 0; off >>= 1) {
        if (t < off) lds[t] += lds[t + off];
        __syncthreads();
    }
    if (t == 0) bsum[b] = lds[0];
}

__global__ void scan_bsums(const int* __restrict__ bsum, int nb, int* __restrict__ boff,
                           int* __restrict__ total_loc) {
    __shared__ int lds[128];
    int t = threadIdx.x;
    int v = (t < nb) ? bsum[t] : 0;
    lds[t] = v;
    __syncthreads();
    for (int off = 1; off < 128; off <<= 1) {
        int x = (t >= off) ? lds[t - off] : 0;
        __syncthreads();
        lds[t] += x;
        __syncthreads();
    }
    if (t < nb) boff[t] = lds[t] - v;
    if (t == nb - 1) {
        boff[nb] = lds[t];
        if (total_loc) *total_loc = lds[t];
    }
}

__global__ void scan_final(const int* __restrict__ in, const int* __restrict__ boff,
                           int* __restrict__ out) {
    __shared__ int lds[SCAN_B];
    int b = blockIdx.x, t = threadIdx.x;
    int idx = b * SCAN_B + t;
    int v = (idx < NN) ? ((in[idx] + 7) & ~7) : 0;
    lds[t] = v;
    __syncthreads();
    for (int off = 1; off < SCAN_B; off <<= 1) {
        int x = (t >= off) ? lds[t - off] : 0;
        __syncthreads();
        lds[t] += x;
        __syncthreads();
    }
    if (idx < NN) out[idx] = boff[b] + lds[t] - v;
}

// ---------------- gemm1: Hh = fp16( X(N,128) @ W(128,64) ) ----------------

__global__ __launch_bounds__(256) void gemm1(const float* __restrict__ X,
                                             const float* __restrict__ W,
                                             __half* __restrict__ Hh) {
    __shared__ float wl[128 * 64];
    __shared__ float xl[32 * 132];
    int t = threadIdx.x;
    int n0 = blockIdx.x * 32;
    for (int i = t * 4; i < 128 * 64; i += 1024)
        *(float4*)&wl[i] = *(const float4*)&W[i];
    for (int i = t * 4; i < 32 * 128; i += 1024) {
        int r = i >> 7, c = i & 127;
        int n = n0 + r;
        float4 v = (n < NN) ? *(const float4*)&X[(size_t)n * 128 + c] : make_float4(0, 0, 0, 0);
        *(float4*)&xl[r * 132 + c] = v;
    }
    __syncthreads();
    int cg = (t & 15) * 4;
    int ng = (t >> 4) * 2;
    float acc[2][4] = {};
    for (int k = 0; k < 128; ++k) {
        float4 w4 = *(float4*)&wl[k * 64 + cg];
        #pragma unroll
        for (int j = 0; j < 2; ++j) {
            float xv = xl[(ng + j) * 132 + k];
            acc[j][0] += xv * w4.x; acc[j][1] += xv * w4.y;
            acc[j][2] += xv * w4.z; acc[j][3] += xv * w4.w;
        }
    }
    #pragma unroll
    for (int j = 0; j < 2; ++j) {
        int n = n0 + ng + j;
        if (n < NN) {
            __half2 p0 = __floats2half2_rn(acc[j][0], acc[j][1]);
            __half2 p1 = __floats2half2_rn(acc[j][2], acc[j][3]);
            *(__half2*)&Hh[(size_t)n * 64 + cg] = p0;
            *(__half2*)&Hh[(size_t)n * 64 + cg + 2] = p1;
        }
    }
}

// ---------------- per-node attention scores (from fp16 H) ----------------

__global__ void scores_kernel(const __half* __restrict__ Hh, const float* __restrict__ a_s,
                              const float* __restrict__ a_d, float* __restrict__ SS,
                              float* __restrict__ SD, int HEADS, int C) {
    int idx = blockIdx.x * blockDim.x + threadIdx.x;
    if (idx >= NN * HEADS) return;
    int n = idx / HEADS, h = idx % HEADS;
    const __half* row = Hh + (size_t)n * HEADS * C + h * C;
    float s1 = 0.f, s2 = 0.f;
    for (int c = 0; c < C; c += 2) {
        float2 v = __half22float2(*(const __half2*)&row[c]);
        s1 += v.x * a_s[h * C + c] + v.y * a_s[h * C + c + 1];
        s2 += v.x * a_d[h * C + c] + v.y * a_d[h * C + c + 1];
    }
    SS[idx] = s1;
    SD[idx] = s2;
}

// ---------------- per-(edge,head) softmax numerators, wave per dst node ----------------
// `slot < end` guard: SPG may exceed the 8-slot padding granularity (R5 race lesson).

template <int H>
__global__ __launch_bounds__(256) void weights_kernel(const float* __restrict__ SS,
                                                      const float* __restrict__ SD,
                                                      const int* __restrict__ offsets,
                                                      const int* __restrict__ counts,
                                                      const int* __restrict__ srcs,
                                                      __half* __restrict__ w) {
    int wid = blockIdx.x * 4 + (threadIdx.x >> 6);
    if (wid >= NN) return;
    int lane = threadIdx.x & 63;
    constexpr int SPG = 64 / H;        // slots per iteration
    int so = lane / H, h = lane % H;
    int beg = offsets[wid], end = offsets[wid + 1];
    int deg = counts[wid];
    float sdv = SD[(unsigned)wid * H + h];
    for (int g = beg; g < end; g += SPG) {
        int slot = g + so;
        if (slot < end) {
            int src = srcs[slot];
            float sc = SS[(unsigned)src * H + h] + sdv;
            sc = sc > 0.f ? sc : 0.2f * sc;
            float wv = (slot - beg) < deg ? __expf(sc) : 0.f;
            w[(unsigned)slot * H + h] = __float2half(wv);
        }
    }
}

// ---------------- GAT gather: streaming weighted sum; GRP=16 deepens MLP (PL=1 only) ----------------

template <int HEADS, int C, int PL, int GRP>
__global__ __launch_bounds__(256) void gat_kernel(const __half* __restrict__ Hh,
                                                  const __half* __restrict__ w,
                                                  const int* __restrict__ offsets,
                                                  const int* __restrict__ srcs,
                                                  const float* __restrict__ bias,
                                                  __half* __restrict__ GO) {
    constexpr int CH = HEADS * C;  // 64 or 96
    int wid = blockIdx.x * (blockDim.x >> 6) + (threadIdx.x >> 6);
    int lane = threadIdx.x & 63;
    if (wid >= NN) return;
    int ch0 = lane * PL;
    bool active = ch0 < CH;
    int ch0l = active ? ch0 : 0;
    int head = active ? (ch0 / C) : 0;
    int beg = offsets[wid], end = offsets[wid + 1];
    float s = 0.f, a0 = 0.f, a1 = 0.f;
    int e = beg;
    if (GRP == 16) {
        for (; e + 16 <= end; e += 16) {
            int sv[16];
            float wv[16];
            #pragma unroll
            for (int i = 0; i < 16; ++i) {
                sv[i] = srcs[e + i];
                wv[i] = __half2float(w[(unsigned)(e + i) * HEADS + head]);
            }
            float hv0[16];
            #pragma unroll
            for (int i = 0; i < 16; ++i)
                hv0[i] = __half2float(Hh[(unsigned)(sv[i] * CH) + ch0l]);
            float pw[8], pa[8];
            #pragma unroll
            for (int i = 0; i < 8; ++i) {
                pw[i] = wv[2 * i] + wv[2 * i + 1];
                pa[i] = wv[2 * i] * hv0[2 * i] + wv[2 * i + 1] * hv0[2 * i + 1];
            }
            s  += ((pw[0] + pw[1]) + (pw[2] + pw[3])) + ((pw[4] + pw[5]) + (pw[6] + pw[7]));
            a0 += ((pa[0] + pa[1]) + (pa[2] + pa[3])) + ((pa[4] + pa[5]) + (pa[6] + pa[7]));
        }
    }
    for (; e < end; e += 8) {
        int sv[8];
        float wv[8];
        #pragma unroll
        for (int i = 0; i < 8; ++i) {
            sv[i] = srcs[e + i];
            wv[i] = __half2float(w[(unsigned)(e + i) * HEADS + head]);
        }
        float hv0[8], hv1[8];
        #pragma unroll
        for (int i = 0; i < 8; ++i) {
            if (PL == 2) {
                __half2 hp = *(const __half2*)&Hh[(unsigned)(sv[i] * CH) + ch0l];
                hv0[i] = __low2float(hp); hv1[i] = __high2float(hp);
            } else {
                hv0[i] = __half2float(Hh[(unsigned)(sv[i] * CH) + ch0l]);
                hv1[i] = 0.f;
            }
        }
        float ws = ((wv[0] + wv[1]) + (wv[2] + wv[3])) + ((wv[4] + wv[5]) + (wv[6] + wv[7]));
        float as0 = ((wv[0] * hv0[0] + wv[1] * hv0[1]) + (wv[2] * hv0[2] + wv[3] * hv0[3]))
                  + ((wv[4] * hv0[4] + wv[5] * hv0[5]) + (wv[6] * hv0[6] + wv[7] * hv0[7]));
        s += ws;
        a0 += as0;
        if (PL == 2) {
            float as1 = ((wv[0] * hv1[0] + wv[1] * hv1[1]) + (wv[2] * hv1[2] + wv[3] * hv1[3]))
                      + ((wv[4] * hv1[4] + wv[5] * hv1[5]) + (wv[6] * hv1[6] + wv[7] * hv1[7]));
            a1 += as1;
        }
    }
    if (active) {
        float inv = 1.f / s;
        if (PL == 2) {
            *(__half2*)&GO[(unsigned)(wid * CH) + ch0] =
                __floats2half2_rn(a0 * inv + bias[ch0], a1 * inv + bias[ch0 + 1]);
        } else {
            GO[(unsigned)(wid * CH) + ch0] = __float2half(a0 * inv + bias[ch0]);
        }
    }
}

// ---------------- BN stats (deterministic two-stage) ----------------

__global__ void stats_kernel(const float* __restrict__ X, int Nn, int C,
                             float* __restrict__ partial) {
    int t = threadIdx.x;
    int c = t % C;
    int grp = t / C;
    int G_ = blockDim.x / C;
    float s = 0.f, q = 0.f;
    for (int n = blockIdx.x * G_ + grp; n < Nn; n += gridDim.x * G_) {
        float v = X[(size_t)n * C + c];
        s += v; q += v * v;
    }
    extern __shared__ float lds[];
    lds[t] = s; lds[blockDim.x + t] = q;
    __syncthreads();
    for (int off = blockDim.x >> 1; off >= C; off >>= 1) {
        if (t < off) {
            lds[t] += lds[t + off];
            lds[blockDim.x + t] += lds[blockDim.x + t + off];
        }
        __syncthreads();
    }
    if (t < C) {
        partial[(size_t)blockIdx.x * 2 * C + t] = lds[t];
        partial[(size_t)blockIdx.x * 2 * C + C + t] = lds[blockDim.x + t];
    }
}

__global__ void stats_h_kernel(const __half* __restrict__ X, int Nn, int C,
                               float* __restrict__ partial) {
    int t = threadIdx.x;
    int c = t % C;
    int grp = t / C;
    int G_ = blockDim.x / C;
    float s = 0.f, q = 0.f;
    for (int n = blockIdx.x * G_ + grp; n < Nn; n += gridDim.x * G_) {
        float v = __half2float(X[(size_t)n * C + c]);
        s += v; q += v * v;
    }
    extern __shared__ float lds[];
    lds[t] = s; lds[blockDim.x + t] = q;
    __syncthreads();
    for (int off = blockDim.x >> 1; off >= C; off >>= 1) {
        if (t < off) {
            lds[t] += lds[t + off];
            lds[blockDim.x + t] += lds[blockDim.x + t + off];
        }
        __syncthreads();
    }
    if (t < C) {
        partial[(size_t)blockIdx.x * 2 * C + t] = lds[t];
        partial[(size_t)blockIdx.x * 2 * C + C + t] = lds[blockDim.x + t];
    }
}

// parallel finalize: blockDim = C * G (G pow2), LDS tree reduce
__global__ void bn_finalize(const float* __restrict__ partial, int nb, int C, float invN,
                            const float* __restrict__ g, const float* __restrict__ be,
                            float* __restrict__ scale, float* __restrict__ shift) {
    extern __shared__ float red[];
    int t = threadIdx.x;
    int c = t % C;
    int grp = t / C;
    int G_ = blockDim.x / C;
    float s = 0.f, q = 0.f;
    for (int b = grp; b < nb; b += G_) {
        s += partial[(size_t)b * 2 * C + c];
        q += partial[(size_t)b * 2 * C + C + c];
    }
    red[t] = s; red[blockDim.x + t] = q;
    __syncthreads();
    for (int off = blockDim.x >> 1; off >= C; off >>= 1) {
        if (t < off) {
            red[t] += red[t + off];
            red[blockDim.x + t] += red[blockDim.x + t + off];
        }
        __syncthreads();
    }
    if (t < C) {
        float mean = red[t] * invN;
        float var = fmaxf(red[blockDim.x + t] * invN - mean * mean, 0.f);
        float rs = rsqrtf(var + 1e-5f);
        float sc = g[t] * rs;
        scale[t] = sc;
        shift[t] = be[t] - mean * sc;
    }
}

// ---------------- relu(bn(X[N,64] fp16)) @ Lw(64,KOUT) + lb -> U ----------------

template <int KOUT>
__global__ __launch_bounds__(256) void bnrelu_linear(const __half* __restrict__ X,
                                                     const float* __restrict__ scale,
                                                     const float* __restrict__ shift,
                                                     const float* __restrict__ Lw,
                                                     const float* __restrict__ lb,
                                                     float* __restrict__ U) {
    __shared__ float tl[64 * 65];
    int t = threadIdx.x;
    int n0 = blockIdx.x * 64;
    for (int i = t * 4; i < 64 * 64; i += 1024) {
        int r = i >> 6, cc = i & 63;
        int n = n0 + r;
        float vv[4] = {0.f, 0.f, 0.f, 0.f};
        if (n < NN) {
            float2 v0 = __half22float2(*(const __half2*)&X[(size_t)n * 64 + cc]);
            float2 v1 = __half22float2(*(const __half2*)&X[(size_t)n * 64 + cc + 2]);
            vv[0] = v0.x; vv[1] = v0.y; vv[2] = v1.x; vv[3] = v1.y;
        }
        #pragma unroll
        for (int j = 0; j < 4; ++j)
            tl[r * 65 + cc + j] = fmaxf(vv[j] * scale[cc + j] + shift[cc + j], 0.f);
    }
    __syncthreads();
    int nl = t & 63;
    int kg = (t >> 6) * (KOUT / 4);
    float acc[KOUT / 4] = {};
    for (int l = 0; l < 64; ++l) {
        float v = tl[nl * 65 + l];
        #pragma unroll
        for (int j = 0; j < KOUT / 4; ++j) acc[j] += v * Lw[l * KOUT + kg + j];
    }
    int n = n0 + nl;
    if (n < NN)
        #pragma unroll
        for (int j = 0; j < KOUT / 4; ++j)
            U[(size_t)n * KOUT + kg + j] = acc[j] + lb[kg + j];
}

// ---------------- relu(bn(U[N,CIN])) @ W(CIN,COUT) -> Hh (fp16) ----------------

template <int CIN, int COUT>
__global__ __launch_bounds__(256) void bnrelu_gemm(const float* __restrict__ U,
                                                   const float* __restrict__ scale,
                                                   const float* __restrict__ shift,
                                                   const float* __restrict__ W,
                                                   __half* __restrict__ Hh) {
    int t = threadIdx.x;
    int nl = t >> 2;
    int q = t & 3;
    int n = blockIdx.x * 64 + nl;
    if (n >= NN) return;
    constexpr int CPT = COUT / 4;
    float v[CIN];
    #pragma unroll
    for (int c = 0; c < CIN; ++c)
        v[c] = fmaxf(U[(size_t)n * CIN + c] * scale[c] + shift[c], 0.f);
    float acc[CPT] = {};
    #pragma unroll
    for (int c = 0; c < CIN; ++c) {
        #pragma unroll
        for (int j = 0; j < CPT; ++j) acc[j] += v[c] * W[c * COUT + q * CPT + j];
    }
    #pragma unroll
    for (int j = 0; j < CPT; j += 2)
        *(__half2*)&Hh[(size_t)n * COUT + q * CPT + j] = __floats2half2_rn(acc[j], acc[j + 1]);
}

// ---------------- mean-pool per graph: grid (NG, 3), block 256 = 8 rows x 32 ch ----------------

__global__ __launch_bounds__(256) void pool_kernel(const __half* __restrict__ GO,
                                                   const float* __restrict__ scale,
                                                   const float* __restrict__ shift,
                                                   const int* __restrict__ goff,
                                                   float* __restrict__ pooled) {
    __shared__ float red[8][32];
    int g = blockIdx.x;
    int ch = blockIdx.y * 32 + (threadIdx.x & 31);
    int row = threadIdx.x >> 5;
    int beg = goff[g], end = goff[g + 1];
    float sc = scale[ch], sh = shift[ch];
    float s = 0.f;
    for (int n = beg + row; n < end; n += 8)
        s += fmaxf(__half2float(GO[(size_t)n * 96 + ch]) * sc + sh, 0.f);
    red[row][threadIdx.x & 31] = s;
    __syncthreads();
    if (row == 0) {
        #pragma unroll
        for (int r = 1; r < 8; ++r) s += red[r][threadIdx.x & 31];
        float cnt = (float)(end - beg);
        pooled[g * 96 + ch] = s / fmaxf(cnt, 1.f);
    }
}

__global__ void final_gemm(const float* __restrict__ pooled, const float* __restrict__ oW,
                           const float* __restrict__ ob, float* __restrict__ out) {
    int idx = blockIdx.x * blockDim.x + threadIdx.x;
    if (idx >= NG * 10) return;
    int g = idx / 10, k = idx % 10;
    float s = ob[k];
    for (int c = 0; c < 96; ++c) s += pooled[g * 96 + c] * oW[c * 10 + k];
    out[idx] = s;
}

// ---------------- launch ----------------

extern "C" void kernel_launch(void* const* d_in, const int* in_sizes, int n_in,
                              void* d_out, int out_size, void* d_ws, size_t ws_size,
                              hipStream_t stream) {
    const float* x   = (const float*)d_in[0];
    const int*   ei  = (const int*)d_in[1];
    const int*   bat = (const int*)d_in[2];
    const float *W1 = (const float*)d_in[3], *a1s = (const float*)d_in[4],
                *a1d = (const float*)d_in[5], *b1 = (const float*)d_in[6],
                *g1 = (const float*)d_in[7], *be1 = (const float*)d_in[8],
                *lW1 = (const float*)d_in[9], *lb1 = (const float*)d_in[10],
                *gl1 = (const float*)d_in[11], *bel1 = (const float*)d_in[12],
                *W2 = (const float*)d_in[13], *a2s = (const float*)d_in[14],
                *a2d = (const float*)d_in[15], *b2 = (const float*)d_in[16],
                *g2 = (const float*)d_in[17], *be2 = (const float*)d_in[18],
                *lW2 = (const float*)d_in[19], *lb2 = (const float*)d_in[20],
                *gl2 = (const float*)d_in[21], *bel2 = (const float*)d_in[22],
                *W3 = (const float*)d_in[23], *a3s = (const float*)d_in[24],
                *a3d = (const float*)d_in[25], *b3 = (const float*)d_in[26],
                *g3 = (const float*)d_in[27], *be3 = (const float*)d_in[28],
                *oW = (const float*)d_in[29], *ob = (const float*)d_in[30];
    float* out = (float*)d_out;

    // workspace layout
    int* iw      = (int*)d_ws;
    int* bcur    = iw;                   // NB  (memset)
    int* counts  = bcur + NB;            // NN
    int* offsets = counts + NN;          // NN+1 (padded offsets)
    int* goff    = offsets + NN + 1;     // NG+1
    int* bsum    = goff + NG + 1;        // SCAN_NB
    int* boff    = bsum + SCAN_NB;       // SCAN_NB+1
    int* srcs    = boff + SCAN_NB + 1;   // PSLOTS
    float* fw      = (float*)(srcs + PSLOTS);
    __half* GOh    = (__half*)fw;                // NN*96 halves (region reserved NN*96 floats)
    float* Ub      = fw + (size_t)NN * 96;       // NN*16
    float* SSb     = Ub + (size_t)NN * 16;       // NN*8
    float* SDb     = SSb + (size_t)NN * 8;       // NN*8
    float* partial = SDb + (size_t)NN * 8;       // STATS_BLOCKS*192
    float* scaleA  = partial + STATS_BLOCKS * 192;
    float* shiftA  = scaleA + 96;
    float* scaleB  = shiftA + 96;
    float* shiftB  = scaleB + 16;
    float* pooled  = shiftB + 16;                // NG*96
    __half* Hh     = (__half*)(pooled + NG * 96);     // NN*96 halves
    __half* wbuf   = (__half*)(Hh + (size_t)NN * 96); // PSLOTS*8 halves (layer1 max)
    unsigned* pairs = (unsigned*)GOh;            // aliases GO region during preprocessing

    const float invN = 1.0f / (float)NN;

    // ---- edge bucket sort -> padded CSR (shared by all layers) ----
    hipMemsetAsync(bcur, 0, NB * sizeof(int), stream);
    hipMemsetAsync(srcs, 0, (size_t)PSLOTS * sizeof(int), stream);
    part_pass1<<<(ET + CHUNK - 1) / CHUNK, 256, 0, stream>>>(ei, bcur, pairs);
    graph_bounds<<<3, 256, 0, stream>>>(bat, goff);
    bucket_counts<<<NB, 256, 0, stream>>>(pairs, bcur, counts);
    scan_reduce<<<SCAN_NB, 256, 0, stream>>>(counts, bsum);
    scan_bsums<<<1, 128, 0, stream>>>(bsum, SCAN_NB, boff, &offsets[NN]);
    scan_final<<<SCAN_NB, SCAN_B, 0, stream>>>(counts, boff, offsets);
    bucket_scatter<<<NB, 256, 0, stream>>>(pairs, bcur, offsets, srcs);

    // ---- layer 1 ----
    gemm1<<<(NN + 31) / 32, 256, 0, stream>>>(x, W1, Hh);
    scores_kernel<<<(NN * 8 + 255) / 256, 256, 0, stream>>>(Hh, a1s, a1d, SSb, SDb, 8, 8);
    weights_kernel<8><<<(NN + 3) / 4, 256, 0, stream>>>(SSb, SDb, offsets, counts, srcs, wbuf);
    gat_kernel<8, 8, 1, 16><<<(NN + 3) / 4, 256, 0, stream>>>(Hh, wbuf, offsets, srcs, b1, GOh);
    stats_h_kernel<<<STATS_BLOCKS, 256, 2 * 256 * sizeof(float), stream>>>(GOh, NN, 64, partial);
    bn_finalize<<<1, 512, 2 * 512 * sizeof(float), stream>>>(partial, STATS_BLOCKS, 64, invN, g1, be1, scaleA, shiftA);
    bnrelu_linear<8><<<(NN + 63) / 64, 256, 0, stream>>>(GOh, scaleA, shiftA, lW1, lb1, Ub);
    stats_kernel<<<STATS_BLOCKS, 256, 2 * 256 * sizeof(float), stream>>>(Ub, NN, 8, partial);
    bn_finalize<<<1, 512, 2 * 512 * sizeof(float), stream>>>(partial, STATS_BLOCKS, 8, invN, gl1, bel1, scaleB, shiftB);

    // ---- layer 2 ----
    bnrelu_gemm<8, 64><<<(NN + 63) / 64, 256, 0, stream>>>(Ub, scaleB, shiftB, W2, Hh);
    scores_kernel<<<(NN * 4 + 255) / 256, 256, 0, stream>>>(Hh, a2s, a2d, SSb, SDb, 4, 16);
    weights_kernel<4><<<(NN + 3) / 4, 256, 0, stream>>>(SSb, SDb, offsets, counts, srcs, wbuf);
    gat_kernel<4, 16, 1, 16><<<(NN + 3) / 4, 256, 0, stream>>>(Hh, wbuf, offsets, srcs, b2, GOh);
    stats_h_kernel<<<STATS_BLOCKS, 256, 2 * 256 * sizeof(float), stream>>>(GOh, NN, 64, partial);
    bn_finalize<<<1, 512, 2 * 512 * sizeof(float), stream>>>(partial, STATS_BLOCKS, 64, invN, g2, be2, scaleA, shiftA);
    bnrelu_linear<16><<<(NN + 63) / 64, 256, 0, stream>>>(GOh, scaleA, shiftA, lW2, lb2, Ub);
    stats_kernel<<<STATS_BLOCKS, 256, 2 * 256 * sizeof(float), stream>>>(Ub, NN, 16, partial);
    bn_finalize<<<1, 512, 2 * 512 * sizeof(float), stream>>>(partial, STATS_BLOCKS, 16, invN, gl2, bel2, scaleB, shiftB);

    // ---- layer 3 ----
    bnrelu_gemm<16, 96><<<(NN + 63) / 64, 256, 0, stream>>>(Ub, scaleB, shiftB, W3, Hh);
    scores_kernel<<<(NN * 4 + 255) / 256, 256, 0, stream>>>(Hh, a3s, a3d, SSb, SDb, 4, 24);
    weights_kernel<4><<<(NN + 3) / 4, 256, 0, stream>>>(SSb, SDb, offsets, counts, srcs, wbuf);
    gat_kernel<4, 24, 2, 8><<<(NN + 3) / 4, 256, 0, stream>>>(Hh, wbuf, offsets, srcs, b3, GOh);
    stats_h_kernel<<<STATS_BLOCKS, 192, 2 * 192 * sizeof(float), stream>>>(GOh, NN, 96, partial);
    bn_finalize<<<1, 768, 2 * 768 * sizeof(float), stream>>>(partial, STATS_BLOCKS, 96, invN, g3, be3, scaleA, shiftA);

    // ---- pool + head ----
    pool_kernel<<<dim3(NG, 3), 256, 0, stream>>>(GOh, scaleA, shiftA, goff, pooled);
    final_gemm<<<(NG * 10 + 255) / 256, 256, 0, stream>>>(pooled, oW, ob, out);
}

// Round 11
// 607.382 us; speedup vs baseline: 2.7902x; 1.1410x over previous
//
#include <hip/hip_runtime.h>
#include <hip/hip_fp16.h>
#include <math.h>

#define NN 100000
#define NE 1600000
#define ET (NE + NN)      // edges + self loops
#define NG 512
#define STATS_BLOCKS 240
#define SCAN_B 1024
#define SCAN_NB ((NN + SCAN_B - 1) / SCAN_B)   // 98
#define PSLOTS (ET + 7 * NN)                   // padded edge-slot capacity (2.4M)

// bucket sort params
#define BSH 9                      // 512 nodes per bucket
#define NB  ((NN + 511) / 512)     // 196 buckets
#define BCAP 12288                 // cap per bucket (mean ~8700)
#define CHUNK 4096

// ---------------- pass1: partition edges into coarse buckets ----------------

__global__ __launch_bounds__(256) void part_pass1(const int* __restrict__ ei,
                                                  int* __restrict__ bcur,
                                                  unsigned* __restrict__ pairs) {
    __shared__ unsigned pck[CHUNK];
    __shared__ unsigned ordv[CHUNK];
    __shared__ unsigned char bkt[CHUNK];
    __shared__ unsigned char obkt[CHUNK];
    __shared__ int hist[NB + 1];
    __shared__ int lofs[NB + 1];
    __shared__ int cur[NB + 1];
    __shared__ int gpos[NB];
    __shared__ int lh[256];

    int t = threadIdx.x;
    int base = blockIdx.x * CHUNK;
    for (int i = t; i <= NB; i += 256) hist[i] = 0;
    __syncthreads();
    for (int i = t; i < CHUNK; i += 256) {
        int e = base + i;
        int b;
        unsigned p = 0;
        if (e < ET) {
            int s, d;
            if (e < NE) { s = ei[e]; d = ei[NE + e]; }
            else        { s = d = e - NE; }
            b = d >> BSH;
            p = ((unsigned)s << BSH) | (unsigned)(d & 511);
        } else b = NB;
        bkt[i] = (unsigned char)b;
        pck[i] = p;
        atomicAdd(&hist[b], 1);
    }
    __syncthreads();
    int v = (t <= NB) ? hist[t] : 0;
    lh[t] = v;
    __syncthreads();
    for (int off = 1; off < 256; off <<= 1) {
        int x = (t >= off) ? lh[t - off] : 0;
        __syncthreads();
        lh[t] += x;
        __syncthreads();
    }
    if (t <= NB) { lofs[t] = lh[t] - v; cur[t] = lh[t] - v; }
    __syncthreads();
    if (t < NB) {
        int h = hist[t];
        gpos[t] = (h > 0) ? atomicAdd(&bcur[t], h) : 0;
    }
    __syncthreads();
    for (int i = t; i < CHUNK; i += 256) {
        int b = bkt[i];
        int pos = atomicAdd(&cur[b], 1);
        ordv[pos] = pck[i];
        obkt[pos] = (unsigned char)b;
    }
    __syncthreads();
    int nvalid = lofs[NB];
    for (int i = t; i < nvalid; i += 256) {
        int b = obkt[i];
        int dst = gpos[b] + (i - lofs[b]);
        if (dst < BCAP) pairs[(size_t)b * BCAP + dst] = ordv[i];
    }
}

// ---------------- pass2a: per-bucket node counts ----------------

__global__ __launch_bounds__(256) void bucket_counts(const unsigned* __restrict__ pairs,
                                                     const int* __restrict__ bcur,
                                                     int* __restrict__ counts) {
    __shared__ int lhist[512];
    int b = blockIdx.x;
    int t = threadIdx.x;
    for (int i = t; i < 512; i += 256) lhist[i] = 0;
    __syncthreads();
    int cnt = min(bcur[b], BCAP);
    const unsigned* seg = pairs + (size_t)b * BCAP;
    for (int i = t; i < cnt; i += 256)
        atomicAdd(&lhist[seg[i] & 511], 1);
    __syncthreads();
    int nbase = b << BSH;
    for (int i = t; i < 512; i += 256) {
        int n = nbase + i;
        if (n < NN) counts[n] = lhist[i];
    }
}

// ---------------- pass2b: per-bucket scatter into padded srcs ----------------

__global__ __launch_bounds__(256) void bucket_scatter(const unsigned* __restrict__ pairs,
                                                      const int* __restrict__ bcur,
                                                      const int* __restrict__ offsets,
                                                      int* __restrict__ srcs) {
    __shared__ int cur[512];
    int b = blockIdx.x;
    int t = threadIdx.x;
    int nbase = b << BSH;
    for (int i = t; i < 512; i += 256) {
        int n = nbase + i;
        cur[i] = (n < NN) ? offsets[n] : 0;
    }
    __syncthreads();
    int cnt = min(bcur[b], BCAP);
    const unsigned* seg = pairs + (size_t)b * BCAP;
    for (int i = t; i < cnt; i += 256) {
        unsigned p = seg[i];
        int pos = atomicAdd(&cur[p & 511], 1);
        srcs[pos] = (int)(p >> BSH);
    }
}

// ---------------- graph boundaries via binary search (batch is sorted) ----------------

__global__ void graph_bounds(const int* __restrict__ batch, int* __restrict__ goff) {
    int g = blockIdx.x * blockDim.x + threadIdx.x;
    if (g > NG) return;
    int lo = 0, hi = NN;
    while (lo < hi) {
        int mid = (lo + hi) >> 1;
        if (batch[mid] < g) lo = mid + 1; else hi = mid;
    }
    goff[g] = lo;
}

// ---------------- scans (counts rounded up to x8 inline -> padded offsets) ----------------

__global__ void scan_reduce(const int* __restrict__ in, int* __restrict__ bsum) {
    __shared__ int lds[256];
    int b = blockIdx.x, t = threadIdx.x;
    int s = 0;
    for (int i = t; i < SCAN_B; i += 256) {
        int idx = b * SCAN_B + i;
        if (idx < NN) s += (in[idx] + 7) & ~7;
    }
    lds[t] = s;
    __syncthreads();
    for (int off = 128; off > 0; off >>= 1) {
        if (t < off) lds[t] += lds[t + off];
        __syncthreads();
    }
    if (t == 0) bsum[b] = lds[0];
}

__global__ void scan_bsums(const int* __restrict__ bsum, int nb, int* __restrict__ boff,
                           int* __restrict__ total_loc) {
    __shared__ int lds[128];
    int t = threadIdx.x;
    int v = (t < nb) ? bsum[t] : 0;
    lds[t] = v;
    __syncthreads();
    for (int off = 1; off < 128; off <<= 1) {
        int x = (t >= off) ? lds[t - off] : 0;
        __syncthreads();
        lds[t] += x;
        __syncthreads();
    }
    if (t < nb) boff[t] = lds[t] - v;
    if (t == nb - 1) {
        boff[nb] = lds[t];
        if (total_loc) *total_loc = lds[t];
    }
}

__global__ void scan_final(const int* __restrict__ in, const int* __restrict__ boff,
                           int* __restrict__ out) {
    __shared__ int lds[SCAN_B];
    int b = blockIdx.x, t = threadIdx.x;
    int idx = b * SCAN_B + t;
    int v = (idx < NN) ? ((in[idx] + 7) & ~7) : 0;
    lds[t] = v;
    __syncthreads();
    for (int off = 1; off < SCAN_B; off <<= 1) {
        int x = (t >= off) ? lds[t - off] : 0;
        __syncthreads();
        lds[t] += x;
        __syncthreads();
    }
    if (idx < NN) out[idx] = boff[b] + lds[t] - v;
}

// ---------------- gemm1: Hh = fp16( X @ W1 ), fused per-head scores ----------------

__global__ __launch_bounds__(256) void gemm1(const float* __restrict__ X,
                                             const float* __restrict__ W,
                                             const float* __restrict__ a_s,
                                             const float* __restrict__ a_d,
                                             __half* __restrict__ Hh,
                                             float* __restrict__ SS,
                                             float* __restrict__ SD) {
    __shared__ float wl[128 * 64];
    __shared__ float xl[32 * 132];
    int t = threadIdx.x;
    int n0 = blockIdx.x * 32;
    for (int i = t * 4; i < 128 * 64; i += 1024)
        *(float4*)&wl[i] = *(const float4*)&W[i];
    for (int i = t * 4; i < 32 * 128; i += 1024) {
        int r = i >> 7, c = i & 127;
        int n = n0 + r;
        float4 v = (n < NN) ? *(const float4*)&X[(size_t)n * 128 + c] : make_float4(0, 0, 0, 0);
        *(float4*)&xl[r * 132 + c] = v;
    }
    __syncthreads();
    int cg = (t & 15) * 4;
    int ng = (t >> 4) * 2;
    float acc[2][4] = {};
    for (int k = 0; k < 128; ++k) {
        float4 w4 = *(float4*)&wl[k * 64 + cg];
        #pragma unroll
        for (int j = 0; j < 2; ++j) {
            float xv = xl[(ng + j) * 132 + k];
            acc[j][0] += xv * w4.x; acc[j][1] += xv * w4.y;
            acc[j][2] += xv * w4.z; acc[j][3] += xv * w4.w;
        }
    }
    int hd = cg >> 3;          // head (C=8), channels cg..cg+3 are half of head hd
    int half = cg & 7;         // 0 or 4
    #pragma unroll
    for (int j = 0; j < 2; ++j) {
        int n = n0 + ng + j;
        // fused scores: partial dot over this thread's 4 channels, complete via lane^1
        float p1 = 0.f, p2 = 0.f;
        #pragma unroll
        for (int k = 0; k < 4; ++k) {
            p1 += acc[j][k] * a_s[hd * 8 + half + k];
            p2 += acc[j][k] * a_d[hd * 8 + half + k];
        }
        float f1 = p1 + __shfl_xor(p1, 1, 64);
        float f2 = p2 + __shfl_xor(p2, 1, 64);
        if (n < NN) {
            __half2 q0 = __floats2half2_rn(acc[j][0], acc[j][1]);
            __half2 q1 = __floats2half2_rn(acc[j][2], acc[j][3]);
            *(__half2*)&Hh[(size_t)n * 64 + cg] = q0;
            *(__half2*)&Hh[(size_t)n * 64 + cg + 2] = q1;
            if (half == 0) {
                SS[(unsigned)n * 8 + hd] = f1;
                SD[(unsigned)n * 8 + hd] = f2;
            }
        }
    }
}

// ---------------- GAT gather: fused score+exp+weighted sum, one pass over edges ----------------

template <int HEADS, int C, int PL, int GRP>
__global__ __launch_bounds__(256) void gat_kernel(const __half* __restrict__ Hh,
                                                  const float* __restrict__ SS,
                                                  const float* __restrict__ SD,
                                                  const int* __restrict__ offsets,
                                                  const int* __restrict__ counts,
                                                  const int* __restrict__ srcs,
                                                  const float* __restrict__ bias,
                                                  __half* __restrict__ GO) {
    constexpr int CH = HEADS * C;  // 64 or 96
    int wid = blockIdx.x * (blockDim.x >> 6) + (threadIdx.x >> 6);
    int lane = threadIdx.x & 63;
    if (wid >= NN) return;
    int ch0 = lane * PL;
    bool active = ch0 < CH;
    int ch0l = active ? ch0 : 0;
    int head = active ? (ch0 / C) : 0;
    int beg = offsets[wid], end = offsets[wid + 1];
    int deg = counts[wid];
    float sdv = SD[(unsigned)wid * HEADS + head];
    float s = 0.f, a0 = 0.f, a1 = 0.f;
    int e = beg;
    if (GRP == 16) {
        for (; e + 16 <= end; e += 16) {
            int sv[16];
            float wv[16];
            #pragma unroll
            for (int i = 0; i < 16; ++i) {
                sv[i] = srcs[e + i];
                float sc = SS[(unsigned)(sv[i] * HEADS) + head] + sdv;
                sc = fmaxf(sc, 0.f) + 0.2f * fminf(sc, 0.f);
                wv[i] = (e + i - beg) < deg ? __expf(sc) : 0.f;
            }
            float hv0[16];
            #pragma unroll
            for (int i = 0; i < 16; ++i)
                hv0[i] = __half2float(Hh[(unsigned)(sv[i] * CH) + ch0l]);
            float pw[8], pa[8];
            #pragma unroll
            for (int i = 0; i < 8; ++i) {
                pw[i] = wv[2 * i] + wv[2 * i + 1];
                pa[i] = wv[2 * i] * hv0[2 * i] + wv[2 * i + 1] * hv0[2 * i + 1];
            }
            s  += ((pw[0] + pw[1]) + (pw[2] + pw[3])) + ((pw[4] + pw[5]) + (pw[6] + pw[7]));
            a0 += ((pa[0] + pa[1]) + (pa[2] + pa[3])) + ((pa[4] + pa[5]) + (pa[6] + pa[7]));
        }
    }
    for (; e < end; e += 8) {
        int sv[8];
        float wv[8];
        #pragma unroll
        for (int i = 0; i < 8; ++i) {
            sv[i] = srcs[e + i];
            float sc = SS[(unsigned)(sv[i] * HEADS) + head] + sdv;
            sc = fmaxf(sc, 0.f) + 0.2f * fminf(sc, 0.f);
            wv[i] = (e + i - beg) < deg ? __expf(sc) : 0.f;
        }
        float hv0[8], hv1[8];
        #pragma unroll
        for (int i = 0; i < 8; ++i) {
            if (PL == 2) {
                __half2 hp = *(const __half2*)&Hh[(unsigned)(sv[i] * CH) + ch0l];
                hv0[i] = __low2float(hp); hv1[i] = __high2float(hp);
            } else {
                hv0[i] = __half2float(Hh[(unsigned)(sv[i] * CH) + ch0l]);
                hv1[i] = 0.f;
            }
        }
        float ws = ((wv[0] + wv[1]) + (wv[2] + wv[3])) + ((wv[4] + wv[5]) + (wv[6] + wv[7]));
        float as0 = ((wv[0] * hv0[0] + wv[1] * hv0[1]) + (wv[2] * hv0[2] + wv[3] * hv0[3]))
                  + ((wv[4] * hv0[4] + wv[5] * hv0[5]) + (wv[6] * hv0[6] + wv[7] * hv0[7]));
        s += ws;
        a0 += as0;
        if (PL == 2) {
            float as1 = ((wv[0] * hv1[0] + wv[1] * hv1[1]) + (wv[2] * hv1[2] + wv[3] * hv1[3]))
                      + ((wv[4] * hv1[4] + wv[5] * hv1[5]) + (wv[6] * hv1[6] + wv[7] * hv1[7]));
            a1 += as1;
        }
    }
    if (active) {
        float inv = 1.f / s;
        if (PL == 2) {
            *(__half2*)&GO[(unsigned)(wid * CH) + ch0] =
                __floats2half2_rn(a0 * inv + bias[ch0], a1 * inv + bias[ch0 + 1]);
        } else {
            GO[(unsigned)(wid * CH) + ch0] = __float2half(a0 * inv + bias[ch0]);
        }
    }
}

// ---------------- BN stats (deterministic two-stage) ----------------

__global__ void stats_kernel(const float* __restrict__ X, int Nn, int C,
                             float* __restrict__ partial) {
    int t = threadIdx.x;
    int c = t % C;
    int grp = t / C;
    int G_ = blockDim.x / C;
    float s = 0.f, q = 0.f;
    for (int n = blockIdx.x * G_ + grp; n < Nn; n += gridDim.x * G_) {
        float v = X[(size_t)n * C + c];
        s += v; q += v * v;
    }
    extern __shared__ float lds[];
    lds[t] = s; lds[blockDim.x + t] = q;
    __syncthreads();
    for (int off = blockDim.x >> 1; off >= C; off >>= 1) {
        if (t < off) {
            lds[t] += lds[t + off];
            lds[blockDim.x + t] += lds[blockDim.x + t + off];
        }
        __syncthreads();
    }
    if (t < C) {
        partial[(size_t)blockIdx.x * 2 * C + t] = lds[t];
        partial[(size_t)blockIdx.x * 2 * C + C + t] = lds[blockDim.x + t];
    }
}

__global__ void stats_h_kernel(const __half* __restrict__ X, int Nn, int C,
                               float* __restrict__ partial) {
    int t = threadIdx.x;
    int c = t % C;
    int grp = t / C;
    int G_ = blockDim.x / C;
    float s = 0.f, q = 0.f;
    for (int n = blockIdx.x * G_ + grp; n < Nn; n += gridDim.x * G_) {
        float v = __half2float(X[(size_t)n * C + c]);
        s += v; q += v * v;
    }
    extern __shared__ float lds[];
    lds[t] = s; lds[blockDim.x + t] = q;
    __syncthreads();
    for (int off = blockDim.x >> 1; off >= C; off >>= 1) {
        if (t < off) {
            lds[t] += lds[t + off];
            lds[blockDim.x + t] += lds[blockDim.x + t + off];
        }
        __syncthreads();
    }
    if (t < C) {
        partial[(size_t)blockIdx.x * 2 * C + t] = lds[t];
        partial[(size_t)blockIdx.x * 2 * C + C + t] = lds[blockDim.x + t];
    }
}

// parallel finalize: blockDim = C * G (G pow2), LDS tree reduce
__global__ void bn_finalize(const float* __restrict__ partial, int nb, int C, float invN,
                            const float* __restrict__ g, const float* __restrict__ be,
                            float* __restrict__ scale, float* __restrict__ shift) {
    extern __shared__ float red[];
    int t = threadIdx.x;
    int c = t % C;
    int grp = t / C;
    int G_ = blockDim.x / C;
    float s = 0.f, q = 0.f;
    for (int b = grp; b < nb; b += G_) {
        s += partial[(size_t)b * 2 * C + c];
        q += partial[(size_t)b * 2 * C + C + c];
    }
    red[t] = s; red[blockDim.x + t] = q;
    __syncthreads();
    for (int off = blockDim.x >> 1; off >= C; off >>= 1) {
        if (t < off) {
            red[t] += red[t + off];
            red[blockDim.x + t] += red[blockDim.x + t + off];
        }
        __syncthreads();
    }
    if (t < C) {
        float mean = red[t] * invN;
        float var = fmaxf(red[blockDim.x + t] * invN - mean * mean, 0.f);
        float rs = rsqrtf(var + 1e-5f);
        float sc = g[t] * rs;
        scale[t] = sc;
        shift[t] = be[t] - mean * sc;
    }
}

// ---------------- relu(bn(X[N,64] fp16)) @ Lw(64,KOUT) + lb -> U ----------------

template <int KOUT>
__global__ __launch_bounds__(256) void bnrelu_linear(const __half* __restrict__ X,
                                                     const float* __restrict__ scale,
                                                     const float* __restrict__ shift,
                                                     const float* __restrict__ Lw,
                                                     const float* __restrict__ lb,
                                                     float* __restrict__ U) {
    __shared__ float tl[64 * 65];
    int t = threadIdx.x;
    int n0 = blockIdx.x * 64;
    for (int i = t * 4; i < 64 * 64; i += 1024) {
        int r = i >> 6, cc = i & 63;
        int n = n0 + r;
        float vv[4] = {0.f, 0.f, 0.f, 0.f};
        if (n < NN) {
            float2 v0 = __half22float2(*(const __half2*)&X[(size_t)n * 64 + cc]);
            float2 v1 = __half22float2(*(const __half2*)&X[(size_t)n * 64 + cc + 2]);
            vv[0] = v0.x; vv[1] = v0.y; vv[2] = v1.x; vv[3] = v1.y;
        }
        #pragma unroll
        for (int j = 0; j < 4; ++j)
            tl[r * 65 + cc + j] = fmaxf(vv[j] * scale[cc + j] + shift[cc + j], 0.f);
    }
    __syncthreads();
    int nl = t & 63;
    int kg = (t >> 6) * (KOUT / 4);
    float acc[KOUT / 4] = {};
    for (int l = 0; l < 64; ++l) {
        float v = tl[nl * 65 + l];
        #pragma unroll
        for (int j = 0; j < KOUT / 4; ++j) acc[j] += v * Lw[l * KOUT + kg + j];
    }
    int n = n0 + nl;
    if (n < NN)
        #pragma unroll
        for (int j = 0; j < KOUT / 4; ++j)
            U[(size_t)n * KOUT + kg + j] = acc[j] + lb[kg + j];
}

// ---------------- relu(bn(U)) @ W -> Hh (fp16), fused per-head scores ----------------
// Thread q of a node owns channels [q*CPT,(q+1)*CPT) == head q exactly (CPT == C).

template <int CIN, int COUT, int H, int C>
__global__ __launch_bounds__(256) void bnrelu_gemm(const float* __restrict__ U,
                                                   const float* __restrict__ scale,
                                                   const float* __restrict__ shift,
                                                   const float* __restrict__ W,
                                                   const float* __restrict__ a_s,
                                                   const float* __restrict__ a_d,
                                                   __half* __restrict__ Hh,
                                                   float* __restrict__ SS,
                                                   float* __restrict__ SD) {
    static_assert(COUT / 4 == C && H == 4, "thread-per-head mapping");
    int t = threadIdx.x;
    int nl = t >> 2;
    int q = t & 3;
    int n = blockIdx.x * 64 + nl;
    if (n >= NN) return;
    constexpr int CPT = COUT / 4;
    float v[CIN];
    #pragma unroll
    for (int c = 0; c < CIN; ++c)
        v[c] = fmaxf(U[(size_t)n * CIN + c] * scale[c] + shift[c], 0.f);
    float acc[CPT] = {};
    #pragma unroll
    for (int c = 0; c < CIN; ++c) {
        #pragma unroll
        for (int j = 0; j < CPT; ++j) acc[j] += v[c] * W[c * COUT + q * CPT + j];
    }
    float s1 = 0.f, s2 = 0.f;
    #pragma unroll
    for (int j = 0; j < CPT; ++j) {
        s1 += acc[j] * a_s[q * C + j];
        s2 += acc[j] * a_d[q * C + j];
    }
    SS[(unsigned)n * H + q] = s1;
    SD[(unsigned)n * H + q] = s2;
    #pragma unroll
    for (int j = 0; j < CPT; j += 2)
        *(__half2*)&Hh[(size_t)n * COUT + q * CPT + j] = __floats2half2_rn(acc[j], acc[j + 1]);
}

// ---------------- mean-pool per graph: grid (NG, 3), block 256 = 8 rows x 32 ch ----------------

__global__ __launch_bounds__(256) void pool_kernel(const __half* __restrict__ GO,
                                                   const float* __restrict__ scale,
                                                   const float* __restrict__ shift,
                                                   const int* __restrict__ goff,
                                                   float* __restrict__ pooled) {
    __shared__ float red[8][32];
    int g = blockIdx.x;
    int ch = blockIdx.y * 32 + (threadIdx.x & 31);
    int row = threadIdx.x >> 5;
    int beg = goff[g], end = goff[g + 1];
    float sc = scale[ch], sh = shift[ch];
    float s = 0.f;
    for (int n = beg + row; n < end; n += 8)
        s += fmaxf(__half2float(GO[(size_t)n * 96 + ch]) * sc + sh, 0.f);
    red[row][threadIdx.x & 31] = s;
    __syncthreads();
    if (row == 0) {
        #pragma unroll
        for (int r = 1; r < 8; ++r) s += red[r][threadIdx.x & 31];
        float cnt = (float)(end - beg);
        pooled[g * 96 + ch] = s / fmaxf(cnt, 1.f);
    }
}

__global__ void final_gemm(const float* __restrict__ pooled, const float* __restrict__ oW,
                           const float* __restrict__ ob, float* __restrict__ out) {
    int idx = blockIdx.x * blockDim.x + threadIdx.x;
    if (idx >= NG * 10) return;
    int g = idx / 10, k = idx % 10;
    float s = ob[k];
    for (int c = 0; c < 96; ++c) s += pooled[g * 96 + c] * oW[c * 10 + k];
    out[idx] = s;
}

// ---------------- launch ----------------

extern "C" void kernel_launch(void* const* d_in, const int* in_sizes, int n_in,
                              void* d_out, int out_size, void* d_ws, size_t ws_size,
                              hipStream_t stream) {
    const float* x   = (const float*)d_in[0];
    const int*   ei  = (const int*)d_in[1];
    const int*   bat = (const int*)d_in[2];
    const float *W1 = (const float*)d_in[3], *a1s = (const float*)d_in[4],
                *a1d = (const float*)d_in[5], *b1 = (const float*)d_in[6],
                *g1 = (const float*)d_in[7], *be1 = (const float*)d_in[8],
                *lW1 = (const float*)d_in[9], *lb1 = (const float*)d_in[10],
                *gl1 = (const float*)d_in[11], *bel1 = (const float*)d_in[12],
                *W2 = (const float*)d_in[13], *a2s = (const float*)d_in[14],
                *a2d = (const float*)d_in[15], *b2 = (const float*)d_in[16],
                *g2 = (const float*)d_in[17], *be2 = (const float*)d_in[18],
                *lW2 = (const float*)d_in[19], *lb2 = (const float*)d_in[20],
                *gl2 = (const float*)d_in[21], *bel2 = (const float*)d_in[22],
                *W3 = (const float*)d_in[23], *a3s = (const float*)d_in[24],
                *a3d = (const float*)d_in[25], *b3 = (const float*)d_in[26],
                *g3 = (const float*)d_in[27], *be3 = (const float*)d_in[28],
                *oW = (const float*)d_in[29], *ob = (const float*)d_in[30];
    float* out = (float*)d_out;

    // workspace layout
    int* iw      = (int*)d_ws;
    int* bcur    = iw;                   // NB  (memset)
    int* counts  = bcur + NB;            // NN
    int* offsets = counts + NN;          // NN+1 (padded offsets)
    int* goff    = offsets + NN + 1;     // NG+1
    int* bsum    = goff + NG + 1;        // SCAN_NB
    int* boff    = bsum + SCAN_NB;       // SCAN_NB+1
    int* srcs    = boff + SCAN_NB + 1;   // PSLOTS
    float* fw      = (float*)(srcs + PSLOTS);
    __half* GOh    = (__half*)fw;                // NN*96 halves (region reserved NN*96 floats)
    float* Ub      = fw + (size_t)NN * 96;       // NN*16
    float* SSb     = Ub + (size_t)NN * 16;       // NN*8
    float* SDb     = SSb + (size_t)NN * 8;       // NN*8
    float* partial = SDb + (size_t)NN * 8;       // STATS_BLOCKS*192
    float* scaleA  = partial + STATS_BLOCKS * 192;
    float* shiftA  = scaleA + 96;
    float* scaleB  = shiftA + 96;
    float* shiftB  = scaleB + 16;
    float* pooled  = shiftB + 16;                // NG*96
    __half* Hh     = (__half*)(pooled + NG * 96);     // NN*96 halves
    unsigned* pairs = (unsigned*)GOh;            // aliases GO region during preprocessing

    const float invN = 1.0f / (float)NN;

    // ---- edge bucket sort -> padded CSR (shared by all layers) ----
    hipMemsetAsync(bcur, 0, NB * sizeof(int), stream);
    hipMemsetAsync(srcs, 0, (size_t)PSLOTS * sizeof(int), stream);
    part_pass1<<<(ET + CHUNK - 1) / CHUNK, 256, 0, stream>>>(ei, bcur, pairs);
    graph_bounds<<<3, 256, 0, stream>>>(bat, goff);
    bucket_counts<<<NB, 256, 0, stream>>>(pairs, bcur, counts);
    scan_reduce<<<SCAN_NB, 256, 0, stream>>>(counts, bsum);
    scan_bsums<<<1, 128, 0, stream>>>(bsum, SCAN_NB, boff, &offsets[NN]);
    scan_final<<<SCAN_NB, SCAN_B, 0, stream>>>(counts, boff, offsets);
    bucket_scatter<<<NB, 256, 0, stream>>>(pairs, bcur, offsets, srcs);

    // ---- layer 1 ----
    gemm1<<<(NN + 31) / 32, 256, 0, stream>>>(x, W1, a1s, a1d, Hh, SSb, SDb);
    gat_kernel<8, 8, 1, 16><<<(NN + 3) / 4, 256, 0, stream>>>(Hh, SSb, SDb, offsets, counts, srcs, b1, GOh);
    stats_h_kernel<<<STATS_BLOCKS, 256, 2 * 256 * sizeof(float), stream>>>(GOh, NN, 64, partial);
    bn_finalize<<<1, 512, 2 * 512 * sizeof(float), stream>>>(partial, STATS_BLOCKS, 64, invN, g1, be1, scaleA, shiftA);
    bnrelu_linear<8><<<(NN + 63) / 64, 256, 0, stream>>>(GOh, scaleA, shiftA, lW1, lb1, Ub);
    stats_kernel<<<STATS_BLOCKS, 256, 2 * 256 * sizeof(float), stream>>>(Ub, NN, 8, partial);
    bn_finalize<<<1, 512, 2 * 512 * sizeof(float), stream>>>(partial, STATS_BLOCKS, 8, invN, gl1, bel1, scaleB, shiftB);

    // ---- layer 2 ----
    bnrelu_gemm<8, 64, 4, 16><<<(NN + 63) / 64, 256, 0, stream>>>(Ub, scaleB, shiftB, W2, a2s, a2d, Hh, SSb, SDb);
    gat_kernel<4, 16, 1, 16><<<(NN + 3) / 4, 256, 0, stream>>>(Hh, SSb, SDb, offsets, counts, srcs, b2, GOh);
    stats_h_kernel<<<STATS_BLOCKS, 256, 2 * 256 * sizeof(float), stream>>>(GOh, NN, 64, partial);
    bn_finalize<<<1, 512, 2 * 512 * sizeof(float), stream>>>(partial, STATS_BLOCKS, 64, invN, g2, be2, scaleA, shiftA);
    bnrelu_linear<16><<<(NN + 63) / 64, 256, 0, stream>>>(GOh, scaleA, shiftA, lW2, lb2, Ub);
    stats_kernel<<<STATS_BLOCKS, 256, 2 * 256 * sizeof(float), stream>>>(Ub, NN, 16, partial);
    bn_finalize<<<1, 512, 2 * 512 * sizeof(float), stream>>>(partial, STATS_BLOCKS, 16, invN, gl2, bel2, scaleB, shiftB);

    // ---- layer 3 ----
    bnrelu_gemm<16, 96, 4, 24><<<(NN + 63) / 64, 256, 0, stream>>>(Ub, scaleB, shiftB, W3, a3s, a3d, Hh, SSb, SDb);
    gat_kernel<4, 24, 2, 8><<<(NN + 3) / 4, 256, 0, stream>>>(Hh, SSb, SDb, offsets, counts, srcs, b3, GOh);
    stats_h_kernel<<<STATS_BLOCKS, 192, 2 * 192 * sizeof(float), stream>>>(GOh, NN, 96, partial);
    bn_finalize<<<1, 768, 2 * 768 * sizeof(float), stream>>>(partial, STATS_BLOCKS, 96, invN, g3, be3, scaleA, shiftA);

    // ---- pool + head ----
    pool_kernel<<<dim3(NG, 3), 256, 0, stream>>>(GOh, scaleA, shiftA, goff, pooled);
    final_gemm<<<(NG * 10 + 255) / 256, 256, 0, stream>>>(pooled, oW, ob, out);
}